// Round 3
// baseline (4856.250 us; speedup 1.0000x reference)
//
#include <hip/hip_runtime.h>
#include <float.h>
#include <math.h>

namespace {

constexpr int NB = 16;
constexpr int NP = 2048;
constexpr int KK = 20;
constexpr int TOT = NB * NP;   // 32768
constexpr int EBLK = 1024;     // edge pass grid

__device__ __forceinline__ float leaky(float v) { return fmaxf(v, 0.2f * v); }

// ---------------- pos -> pos4 (pad to 4 comps) ----------------
__global__ __launch_bounds__(256) void pos4_kernel(const float* __restrict__ pos,
                                                   float* __restrict__ pos4) {
    int i = blockIdx.x * 256 + threadIdx.x;
    if (i < TOT) {
        pos4[i * 4 + 0] = pos[i * 3 + 0];
        pos4[i * 4 + 1] = pos[i * 3 + 1];
        pos4[i * 4 + 2] = pos[i * 3 + 2];
        pos4[i * 4 + 3] = 0.f;
    }
}

// ---------------- squared norms (float4 rows) ----------------
__global__ __launch_bounds__(256) void sq4_kernel(const float* __restrict__ x, int ldx, int nj4,
                                                  float* __restrict__ sq) {
    int i = blockIdx.x * 256 + threadIdx.x;
    if (i < TOT) {
        const float4* r = reinterpret_cast<const float4*>(x + (size_t)i * ldx);
        float s = 0.f;
        for (int j4 = 0; j4 < nj4; ++j4) {
            float4 v = r[j4];
            s += v.x * v.x + v.y * v.y + v.z * v.z + v.w * v.w;
        }
        sq[i] = s;
    }
}

// ---------------- kNN via per-wave radix select ----------------
// Block = 256 threads = 4 waves; wave w owns query q0+w. Lane holds the 32
// candidates m = u*64+lane in registers as monotone uint keys. Selection:
// bound M (max of per-lane mins), then 4 x 8-bit radix rounds on a per-wave
// 256-bin LDS histogram -> exact 20th-smallest key T; emit (<T) unordered,
// (==T) in index order (matches lax.top_k stable ties).
template <int NJ4>
__global__ __launch_bounds__(256) void knn_rs_kernel(const float* __restrict__ x, int ldx,
                                                     const float* __restrict__ sq,
                                                     int* __restrict__ idx_out) {
    __shared__ float4 qs[4][NJ4];
    __shared__ unsigned hist[4][256];
    const int tid = threadIdx.x;
    const int w = tid >> 6, lane = tid & 63;
    const int q0 = blockIdx.x * 4;
    const int b = q0 / NP, bofs = b * NP;
    const float* xb = x + (size_t)bofs * ldx;
    if (tid < 4 * NJ4) {
        int qq = tid / NJ4, j4 = tid % NJ4;
        qs[qq][j4] = *reinterpret_cast<const float4*>(
            xb + (size_t)(q0 + qq - bofs) * ldx + j4 * 4);
    }
    __syncthreads();
    const int q = q0 + w;
    const float sqq = sq[q];
    const float* sqb = sq + bofs;

    unsigned keys[32];
    #pragma unroll
    for (int u = 0; u < 32; ++u) {
        const int m = u * 64 + lane;
        const float* xm = xb + (size_t)m * ldx;
        float dot = 0.f;
        #pragma unroll
        for (int j4 = 0; j4 < NJ4; ++j4) {
            float4 cv = *reinterpret_cast<const float4*>(xm + j4 * 4);
            float4 av = qs[w][j4];
            dot += av.x * cv.x + av.y * cv.y + av.z * cv.z + av.w * cv.w;
        }
        float d = sqq + sqb[m] - 2.f * dot;
        unsigned bits = __float_as_uint(d);
        keys[u] = (bits & 0x80000000u) ? ~bits : (bits | 0x80000000u);
    }

    // upper bound on T: max over lanes of per-lane min (>= 64th smallest)
    unsigned lm = 0xFFFFFFFFu;
    #pragma unroll
    for (int u = 0; u < 32; ++u) lm = min(lm, keys[u]);
    unsigned M = lm;
    #pragma unroll
    for (int off = 1; off < 64; off <<= 1) {
        unsigned t = __shfl_xor(M, off);
        M = max(M, t);
    }

    // 4 radix rounds -> exact T
    unsigned pref = 0, pmask = 0;
    int k0r = KK - 1;   // 0-based rank within remaining prefix class
    #pragma unroll
    for (int r = 0; r < 4; ++r) {
        const int shift = 24 - 8 * r;
        *reinterpret_cast<uint4*>(&hist[w][lane * 4]) = make_uint4(0u, 0u, 0u, 0u);
        #pragma unroll
        for (int u = 0; u < 32; ++u) {
            unsigned k = keys[u];
            if (k <= M && (k & pmask) == pref)
                atomicAdd(&hist[w][(k >> shift) & 255], 1u);
        }
        unsigned h0 = hist[w][lane * 4 + 0];
        unsigned h1 = hist[w][lane * 4 + 1];
        unsigned h2 = hist[w][lane * 4 + 2];
        unsigned h3 = hist[w][lane * 4 + 3];
        unsigned s = h0 + h1 + h2 + h3;
        unsigned sc = s;
        #pragma unroll
        for (int off = 1; off < 64; off <<= 1) {
            unsigned t = __shfl_up(sc, off);
            if (lane >= off) sc += t;
        }
        unsigned excl = sc - s;
        bool has = ((unsigned)k0r >= excl) && ((unsigned)k0r < sc);
        unsigned long long bm = __ballot(has);
        int src = __ffsll((unsigned long long)bm) - 1;
        unsigned bsel = 0, cb = 0;
        if (has) {
            unsigned c0 = excl;
            if ((unsigned)k0r < c0 + h0)                { bsel = lane * 4 + 0; cb = c0; }
            else if ((unsigned)k0r < c0 + h0 + h1)      { bsel = lane * 4 + 1; cb = c0 + h0; }
            else if ((unsigned)k0r < c0 + h0 + h1 + h2) { bsel = lane * 4 + 2; cb = c0 + h0 + h1; }
            else                                        { bsel = lane * 4 + 3; cb = c0 + h0 + h1 + h2; }
        }
        bsel = __shfl(bsel, src);
        cb = __shfl(cb, src);
        pref |= bsel << shift;
        pmask |= 0xFFu << shift;
        k0r -= (int)cb;
    }
    const unsigned T = pref;

    // emit strict winners (key < T), order irrelevant
    unsigned nl = 0;
    #pragma unroll
    for (int u = 0; u < 32; ++u) nl += (keys[u] < T) ? 1u : 0u;
    unsigned sc2 = nl;
    #pragma unroll
    for (int off = 1; off < 64; off <<= 1) {
        unsigned t = __shfl_up(sc2, off);
        if (lane >= off) sc2 += t;
    }
    unsigned cstrict = __shfl(sc2, 63);
    unsigned o = sc2 - nl;   // exclusive prefix = this lane's write base
    int* op = idx_out + (size_t)q * KK;
    #pragma unroll
    for (int u = 0; u < 32; ++u) {
        if (keys[u] < T) { op[o] = bofs + u * 64 + lane; ++o; }
    }
    // emit ties (key == T) in global index order (index = u*64+lane)
    int rem = KK - (int)cstrict;
    int ebase = (int)cstrict;
    #pragma unroll
    for (int u = 0; u < 32; ++u) {
        if (rem > 0) {
            bool eq = (keys[u] == T);
            unsigned long long bm = __ballot(eq);
            int before = __popcll(bm & ((1ull << lane) - 1ull));
            if (eq && before < rem) op[ebase + before] = bofs + u * 64 + lane;
            int take = __popcll(bm);
            if (take > rem) take = rem;
            ebase += take;
            rem -= take;
        }
    }
}

// ---------------- Wt[c][j] build: [Wd | Wtail] transposed, zero-padded ----------------
__global__ __launch_bounds__(256) void wt_build_kernel(const float* __restrict__ W,
                                                       float* __restrict__ Wt,
                                                       int D, int Dp, int C) {
    int i = blockIdx.x * 256 + threadIdx.x;
    if (i < 2 * C * Dp) {
        int c = i / Dp, j = i % Dp;
        float v = 0.f;
        if (j < D) {
            v = (c < C) ? (W[j * C + c] - W[(D + j) * C + c])
                        : W[(D + j) * C + (c - C)];
        }
        Wt[i] = v;
    }
}

// ---------------- X[TOT,Dp] @ Wt^T -> basexw[TOT,2C] ----------------
template <int NJ4, int C2>
__global__ __launch_bounds__(256) void xw_gemm_kernel(const float* __restrict__ x, int ldx,
                                                      const float* __restrict__ Wt,
                                                      float* __restrict__ bx) {
    constexpr int PG = 256 / C2;   // point groups
    constexpr int PTS = 16 / PG;   // points per thread
    __shared__ float4 Xs[16][NJ4];
    const int tid = threadIdx.x;
    const int p0 = blockIdx.x * 16;
    for (int i = tid; i < 16 * NJ4; i += 256) {
        int r = i / NJ4, j4 = i % NJ4;
        Xs[r][j4] = *reinterpret_cast<const float4*>(x + (size_t)(p0 + r) * ldx + j4 * 4);
    }
    __syncthreads();
    const int c = tid % C2, pg = tid / C2;
    const float4* wrow = reinterpret_cast<const float4*>(Wt + (size_t)c * (NJ4 * 4));
    float acc[PTS];
    #pragma unroll
    for (int u = 0; u < PTS; ++u) acc[u] = 0.f;
    #pragma unroll
    for (int j4 = 0; j4 < NJ4; ++j4) {
        float4 w4 = wrow[j4];
        #pragma unroll
        for (int u = 0; u < PTS; ++u) {
            float4 x4 = Xs[pg * PTS + u][j4];
            acc[u] += x4.x * w4.x + x4.y * w4.y + x4.z * w4.z + x4.w * w4.w;
        }
    }
    #pragma unroll
    for (int u = 0; u < PTS; ++u)
        bx[(size_t)(p0 + pg * PTS + u) * C2 + c] = acc[u];
}

// ---------------- edge pass: gather XW, stats + per-point max/min ----------------
template <int C>
__global__ __launch_bounds__(256) void edge_pass_kernel(const float* __restrict__ bx,
                                                        const int* __restrict__ idx,
                                                        float* __restrict__ psum,
                                                        float* __restrict__ psum2,
                                                        float* __restrict__ mmax,
                                                        float* __restrict__ mmin) {
    constexpr int PT = 256 / C;
    constexpr int C2 = 2 * C;
    __shared__ int sidx[PT][KK];
    __shared__ float red[256];
    const int tid = threadIdx.x;
    const int c = tid % C;
    const int pl = tid / C;
    float s1 = 0.f, s2 = 0.f;
    const int NT = TOT / PT;
    for (int t = blockIdx.x; t < NT; t += EBLK) {
        const int p0 = t * PT;
        __syncthreads();
        if (tid < PT * KK) sidx[tid / KK][tid % KK] = idx[(size_t)p0 * KK + tid];
        __syncthreads();
        const int p = p0 + pl;
        const float bv = bx[(size_t)p * C2 + c];
        float A = 0.f, Q = 0.f, M = -FLT_MAX, mn = FLT_MAX;
        #pragma unroll
        for (int k = 0; k < KK; ++k) {
            float v = bx[(size_t)sidx[pl][k] * C2 + C + c];
            A += v; Q += v * v; M = fmaxf(M, v); mn = fminf(mn, v);
        }
        s1 += (float)KK * bv + A;
        s2 += (float)KK * bv * bv + 2.f * bv * A + Q;
        mmax[(size_t)p * C + c] = bv + M;
        mmin[(size_t)p * C + c] = bv + mn;
    }
    red[tid] = s1;
    __syncthreads();
    if (tid < C) {
        float v = red[tid];
        #pragma unroll
        for (int u = 1; u < PT; ++u) v += red[tid + u * C];
        psum[(size_t)blockIdx.x * C + tid] = v;
    }
    __syncthreads();
    red[tid] = s2;
    __syncthreads();
    if (tid < C) {
        float v = red[tid];
        #pragma unroll
        for (int u = 1; u < PT; ++u) v += red[tid + u * C];
        psum2[(size_t)blockIdx.x * C + tid] = v;
    }
}

// ---------------- BN stats reduce -> alpha/beta ----------------
__global__ __launch_bounds__(256) void bn_reduce_kernel(
        const float* __restrict__ psum, const float* __restrict__ psum2,
        int npart, int C, const float* __restrict__ g, const float* __restrict__ bb,
        float inv_cnt, float* __restrict__ alpha, float* __restrict__ beta) {
    const int c = blockIdx.x;
    const int tid = threadIdx.x;
    __shared__ float r1[256], r2[256];
    float s1 = 0.f, s2 = 0.f;
    for (int i = tid; i < npart; i += 256) {
        s1 += psum[(size_t)i * C + c];
        s2 += psum2[(size_t)i * C + c];
    }
    r1[tid] = s1; r2[tid] = s2;
    __syncthreads();
    for (int s = 128; s > 0; s >>= 1) {
        if (tid < s) { r1[tid] += r1[tid + s]; r2[tid] += r2[tid + s]; }
        __syncthreads();
    }
    if (tid == 0) {
        float mean = r1[0] * inv_cnt;
        float var = r2[0] * inv_cnt - mean * mean;
        float a = g[c] * rsqrtf(var + 1e-5f);
        alpha[c] = a;
        beta[c] = bb[c] - mean * a;
    }
}

// ---------------- edge finalize: pick max/min by sign(alpha), affine+leaky ----------------
template <int C>
__global__ __launch_bounds__(256) void edge_finalize_kernel(const float* __restrict__ mmax,
                                                            const float* __restrict__ mmin,
                                                            const float* __restrict__ alpha,
                                                            const float* __restrict__ beta,
                                                            float* __restrict__ xc_slice) {
    constexpr int CQ = C / 4;
    int i4 = blockIdx.x * 256 + threadIdx.x;
    if (i4 < TOT * CQ) {
        int p = i4 / CQ, cq = i4 - p * CQ;
        float4 M4 = reinterpret_cast<const float4*>(mmax)[i4];
        float4 m4 = reinterpret_cast<const float4*>(mmin)[i4];
        float4 a4 = reinterpret_cast<const float4*>(alpha)[cq];
        float4 b4 = reinterpret_cast<const float4*>(beta)[cq];
        float4 o;
        o.x = leaky(a4.x * (a4.x >= 0.f ? M4.x : m4.x) + b4.x);
        o.y = leaky(a4.y * (a4.y >= 0.f ? M4.y : m4.y) + b4.y);
        o.z = leaky(a4.z * (a4.z >= 0.f ? M4.z : m4.z) + b4.z);
        o.w = leaky(a4.w * (a4.w >= 0.f ? M4.w : m4.w) + b4.w);
        *reinterpret_cast<float4*>(xc_slice + (size_t)p * 256 + cq * 4) = o;
    }
}

// ---------------- Wf transpose: [256][1024] -> [1024][256] ----------------
__global__ __launch_bounds__(256) void wft_build_kernel(const float* __restrict__ Wf,
                                                        float* __restrict__ Wft) {
    int i = blockIdx.x * 256 + threadIdx.x;
    if (i < 256 * 1024) {
        int e = i / 1024, o = i - e * 1024;
        Wft[(size_t)o * 256 + e] = Wf[i];
    }
}

// ---------------- conv_final fused: stats + per-batch max/min partials ----------------
__global__ __launch_bounds__(256) void fc_fused_kernel(const float* __restrict__ xc,
                                                       const float* __restrict__ Wft,
                                                       float* __restrict__ psum,
                                                       float* __restrict__ psum2,
                                                       float* __restrict__ pmax,
                                                       float* __restrict__ pmin) {
    __shared__ float4 rows[16][64];   // 16 points x 256 feats
    const int tid = threadIdx.x;
    const int b = blockIdx.x >> 5, jb = blockIdx.x & 31;
    float s1[4] = {0.f, 0.f, 0.f, 0.f}, s2[4] = {0.f, 0.f, 0.f, 0.f};
    float gx[4], gn[4];
    #pragma unroll
    for (int i = 0; i < 4; ++i) { gx[i] = -FLT_MAX; gn[i] = FLT_MAX; }
    for (int t = jb; t < 128; t += 32) {
        const int p0 = b * NP + t * 16;
        __syncthreads();
        for (int i = tid; i < 16 * 64; i += 256)
            rows[i >> 6][i & 63] = reinterpret_cast<const float4*>(xc)[(size_t)p0 * 64 + i];
        __syncthreads();
        float h[4][16];
        #pragma unroll
        for (int i = 0; i < 4; ++i)
            #pragma unroll
            for (int q = 0; q < 16; ++q) h[i][q] = 0.f;
        for (int e4 = 0; e4 < 64; ++e4) {
            float4 w4[4];
            #pragma unroll
            for (int i = 0; i < 4; ++i)
                w4[i] = reinterpret_cast<const float4*>(Wft)[(size_t)(tid + i * 256) * 64 + e4];
            #pragma unroll
            for (int q = 0; q < 16; ++q) {
                float4 r = rows[q][e4];
                #pragma unroll
                for (int i = 0; i < 4; ++i)
                    h[i][q] += r.x * w4[i].x + r.y * w4[i].y + r.z * w4[i].z + r.w * w4[i].w;
            }
        }
        #pragma unroll
        for (int i = 0; i < 4; ++i)
            #pragma unroll
            for (int q = 0; q < 16; ++q) {
                float v = h[i][q];
                s1[i] += v; s2[i] += v * v;
                gx[i] = fmaxf(gx[i], v); gn[i] = fminf(gn[i], v);
            }
    }
    #pragma unroll
    for (int i = 0; i < 4; ++i) {
        const size_t o = (size_t)blockIdx.x * 1024 + tid + i * 256;
        psum[o] = s1[i]; psum2[o] = s2[i];
        pmax[o] = gx[i]; pmin[o] = gn[i];
    }
}

// ---------------- gfeat finalize ----------------
__global__ __launch_bounds__(256) void gfeat_final_kernel(const float* __restrict__ pmax,
                                                          const float* __restrict__ pmin,
                                                          const float* __restrict__ alpha,
                                                          const float* __restrict__ beta,
                                                          float* __restrict__ gfeat) {
    int i = blockIdx.x * 256 + threadIdx.x;
    if (i < NB * 1024) {
        int b = i >> 10, c = i & 1023;
        float mx = -FLT_MAX, mn = FLT_MAX;
        for (int j = 0; j < 32; ++j) {
            size_t o = (size_t)((b << 5) + j) * 1024 + c;
            mx = fmaxf(mx, pmax[o]);
            mn = fminf(mn, pmin[o]);
        }
        float a = alpha[c];
        gfeat[i] = leaky(a * (a >= 0.f ? mx : mn) + beta[c]);
    }
}

// ---------------- tiny classifier ----------------
__global__ __launch_bounds__(256) void gemm_small(const float* __restrict__ A,
                                                  const float* __restrict__ W,
                                                  const float* __restrict__ bias,
                                                  float* __restrict__ out,
                                                  int M, int Kd, int Nd) {
    int i = blockIdx.x * 256 + threadIdx.x;
    if (i < M * Nd) {
        int m = i / Nd, c = i - m * Nd;
        float s = bias[c];
        const float* a = A + (size_t)m * Kd;
        for (int e = 0; e < Kd; ++e) s += a[e] * W[(size_t)e * Nd + c];
        out[i] = s;
    }
}

__global__ __launch_bounds__(256) void bn_rows_kernel(const float* __restrict__ z,
                                                      const float* __restrict__ g,
                                                      const float* __restrict__ bb,
                                                      float* __restrict__ out, int C) {
    int c = blockIdx.x * 256 + threadIdx.x;
    if (c < C) {
        float s = 0.f, s2 = 0.f;
        for (int b = 0; b < NB; ++b) {
            float v = z[(size_t)b * C + c];
            s += v; s2 += v * v;
        }
        float mean = s * (1.f / NB);
        float var = s2 * (1.f / NB) - mean * mean;
        float a = g[c] * rsqrtf(var + 1e-5f);
        float be = bb[c] - mean * a;
        for (int b = 0; b < NB; ++b) {
            float v = a * z[(size_t)b * C + c] + be;
            out[(size_t)b * C + c] = leaky(v);
        }
    }
}

} // namespace

extern "C" void kernel_launch(void* const* d_in, const int* in_sizes, int n_in,
                              void* d_out, int out_size, void* d_ws, size_t ws_size,
                              hipStream_t stream) {
    (void)in_sizes; (void)n_in; (void)out_size; (void)ws_size;
    const float* pos = (const float*)d_in[0];
    const float* W1  = (const float*)d_in[1];
    const float* g1  = (const float*)d_in[2];
    const float* b1  = (const float*)d_in[3];
    const float* W2  = (const float*)d_in[4];
    const float* g2  = (const float*)d_in[5];
    const float* b2  = (const float*)d_in[6];
    const float* W3  = (const float*)d_in[7];
    const float* g3  = (const float*)d_in[8];
    const float* b3  = (const float*)d_in[9];
    const float* Wf  = (const float*)d_in[10];
    const float* gf  = (const float*)d_in[11];
    const float* bf  = (const float*)d_in[12];
    const float* W4  = (const float*)d_in[13];
    const float* b4  = (const float*)d_in[14];
    const float* g4  = (const float*)d_in[15];
    const float* be4 = (const float*)d_in[16];
    const float* W5  = (const float*)d_in[17];
    const float* b5  = (const float*)d_in[18];
    const float* g5  = (const float*)d_in[19];
    const float* be5 = (const float*)d_in[20];
    const float* W6  = (const float*)d_in[21];
    const float* b6  = (const float*)d_in[22];
    float* out = (float*)d_out;

    float* ws = (float*)d_ws;
    size_t off = 0;
    int*   idx    = (int*)ws;      off += (size_t)TOT * KK;          // 2.6 MB
    float* pos4   = ws + off;      off += (size_t)TOT * 4;
    float* sq     = ws + off;      off += (size_t)TOT;
    float* Wt     = ws + off;      off += 256 * 64;
    float* Wft    = ws + off;      off += 1024 * 256;                // 1 MB
    float* basexw = ws + off;      off += (size_t)TOT * 256;         // 32 MB
    float* mmax   = ws + off;      off += (size_t)TOT * 128;         // 16 MB
    float* mmin   = ws + off;      off += (size_t)TOT * 128;         // 16 MB
    float* xc     = ws + off;      off += (size_t)TOT * 256;         // 32 MB
    float* psum   = ws + off;      off += (size_t)512 * 1024;        // 2 MB
    float* psum2  = ws + off;      off += (size_t)512 * 1024;
    float* pmax   = ws + off;      off += (size_t)512 * 1024;
    float* pmin   = ws + off;      off += (size_t)512 * 1024;
    float* alpha  = ws + off;      off += 1024;
    float* beta   = ws + off;      off += 1024;
    float* gfeat  = ws + off;      off += NB * 1024;
    float* z4     = ws + off;      off += NB * 512;
    float* h4     = ws + off;      off += NB * 512;
    float* z5     = ws + off;      off += NB * 256;
    float* h5     = ws + off;      off += NB * 256;

    const int npts_blk = (TOT + 255) / 256;

    // ---------- Layer 1 (D=3 padded to 4, C=64) ----------
    pos4_kernel<<<npts_blk, 256, 0, stream>>>(pos, pos4);
    sq4_kernel<<<npts_blk, 256, 0, stream>>>(pos4, 4, 1, sq);
    knn_rs_kernel<1><<<TOT / 4, 256, 0, stream>>>(pos4, 4, sq, idx);
    wt_build_kernel<<<2, 256, 0, stream>>>(W1, Wt, 3, 4, 64);
    xw_gemm_kernel<1, 128><<<TOT / 16, 256, 0, stream>>>(pos4, 4, Wt, basexw);
    edge_pass_kernel<64><<<EBLK, 256, 0, stream>>>(basexw, idx, psum, psum2, mmax, mmin);
    bn_reduce_kernel<<<64, 256, 0, stream>>>(psum, psum2, EBLK, 64, g1, b1,
                                             1.f / (float)(TOT * KK), alpha, beta);
    edge_finalize_kernel<64><<<TOT * 16 / 256, 256, 0, stream>>>(mmax, mmin, alpha, beta, xc + 0);

    // ---------- Layer 2 (D=64, C=64), input x1 = xc[:,0:64] ----------
    sq4_kernel<<<npts_blk, 256, 0, stream>>>(xc + 0, 256, 16, sq);
    knn_rs_kernel<16><<<TOT / 4, 256, 0, stream>>>(xc + 0, 256, sq, idx);
    wt_build_kernel<<<32, 256, 0, stream>>>(W2, Wt, 64, 64, 64);
    xw_gemm_kernel<16, 128><<<TOT / 16, 256, 0, stream>>>(xc + 0, 256, Wt, basexw);
    edge_pass_kernel<64><<<EBLK, 256, 0, stream>>>(basexw, idx, psum, psum2, mmax, mmin);
    bn_reduce_kernel<<<64, 256, 0, stream>>>(psum, psum2, EBLK, 64, g2, b2,
                                             1.f / (float)(TOT * KK), alpha, beta);
    edge_finalize_kernel<64><<<TOT * 16 / 256, 256, 0, stream>>>(mmax, mmin, alpha, beta, xc + 64);

    // ---------- Layer 3 (D=64, C=128), input x2 = xc[:,64:128] ----------
    sq4_kernel<<<npts_blk, 256, 0, stream>>>(xc + 64, 256, 16, sq);
    knn_rs_kernel<16><<<TOT / 4, 256, 0, stream>>>(xc + 64, 256, sq, idx);
    wt_build_kernel<<<64, 256, 0, stream>>>(W3, Wt, 64, 64, 128);
    xw_gemm_kernel<16, 256><<<TOT / 16, 256, 0, stream>>>(xc + 64, 256, Wt, basexw);
    edge_pass_kernel<128><<<EBLK, 256, 0, stream>>>(basexw, idx, psum, psum2, mmax, mmin);
    bn_reduce_kernel<<<128, 256, 0, stream>>>(psum, psum2, EBLK, 128, g3, b3,
                                              1.f / (float)(TOT * KK), alpha, beta);
    edge_finalize_kernel<128><<<TOT * 32 / 256, 256, 0, stream>>>(mmax, mmin, alpha, beta, xc + 128);

    // ---------- conv_final + global max pool ----------
    wft_build_kernel<<<1024, 256, 0, stream>>>(Wf, Wft);
    fc_fused_kernel<<<512, 256, 0, stream>>>(xc, Wft, psum, psum2, pmax, pmin);
    bn_reduce_kernel<<<1024, 256, 0, stream>>>(psum, psum2, 512, 1024, gf, bf,
                                               1.f / (float)TOT, alpha, beta);
    gfeat_final_kernel<<<64, 256, 0, stream>>>(pmax, pmin, alpha, beta, gfeat);

    // ---------- classifier ----------
    gemm_small<<<(NB * 512 + 255) / 256, 256, 0, stream>>>(gfeat, W4, b4, z4, NB, 1024, 512);
    bn_rows_kernel<<<2, 256, 0, stream>>>(z4, g4, be4, h4, 512);
    gemm_small<<<(NB * 256 + 255) / 256, 256, 0, stream>>>(h4, W5, b5, z5, NB, 512, 256);
    bn_rows_kernel<<<1, 256, 0, stream>>>(z5, g5, be5, h5, 256);
    gemm_small<<<(NB * 40 + 255) / 256, 256, 0, stream>>>(h5, W6, b6, out, NB, 256, 40);
}

// Round 4
// 1963.979 us; speedup vs baseline: 2.4727x; 2.4727x over previous
//
#include <hip/hip_runtime.h>
#include <float.h>
#include <math.h>

namespace {

constexpr int NB = 16;
constexpr int NP = 2048;
constexpr int KK = 20;
constexpr int TOT = NB * NP;   // 32768
constexpr int EBLK = 1024;     // edge pass grid

__device__ __forceinline__ float leaky(float v) { return fmaxf(v, 0.2f * v); }

// ---------------- pos -> pos4 (pad to 4 comps) ----------------
__global__ __launch_bounds__(256) void pos4_kernel(const float* __restrict__ pos,
                                                   float* __restrict__ pos4) {
    int i = blockIdx.x * 256 + threadIdx.x;
    if (i < TOT) {
        pos4[i * 4 + 0] = pos[i * 3 + 0];
        pos4[i * 4 + 1] = pos[i * 3 + 1];
        pos4[i * 4 + 2] = pos[i * 3 + 2];
        pos4[i * 4 + 3] = 0.f;
    }
}

// ---------------- squared norms (float4 rows) ----------------
__global__ __launch_bounds__(256) void sq4_kernel(const float* __restrict__ x, int ldx, int nj4,
                                                  float* __restrict__ sq) {
    int i = blockIdx.x * 256 + threadIdx.x;
    if (i < TOT) {
        const float4* r = reinterpret_cast<const float4*>(x + (size_t)i * ldx);
        float s = 0.f;
        for (int j4 = 0; j4 < nj4; ++j4) {
            float4 v = r[j4];
            s += v.x * v.x + v.y * v.y + v.z * v.z + v.w * v.w;
        }
        sq[i] = s;
    }
}

// ---------------- distance GEMM -> monotone uint keys ----------------
// grid (NP/64, NP/64, CB); block 256. 64x64 output tile, 4x4 per thread.
// keys[bc][m][n] = monotone(sq[m]+sq[n]-2*dot(x_m,x_n)) for batch b0+bc.
template <int NK>
__global__ __launch_bounds__(256) void dist_gemm_kernel(const float* __restrict__ x, int ldx,
                                                        const float* __restrict__ sq,
                                                        int b0,
                                                        unsigned* __restrict__ keys) {
    constexpr int NKP = NK + 1;            // row pad: stride 65 (or 5) floats
    __shared__ float At[64 * NKP];
    __shared__ float Bt[64 * NKP];
    const int tid = threadIdx.x;
    const int b = b0 + blockIdx.z;
    const int m0 = blockIdx.y * 64, n0 = blockIdx.x * 64;
    const int bofs = b * NP;
    const float* xb = x + (size_t)bofs * ldx;
    // stage tiles (row-major, padded)
    for (int i = tid; i < 64 * (NK / 4); i += 256) {
        const int r = i / (NK / 4), j4 = i % (NK / 4);
        float4 v = *reinterpret_cast<const float4*>(xb + (size_t)(m0 + r) * ldx + j4 * 4);
        At[r * NKP + j4 * 4 + 0] = v.x; At[r * NKP + j4 * 4 + 1] = v.y;
        At[r * NKP + j4 * 4 + 2] = v.z; At[r * NKP + j4 * 4 + 3] = v.w;
    }
    for (int i = tid; i < 64 * (NK / 4); i += 256) {
        const int r = i / (NK / 4), j4 = i % (NK / 4);
        float4 v = *reinterpret_cast<const float4*>(xb + (size_t)(n0 + r) * ldx + j4 * 4);
        Bt[r * NKP + j4 * 4 + 0] = v.x; Bt[r * NKP + j4 * 4 + 1] = v.y;
        Bt[r * NKP + j4 * 4 + 2] = v.z; Bt[r * NKP + j4 * 4 + 3] = v.w;
    }
    __syncthreads();
    const int tr = tid >> 4, tc = tid & 15;
    float acc[4][4];
    #pragma unroll
    for (int i = 0; i < 4; ++i)
        #pragma unroll
        for (int j = 0; j < 4; ++j) acc[i][j] = 0.f;
    #pragma unroll 4
    for (int k = 0; k < NK; ++k) {
        float a0 = At[(tr * 4 + 0) * NKP + k];
        float a1 = At[(tr * 4 + 1) * NKP + k];
        float a2 = At[(tr * 4 + 2) * NKP + k];
        float a3 = At[(tr * 4 + 3) * NKP + k];
        float v0 = Bt[(tc * 4 + 0) * NKP + k];
        float v1 = Bt[(tc * 4 + 1) * NKP + k];
        float v2 = Bt[(tc * 4 + 2) * NKP + k];
        float v3 = Bt[(tc * 4 + 3) * NKP + k];
        acc[0][0] += a0 * v0; acc[0][1] += a0 * v1; acc[0][2] += a0 * v2; acc[0][3] += a0 * v3;
        acc[1][0] += a1 * v0; acc[1][1] += a1 * v1; acc[1][2] += a1 * v2; acc[1][3] += a1 * v3;
        acc[2][0] += a2 * v0; acc[2][1] += a2 * v1; acc[2][2] += a2 * v2; acc[2][3] += a2 * v3;
        acc[3][0] += a3 * v0; acc[3][1] += a3 * v1; acc[3][2] += a3 * v2; acc[3][3] += a3 * v3;
    }
    float sa[4], sb[4];
    #pragma unroll
    for (int i = 0; i < 4; ++i) sa[i] = sq[bofs + m0 + tr * 4 + i];
    #pragma unroll
    for (int j = 0; j < 4; ++j) sb[j] = sq[bofs + n0 + tc * 4 + j];
    #pragma unroll
    for (int i = 0; i < 4; ++i) {
        unsigned kk[4];
        #pragma unroll
        for (int j = 0; j < 4; ++j) {
            float d = sa[i] + sb[j] - 2.f * acc[i][j];
            unsigned bits = __float_as_uint(d);
            kk[j] = (bits & 0x80000000u) ? ~bits : (bits | 0x80000000u);
        }
        *reinterpret_cast<uint4*>(keys + ((size_t)blockIdx.z * NP + m0 + tr * 4 + i) * NP
                                  + n0 + tc * 4) = make_uint4(kk[0], kk[1], kk[2], kk[3]);
    }
}

// ---------------- kNN select: ballot binary search, wave per query ----------------
__global__ __launch_bounds__(256) void knn_select_kernel(const unsigned* __restrict__ keys,
                                                         int b0,
                                                         int* __restrict__ idx_out) {
    const int tid = threadIdx.x;
    const int w = tid >> 6, lane = tid & 63;
    const int ql = blockIdx.x * 4 + w;        // chunk-local query
    const int bc = ql / NP;
    const int b = b0 + bc;
    const int bofs = b * NP;
    const unsigned* kr = keys + (size_t)ql * NP;

    unsigned keysr[32];
    #pragma unroll
    for (int u = 0; u < 32; ++u) keysr[u] = kr[u * 64 + lane];

    // per-lane min; wave: lo = min of all, M = max of lane-mins (>= 64th smallest)
    unsigned lmn = 0xFFFFFFFFu;
    #pragma unroll
    for (int u = 0; u < 32; ++u) lmn = min(lmn, keysr[u]);
    unsigned M = lmn, lo = lmn;
    #pragma unroll
    for (int off = 1; off < 64; off <<= 1) {
        unsigned tM = __shfl_xor(M, off);
        unsigned tl = __shfl_xor(lo, off);
        M = max(M, tM);
        lo = min(lo, tl);
    }
    // smallest t in [lo, M] with count(keys <= t) >= KK  (exists: count<=M >= 64)
    unsigned hi = M;
    while (lo < hi) {
        unsigned mid = lo + ((hi - lo) >> 1);
        int cnt = 0;
        #pragma unroll
        for (int u = 0; u < 32; ++u)
            cnt += __popcll(__ballot(keysr[u] <= mid));
        if (cnt >= KK) hi = mid; else lo = mid + 1;
    }
    const unsigned T = lo;

    // emit strict winners (key < T), order irrelevant (downstream symmetric in k)
    unsigned nl = 0;
    #pragma unroll
    for (int u = 0; u < 32; ++u) nl += (keysr[u] < T) ? 1u : 0u;
    unsigned sc2 = nl;
    #pragma unroll
    for (int off = 1; off < 64; off <<= 1) {
        unsigned t = __shfl_up(sc2, off);
        if (lane >= off) sc2 += t;
    }
    unsigned cstrict = __shfl(sc2, 63);
    unsigned o = sc2 - nl;   // exclusive prefix = this lane's write base
    int* op = idx_out + (size_t)(bofs + (ql - bc * NP)) * KK;
    #pragma unroll
    for (int u = 0; u < 32; ++u) {
        if (keysr[u] < T) { op[o] = bofs + u * 64 + lane; ++o; }
    }
    // emit ties (key == T) in ascending global index order (matches lax.top_k)
    int rem = KK - (int)cstrict;
    int ebase = (int)cstrict;
    #pragma unroll
    for (int u = 0; u < 32; ++u) {
        if (rem > 0) {
            bool eq = (keysr[u] == T);
            unsigned long long bm = __ballot(eq);
            int before = __popcll(bm & ((1ull << lane) - 1ull));
            if (eq && before < rem) op[ebase + before] = bofs + u * 64 + lane;
            int take = __popcll(bm);
            if (take > rem) take = rem;
            ebase += take;
            rem -= take;
        }
    }
}

// ---------------- Wt[c][j] build: [Wd | Wtail] transposed, zero-padded ----------------
__global__ __launch_bounds__(256) void wt_build_kernel(const float* __restrict__ W,
                                                       float* __restrict__ Wt,
                                                       int D, int Dp, int C) {
    int i = blockIdx.x * 256 + threadIdx.x;
    if (i < 2 * C * Dp) {
        int c = i / Dp, j = i % Dp;
        float v = 0.f;
        if (j < D) {
            v = (c < C) ? (W[j * C + c] - W[(D + j) * C + c])
                        : W[(D + j) * C + (c - C)];
        }
        Wt[i] = v;
    }
}

// ---------------- X[TOT,Dp] @ Wt^T -> basexw[TOT,2C] ----------------
template <int NJ4, int C2>
__global__ __launch_bounds__(256) void xw_gemm_kernel(const float* __restrict__ x, int ldx,
                                                      const float* __restrict__ Wt,
                                                      float* __restrict__ bx) {
    constexpr int PG = 256 / C2;   // point groups
    constexpr int PTS = 16 / PG;   // points per thread
    __shared__ float4 Xs[16][NJ4];
    const int tid = threadIdx.x;
    const int p0 = blockIdx.x * 16;
    for (int i = tid; i < 16 * NJ4; i += 256) {
        int r = i / NJ4, j4 = i % NJ4;
        Xs[r][j4] = *reinterpret_cast<const float4*>(x + (size_t)(p0 + r) * ldx + j4 * 4);
    }
    __syncthreads();
    const int c = tid % C2, pg = tid / C2;
    const float4* wrow = reinterpret_cast<const float4*>(Wt + (size_t)c * (NJ4 * 4));
    float acc[PTS];
    #pragma unroll
    for (int u = 0; u < PTS; ++u) acc[u] = 0.f;
    #pragma unroll
    for (int j4 = 0; j4 < NJ4; ++j4) {
        float4 w4 = wrow[j4];
        #pragma unroll
        for (int u = 0; u < PTS; ++u) {
            float4 x4 = Xs[pg * PTS + u][j4];
            acc[u] += x4.x * w4.x + x4.y * w4.y + x4.z * w4.z + x4.w * w4.w;
        }
    }
    #pragma unroll
    for (int u = 0; u < PTS; ++u)
        bx[(size_t)(p0 + pg * PTS + u) * C2 + c] = acc[u];
}

// ---------------- edge pass: gather XW, stats + per-point max/min ----------------
template <int C>
__global__ __launch_bounds__(256) void edge_pass_kernel(const float* __restrict__ bx,
                                                        const int* __restrict__ idx,
                                                        float* __restrict__ psum,
                                                        float* __restrict__ psum2,
                                                        float* __restrict__ mmax,
                                                        float* __restrict__ mmin) {
    constexpr int PT = 256 / C;
    constexpr int C2 = 2 * C;
    __shared__ int sidx[PT][KK];
    __shared__ float red[256];
    const int tid = threadIdx.x;
    const int c = tid % C;
    const int pl = tid / C;
    float s1 = 0.f, s2 = 0.f;
    const int NT = TOT / PT;
    for (int t = blockIdx.x; t < NT; t += EBLK) {
        const int p0 = t * PT;
        __syncthreads();
        if (tid < PT * KK) sidx[tid / KK][tid % KK] = idx[(size_t)p0 * KK + tid];
        __syncthreads();
        const int p = p0 + pl;
        const float bv = bx[(size_t)p * C2 + c];
        float A = 0.f, Q = 0.f, M = -FLT_MAX, mn = FLT_MAX;
        #pragma unroll
        for (int k = 0; k < KK; ++k) {
            float v = bx[(size_t)sidx[pl][k] * C2 + C + c];
            A += v; Q += v * v; M = fmaxf(M, v); mn = fminf(mn, v);
        }
        s1 += (float)KK * bv + A;
        s2 += (float)KK * bv * bv + 2.f * bv * A + Q;
        mmax[(size_t)p * C + c] = bv + M;
        mmin[(size_t)p * C + c] = bv + mn;
    }
    red[tid] = s1;
    __syncthreads();
    if (tid < C) {
        float v = red[tid];
        #pragma unroll
        for (int u = 1; u < PT; ++u) v += red[tid + u * C];
        psum[(size_t)blockIdx.x * C + tid] = v;
    }
    __syncthreads();
    red[tid] = s2;
    __syncthreads();
    if (tid < C) {
        float v = red[tid];
        #pragma unroll
        for (int u = 1; u < PT; ++u) v += red[tid + u * C];
        psum2[(size_t)blockIdx.x * C + tid] = v;
    }
}

// ---------------- BN stats reduce -> alpha/beta ----------------
__global__ __launch_bounds__(256) void bn_reduce_kernel(
        const float* __restrict__ psum, const float* __restrict__ psum2,
        int npart, int C, const float* __restrict__ g, const float* __restrict__ bb,
        float inv_cnt, float* __restrict__ alpha, float* __restrict__ beta) {
    const int c = blockIdx.x;
    const int tid = threadIdx.x;
    __shared__ float r1[256], r2[256];
    float s1 = 0.f, s2 = 0.f;
    for (int i = tid; i < npart; i += 256) {
        s1 += psum[(size_t)i * C + c];
        s2 += psum2[(size_t)i * C + c];
    }
    r1[tid] = s1; r2[tid] = s2;
    __syncthreads();
    for (int s = 128; s > 0; s >>= 1) {
        if (tid < s) { r1[tid] += r1[tid + s]; r2[tid] += r2[tid + s]; }
        __syncthreads();
    }
    if (tid == 0) {
        float mean = r1[0] * inv_cnt;
        float var = r2[0] * inv_cnt - mean * mean;
        float a = g[c] * rsqrtf(var + 1e-5f);
        alpha[c] = a;
        beta[c] = bb[c] - mean * a;
    }
}

// ---------------- edge finalize: pick max/min by sign(alpha), affine+leaky ----------------
template <int C>
__global__ __launch_bounds__(256) void edge_finalize_kernel(const float* __restrict__ mmax,
                                                            const float* __restrict__ mmin,
                                                            const float* __restrict__ alpha,
                                                            const float* __restrict__ beta,
                                                            float* __restrict__ xc_slice) {
    constexpr int CQ = C / 4;
    int i4 = blockIdx.x * 256 + threadIdx.x;
    if (i4 < TOT * CQ) {
        int p = i4 / CQ, cq = i4 - p * CQ;
        float4 M4 = reinterpret_cast<const float4*>(mmax)[i4];
        float4 m4 = reinterpret_cast<const float4*>(mmin)[i4];
        float4 a4 = reinterpret_cast<const float4*>(alpha)[cq];
        float4 b4 = reinterpret_cast<const float4*>(beta)[cq];
        float4 o;
        o.x = leaky(a4.x * (a4.x >= 0.f ? M4.x : m4.x) + b4.x);
        o.y = leaky(a4.y * (a4.y >= 0.f ? M4.y : m4.y) + b4.y);
        o.z = leaky(a4.z * (a4.z >= 0.f ? M4.z : m4.z) + b4.z);
        o.w = leaky(a4.w * (a4.w >= 0.f ? M4.w : m4.w) + b4.w);
        *reinterpret_cast<float4*>(xc_slice + (size_t)p * 256 + cq * 4) = o;
    }
}

// ---------------- Wf transpose: [256][1024] -> [1024][256] ----------------
__global__ __launch_bounds__(256) void wft_build_kernel(const float* __restrict__ Wf,
                                                        float* __restrict__ Wft) {
    int i = blockIdx.x * 256 + threadIdx.x;
    if (i < 256 * 1024) {
        int e = i / 1024, o = i - e * 1024;
        Wft[(size_t)o * 256 + e] = Wf[i];
    }
}

// ---------------- conv_final fused: stats + per-batch max/min partials ----------------
__global__ __launch_bounds__(256) void fc_fused_kernel(const float* __restrict__ xc,
                                                       const float* __restrict__ Wft,
                                                       float* __restrict__ psum,
                                                       float* __restrict__ psum2,
                                                       float* __restrict__ pmax,
                                                       float* __restrict__ pmin) {
    __shared__ float4 rows[16][64];   // 16 points x 256 feats
    const int tid = threadIdx.x;
    const int b = blockIdx.x >> 5, jb = blockIdx.x & 31;
    float s1[4] = {0.f, 0.f, 0.f, 0.f}, s2[4] = {0.f, 0.f, 0.f, 0.f};
    float gx[4], gn[4];
    #pragma unroll
    for (int i = 0; i < 4; ++i) { gx[i] = -FLT_MAX; gn[i] = FLT_MAX; }
    for (int t = jb; t < 128; t += 32) {
        const int p0 = b * NP + t * 16;
        __syncthreads();
        for (int i = tid; i < 16 * 64; i += 256)
            rows[i >> 6][i & 63] = reinterpret_cast<const float4*>(xc)[(size_t)p0 * 64 + i];
        __syncthreads();
        float h[4][16];
        #pragma unroll
        for (int i = 0; i < 4; ++i)
            #pragma unroll
            for (int q = 0; q < 16; ++q) h[i][q] = 0.f;
        for (int e4 = 0; e4 < 64; ++e4) {
            float4 w4[4];
            #pragma unroll
            for (int i = 0; i < 4; ++i)
                w4[i] = reinterpret_cast<const float4*>(Wft)[(size_t)(tid + i * 256) * 64 + e4];
            #pragma unroll
            for (int q = 0; q < 16; ++q) {
                float4 r = rows[q][e4];
                #pragma unroll
                for (int i = 0; i < 4; ++i)
                    h[i][q] += r.x * w4[i].x + r.y * w4[i].y + r.z * w4[i].z + r.w * w4[i].w;
            }
        }
        #pragma unroll
        for (int i = 0; i < 4; ++i)
            #pragma unroll
            for (int q = 0; q < 16; ++q) {
                float v = h[i][q];
                s1[i] += v; s2[i] += v * v;
                gx[i] = fmaxf(gx[i], v); gn[i] = fminf(gn[i], v);
            }
    }
    #pragma unroll
    for (int i = 0; i < 4; ++i) {
        const size_t o = (size_t)blockIdx.x * 1024 + tid + i * 256;
        psum[o] = s1[i]; psum2[o] = s2[i];
        pmax[o] = gx[i]; pmin[o] = gn[i];
    }
}

// ---------------- gfeat finalize ----------------
__global__ __launch_bounds__(256) void gfeat_final_kernel(const float* __restrict__ pmax,
                                                          const float* __restrict__ pmin,
                                                          const float* __restrict__ alpha,
                                                          const float* __restrict__ beta,
                                                          float* __restrict__ gfeat) {
    int i = blockIdx.x * 256 + threadIdx.x;
    if (i < NB * 1024) {
        int b = i >> 10, c = i & 1023;
        float mx = -FLT_MAX, mn = FLT_MAX;
        for (int j = 0; j < 32; ++j) {
            size_t o = (size_t)((b << 5) + j) * 1024 + c;
            mx = fmaxf(mx, pmax[o]);
            mn = fminf(mn, pmin[o]);
        }
        float a = alpha[c];
        gfeat[i] = leaky(a * (a >= 0.f ? mx : mn) + beta[c]);
    }
}

// ---------------- tiny classifier ----------------
__global__ __launch_bounds__(256) void gemm_small(const float* __restrict__ A,
                                                  const float* __restrict__ W,
                                                  const float* __restrict__ bias,
                                                  float* __restrict__ out,
                                                  int M, int Kd, int Nd) {
    int i = blockIdx.x * 256 + threadIdx.x;
    if (i < M * Nd) {
        int m = i / Nd, c = i - m * Nd;
        float s = bias[c];
        const float* a = A + (size_t)m * Kd;
        for (int e = 0; e < Kd; ++e) s += a[e] * W[(size_t)e * Nd + c];
        out[i] = s;
    }
}

__global__ __launch_bounds__(256) void bn_rows_kernel(const float* __restrict__ z,
                                                      const float* __restrict__ g,
                                                      const float* __restrict__ bb,
                                                      float* __restrict__ out, int C) {
    int c = blockIdx.x * 256 + threadIdx.x;
    if (c < C) {
        float s = 0.f, s2 = 0.f;
        for (int b = 0; b < NB; ++b) {
            float v = z[(size_t)b * C + c];
            s += v; s2 += v * v;
        }
        float mean = s * (1.f / NB);
        float var = s2 * (1.f / NB) - mean * mean;
        float a = g[c] * rsqrtf(var + 1e-5f);
        float be = bb[c] - mean * a;
        for (int b = 0; b < NB; ++b) {
            float v = a * z[(size_t)b * C + c] + be;
            out[(size_t)b * C + c] = leaky(v);
        }
    }
}

static void run_knn(const float* x, int ldx, int nk, const float* sq, unsigned* keys,
                    int CB, int* idx, hipStream_t stream) {
    for (int b0 = 0; b0 < NB; b0 += CB) {
        dim3 g(NP / 64, NP / 64, CB);
        if (nk == 4)
            dist_gemm_kernel<4><<<g, 256, 0, stream>>>(x, ldx, sq, b0, keys);
        else
            dist_gemm_kernel<64><<<g, 256, 0, stream>>>(x, ldx, sq, b0, keys);
        knn_select_kernel<<<CB * NP / 4, 256, 0, stream>>>(keys, b0, idx);
    }
}

} // namespace

extern "C" void kernel_launch(void* const* d_in, const int* in_sizes, int n_in,
                              void* d_out, int out_size, void* d_ws, size_t ws_size,
                              hipStream_t stream) {
    (void)in_sizes; (void)n_in; (void)out_size;
    const float* pos = (const float*)d_in[0];
    const float* W1  = (const float*)d_in[1];
    const float* g1  = (const float*)d_in[2];
    const float* b1  = (const float*)d_in[3];
    const float* W2  = (const float*)d_in[4];
    const float* g2  = (const float*)d_in[5];
    const float* b2  = (const float*)d_in[6];
    const float* W3  = (const float*)d_in[7];
    const float* g3  = (const float*)d_in[8];
    const float* b3  = (const float*)d_in[9];
    const float* Wf  = (const float*)d_in[10];
    const float* gf  = (const float*)d_in[11];
    const float* bf  = (const float*)d_in[12];
    const float* W4  = (const float*)d_in[13];
    const float* b4  = (const float*)d_in[14];
    const float* g4  = (const float*)d_in[15];
    const float* be4 = (const float*)d_in[16];
    const float* W5  = (const float*)d_in[17];
    const float* b5  = (const float*)d_in[18];
    const float* g5  = (const float*)d_in[19];
    const float* be5 = (const float*)d_in[20];
    const float* W6  = (const float*)d_in[21];
    const float* b6  = (const float*)d_in[22];
    float* out = (float*)d_out;

    float* ws = (float*)d_ws;
    size_t off = 0;
    int*   idx    = (int*)ws;      off += (size_t)TOT * KK;          // 2.6 MB
    float* pos4   = ws + off;      off += (size_t)TOT * 4;
    float* sq     = ws + off;      off += (size_t)TOT;
    float* Wt     = ws + off;      off += 256 * 64;
    float* Wft    = ws + off;      off += 1024 * 256;                // 1 MB
    float* basexw = ws + off;      off += (size_t)TOT * 256;         // 32 MB
    float* mmax   = ws + off;      off += (size_t)TOT * 128;         // 16 MB
    float* mmin   = ws + off;      off += (size_t)TOT * 128;         // 16 MB
    float* xc     = ws + off;      off += (size_t)TOT * 256;         // 32 MB
    float* psum   = ws + off;      off += (size_t)512 * 1024;        // 2 MB
    float* psum2  = ws + off;      off += (size_t)512 * 1024;
    float* pmax   = ws + off;      off += (size_t)512 * 1024;
    float* pmin   = ws + off;      off += (size_t)512 * 1024;
    float* alpha  = ws + off;      off += 1024;
    float* beta   = ws + off;      off += 1024;
    float* gfeat  = ws + off;      off += NB * 1024;
    float* z4     = ws + off;      off += NB * 512;
    float* h4     = ws + off;      off += NB * 512;
    float* z5     = ws + off;      off += NB * 256;
    float* h5     = ws + off;      off += NB * 256;
    unsigned* keys = (unsigned*)(ws + off);
    // choose keys chunk size (batches) from remaining workspace — deterministic
    const size_t avail = (ws_size > off * 4) ? (ws_size - off * 4) : 0;
    const size_t per_batch = (size_t)NP * NP * 4;
    int CB = 1;
    for (int cb : {16, 8, 4, 2}) {
        if ((size_t)cb * per_batch <= avail) { CB = cb; break; }
    }

    const int npts_blk = (TOT + 255) / 256;

    // ---------- Layer 1 (D=3 padded to 4, C=64) ----------
    pos4_kernel<<<npts_blk, 256, 0, stream>>>(pos, pos4);
    sq4_kernel<<<npts_blk, 256, 0, stream>>>(pos4, 4, 1, sq);
    run_knn(pos4, 4, 4, sq, keys, CB, idx, stream);
    wt_build_kernel<<<2, 256, 0, stream>>>(W1, Wt, 3, 4, 64);
    xw_gemm_kernel<1, 128><<<TOT / 16, 256, 0, stream>>>(pos4, 4, Wt, basexw);
    edge_pass_kernel<64><<<EBLK, 256, 0, stream>>>(basexw, idx, psum, psum2, mmax, mmin);
    bn_reduce_kernel<<<64, 256, 0, stream>>>(psum, psum2, EBLK, 64, g1, b1,
                                             1.f / (float)(TOT * KK), alpha, beta);
    edge_finalize_kernel<64><<<TOT * 16 / 256, 256, 0, stream>>>(mmax, mmin, alpha, beta, xc + 0);

    // ---------- Layer 2 (D=64, C=64), input x1 = xc[:,0:64] ----------
    sq4_kernel<<<npts_blk, 256, 0, stream>>>(xc + 0, 256, 16, sq);
    run_knn(xc + 0, 256, 64, sq, keys, CB, idx, stream);
    wt_build_kernel<<<32, 256, 0, stream>>>(W2, Wt, 64, 64, 64);
    xw_gemm_kernel<16, 128><<<TOT / 16, 256, 0, stream>>>(xc + 0, 256, Wt, basexw);
    edge_pass_kernel<64><<<EBLK, 256, 0, stream>>>(basexw, idx, psum, psum2, mmax, mmin);
    bn_reduce_kernel<<<64, 256, 0, stream>>>(psum, psum2, EBLK, 64, g2, b2,
                                             1.f / (float)(TOT * KK), alpha, beta);
    edge_finalize_kernel<64><<<TOT * 16 / 256, 256, 0, stream>>>(mmax, mmin, alpha, beta, xc + 64);

    // ---------- Layer 3 (D=64, C=128), input x2 = xc[:,64:128] ----------
    sq4_kernel<<<npts_blk, 256, 0, stream>>>(xc + 64, 256, 16, sq);
    run_knn(xc + 64, 256, 64, sq, keys, CB, idx, stream);
    wt_build_kernel<<<64, 256, 0, stream>>>(W3, Wt, 64, 64, 128);
    xw_gemm_kernel<16, 256><<<TOT / 16, 256, 0, stream>>>(xc + 64, 256, Wt, basexw);
    edge_pass_kernel<128><<<EBLK, 256, 0, stream>>>(basexw, idx, psum, psum2, mmax, mmin);
    bn_reduce_kernel<<<128, 256, 0, stream>>>(psum, psum2, EBLK, 128, g3, b3,
                                              1.f / (float)(TOT * KK), alpha, beta);
    edge_finalize_kernel<128><<<TOT * 32 / 256, 256, 0, stream>>>(mmax, mmin, alpha, beta, xc + 128);

    // ---------- conv_final + global max pool ----------
    wft_build_kernel<<<1024, 256, 0, stream>>>(Wf, Wft);
    fc_fused_kernel<<<512, 256, 0, stream>>>(xc, Wft, psum, psum2, pmax, pmin);
    bn_reduce_kernel<<<1024, 256, 0, stream>>>(psum, psum2, 512, 1024, gf, bf,
                                               1.f / (float)TOT, alpha, beta);
    gfeat_final_kernel<<<64, 256, 0, stream>>>(pmax, pmin, alpha, beta, gfeat);

    // ---------- classifier ----------
    gemm_small<<<(NB * 512 + 255) / 256, 256, 0, stream>>>(gfeat, W4, b4, z4, NB, 1024, 512);
    bn_rows_kernel<<<2, 256, 0, stream>>>(z4, g4, be4, h4, 512);
    gemm_small<<<(NB * 256 + 255) / 256, 256, 0, stream>>>(h4, W5, b5, z5, NB, 512, 256);
    bn_rows_kernel<<<1, 256, 0, stream>>>(z5, g5, be5, h5, 256);
    gemm_small<<<(NB * 40 + 255) / 256, 256, 0, stream>>>(h5, W6, b6, out, NB, 256, 40);
}

// Round 5
// 1947.908 us; speedup vs baseline: 2.4931x; 1.0083x over previous
//
#include <hip/hip_runtime.h>
#include <float.h>
#include <math.h>

namespace {

constexpr int NB = 16;
constexpr int NP = 2048;
constexpr int KK = 20;
constexpr int TOT = NB * NP;   // 32768
constexpr int EBLK = 1024;     // edge pass grid

__device__ __forceinline__ float leaky(float v) { return fmaxf(v, 0.2f * v); }

// ---------------- pos -> pos4 (pad to 4 comps) ----------------
__global__ __launch_bounds__(256) void pos4_kernel(const float* __restrict__ pos,
                                                   float* __restrict__ pos4) {
    int i = blockIdx.x * 256 + threadIdx.x;
    if (i < TOT) {
        pos4[i * 4 + 0] = pos[i * 3 + 0];
        pos4[i * 4 + 1] = pos[i * 3 + 1];
        pos4[i * 4 + 2] = pos[i * 3 + 2];
        pos4[i * 4 + 3] = 0.f;
    }
}

// ---------------- squared norms (float4 rows) ----------------
__global__ __launch_bounds__(256) void sq4_kernel(const float* __restrict__ x, int ldx, int nj4,
                                                  float* __restrict__ sq) {
    int i = blockIdx.x * 256 + threadIdx.x;
    if (i < TOT) {
        const float4* r = reinterpret_cast<const float4*>(x + (size_t)i * ldx);
        float s = 0.f;
        for (int j4 = 0; j4 < nj4; ++j4) {
            float4 v = r[j4];
            s += v.x * v.x + v.y * v.y + v.z * v.z + v.w * v.w;
        }
        sq[i] = s;
    }
}

// ---------------- shared GEMM tile staging: 128 rows x KC floats, pad KC+1 ----------------
template <int KC>
__device__ __forceinline__ void stage_tile(const float* __restrict__ src, int ldx,
                                           int row0, int k0, float* __restrict__ dst) {
    constexpr int F4 = KC / 4;
    const int tid = threadIdx.x;
    #pragma unroll
    for (int i = tid; i < 128 * F4; i += 256) {
        const int r = i / F4, c4 = i % F4;
        float4 v = *reinterpret_cast<const float4*>(src + (size_t)(row0 + r) * ldx + k0 + c4 * 4);
        float* d = dst + r * (KC + 1) + c4 * 4;
        d[0] = v.x; d[1] = v.y; d[2] = v.z; d[3] = v.w;
    }
}

// ---------------- distance GEMM -> monotone uint keys ----------------
// 128x128 tile, 8x8/thread (interleaved cols: r=tr+16i, c=tc+16j), K-chunk 32.
template <int KTOT>
__global__ __launch_bounds__(256, 4) void dist_gemm_kernel(const float* __restrict__ x, int ldx,
                                                           const float* __restrict__ sq,
                                                           int b0,
                                                           unsigned* __restrict__ keys) {
    constexpr int KC = (KTOT < 32) ? KTOT : 32;
    constexpr int LP = KC + 1;
    __shared__ float As[128 * LP];
    __shared__ float Bs[128 * LP];
    const int tid = threadIdx.x;
    const int tr = tid >> 4, tc = tid & 15;
    const int m0 = blockIdx.y * 128, n0 = blockIdx.x * 128;
    const int bofs = (b0 + blockIdx.z) * NP;
    const float* xb = x + (size_t)bofs * ldx;
    float acc[8][8] = {};
    for (int k0 = 0; k0 < KTOT; k0 += KC) {
        __syncthreads();
        stage_tile<KC>(xb, ldx, m0, k0, As);
        stage_tile<KC>(xb, ldx, n0, k0, Bs);
        __syncthreads();
        #pragma unroll 4
        for (int k = 0; k < KC; ++k) {
            float a[8], bv[8];
            #pragma unroll
            for (int i = 0; i < 8; ++i) a[i] = As[(tr + 16 * i) * LP + k];
            #pragma unroll
            for (int j = 0; j < 8; ++j) bv[j] = Bs[(tc + 16 * j) * LP + k];
            #pragma unroll
            for (int i = 0; i < 8; ++i)
                #pragma unroll
                for (int j = 0; j < 8; ++j)
                    acc[i][j] += a[i] * bv[j];
        }
    }
    float sa[8], sb[8];
    #pragma unroll
    for (int i = 0; i < 8; ++i) sa[i] = sq[bofs + m0 + tr + 16 * i];
    #pragma unroll
    for (int j = 0; j < 8; ++j) sb[j] = sq[bofs + n0 + tc + 16 * j];
    #pragma unroll
    for (int i = 0; i < 8; ++i) {
        unsigned* kr = keys + ((size_t)blockIdx.z * NP + m0 + tr + 16 * i) * NP + n0;
        #pragma unroll
        for (int j = 0; j < 8; ++j) {
            float d = sa[i] + sb[j] - 2.f * acc[i][j];
            unsigned bits = __float_as_uint(d);
            kr[tc + 16 * j] = (bits & 0x80000000u) ? ~bits : (bits | 0x80000000u);
        }
    }
}

// ---------------- kNN select: ballot binary search, wave per query ----------------
__global__ __launch_bounds__(256) void knn_select_kernel(const unsigned* __restrict__ keys,
                                                         int b0,
                                                         int* __restrict__ idx_out) {
    const int tid = threadIdx.x;
    const int w = tid >> 6, lane = tid & 63;
    const int ql = blockIdx.x * 4 + w;        // chunk-local query
    const int bc = ql / NP;
    const int b = b0 + bc;
    const int bofs = b * NP;
    const unsigned* kr = keys + (size_t)ql * NP;

    unsigned keysr[32];
    #pragma unroll
    for (int u = 0; u < 32; ++u) keysr[u] = kr[u * 64 + lane];

    unsigned lmn = 0xFFFFFFFFu;
    #pragma unroll
    for (int u = 0; u < 32; ++u) lmn = min(lmn, keysr[u]);
    unsigned M = lmn, lo = lmn;
    #pragma unroll
    for (int off = 1; off < 64; off <<= 1) {
        unsigned tM = __shfl_xor(M, off);
        unsigned tl = __shfl_xor(lo, off);
        M = max(M, tM);
        lo = min(lo, tl);
    }
    unsigned hi = M;
    while (lo < hi) {
        unsigned mid = lo + ((hi - lo) >> 1);
        int cnt = 0;
        #pragma unroll
        for (int u = 0; u < 32; ++u)
            cnt += __popcll(__ballot(keysr[u] <= mid));
        if (cnt >= KK) hi = mid; else lo = mid + 1;
    }
    const unsigned T = lo;

    unsigned nl = 0;
    #pragma unroll
    for (int u = 0; u < 32; ++u) nl += (keysr[u] < T) ? 1u : 0u;
    unsigned sc2 = nl;
    #pragma unroll
    for (int off = 1; off < 64; off <<= 1) {
        unsigned t = __shfl_up(sc2, off);
        if (lane >= off) sc2 += t;
    }
    unsigned cstrict = __shfl(sc2, 63);
    unsigned o = sc2 - nl;
    int* op = idx_out + (size_t)(bofs + (ql - bc * NP)) * KK;
    #pragma unroll
    for (int u = 0; u < 32; ++u) {
        if (keysr[u] < T) { op[o] = bofs + u * 64 + lane; ++o; }
    }
    int rem = KK - (int)cstrict;
    int ebase = (int)cstrict;
    #pragma unroll
    for (int u = 0; u < 32; ++u) {
        if (rem > 0) {
            bool eq = (keysr[u] == T);
            unsigned long long bm = __ballot(eq);
            int before = __popcll(bm & ((1ull << lane) - 1ull));
            if (eq && before < rem) op[ebase + before] = bofs + u * 64 + lane;
            int take = __popcll(bm);
            if (take > rem) take = rem;
            ebase += take;
            rem -= take;
        }
    }
}

// ---------------- Wt[c][j] build: [Wd | Wtail] transposed, zero-padded ----------------
__global__ __launch_bounds__(256) void wt_build_kernel(const float* __restrict__ W,
                                                       float* __restrict__ Wt,
                                                       int D, int Dp, int C) {
    int i = blockIdx.x * 256 + threadIdx.x;
    if (i < 2 * C * Dp) {
        int c = i / Dp, j = i % Dp;
        float v = 0.f;
        if (j < D) {
            v = (c < C) ? (W[j * C + c] - W[(D + j) * C + c])
                        : W[(D + j) * C + (c - C)];
        }
        Wt[i] = v;
    }
}

// ---------------- X[TOT,Dp] @ Wt^T -> basexw[TOT,2C] ----------------
template <int NJ4, int C2>
__global__ __launch_bounds__(256) void xw_gemm_kernel(const float* __restrict__ x, int ldx,
                                                      const float* __restrict__ Wt,
                                                      float* __restrict__ bx) {
    constexpr int PG = 256 / C2;   // point groups
    constexpr int PTS = 16 / PG;   // points per thread
    __shared__ float4 Xs[16][NJ4];
    const int tid = threadIdx.x;
    const int p0 = blockIdx.x * 16;
    for (int i = tid; i < 16 * NJ4; i += 256) {
        int r = i / NJ4, j4 = i % NJ4;
        Xs[r][j4] = *reinterpret_cast<const float4*>(x + (size_t)(p0 + r) * ldx + j4 * 4);
    }
    __syncthreads();
    const int c = tid % C2, pg = tid / C2;
    const float4* wrow = reinterpret_cast<const float4*>(Wt + (size_t)c * (NJ4 * 4));
    float acc[PTS];
    #pragma unroll
    for (int u = 0; u < PTS; ++u) acc[u] = 0.f;
    #pragma unroll
    for (int j4 = 0; j4 < NJ4; ++j4) {
        float4 w4 = wrow[j4];
        #pragma unroll
        for (int u = 0; u < PTS; ++u) {
            float4 x4 = Xs[pg * PTS + u][j4];
            acc[u] += x4.x * w4.x + x4.y * w4.y + x4.z * w4.z + x4.w * w4.w;
        }
    }
    #pragma unroll
    for (int u = 0; u < PTS; ++u)
        bx[(size_t)(p0 + pg * PTS + u) * C2 + c] = acc[u];
}

// ---------------- edge pass: gather XW, stats + per-point max/min ----------------
template <int C>
__global__ __launch_bounds__(256) void edge_pass_kernel(const float* __restrict__ bx,
                                                        const int* __restrict__ idx,
                                                        float* __restrict__ psum,
                                                        float* __restrict__ psum2,
                                                        float* __restrict__ mmax,
                                                        float* __restrict__ mmin) {
    constexpr int PT = 256 / C;
    constexpr int C2 = 2 * C;
    __shared__ int sidx[PT][KK];
    __shared__ float red[256];
    const int tid = threadIdx.x;
    const int c = tid % C;
    const int pl = tid / C;
    float s1 = 0.f, s2 = 0.f;
    const int NT = TOT / PT;
    for (int t = blockIdx.x; t < NT; t += EBLK) {
        const int p0 = t * PT;
        __syncthreads();
        if (tid < PT * KK) sidx[tid / KK][tid % KK] = idx[(size_t)p0 * KK + tid];
        __syncthreads();
        const int p = p0 + pl;
        const float bv = bx[(size_t)p * C2 + c];
        float A = 0.f, Q = 0.f, M = -FLT_MAX, mn = FLT_MAX;
        #pragma unroll
        for (int k = 0; k < KK; ++k) {
            float v = bx[(size_t)sidx[pl][k] * C2 + C + c];
            A += v; Q += v * v; M = fmaxf(M, v); mn = fminf(mn, v);
        }
        s1 += (float)KK * bv + A;
        s2 += (float)KK * bv * bv + 2.f * bv * A + Q;
        mmax[(size_t)p * C + c] = bv + M;
        mmin[(size_t)p * C + c] = bv + mn;
    }
    red[tid] = s1;
    __syncthreads();
    if (tid < C) {
        float v = red[tid];
        #pragma unroll
        for (int u = 1; u < PT; ++u) v += red[tid + u * C];
        psum[(size_t)blockIdx.x * C + tid] = v;
    }
    __syncthreads();
    red[tid] = s2;
    __syncthreads();
    if (tid < C) {
        float v = red[tid];
        #pragma unroll
        for (int u = 1; u < PT; ++u) v += red[tid + u * C];
        psum2[(size_t)blockIdx.x * C + tid] = v;
    }
}

// ---------------- BN stats reduce -> alpha/beta ----------------
__global__ __launch_bounds__(256) void bn_reduce_kernel(
        const float* __restrict__ psum, const float* __restrict__ psum2,
        int npart, int C, const float* __restrict__ g, const float* __restrict__ bb,
        float inv_cnt, float* __restrict__ alpha, float* __restrict__ beta) {
    const int c = blockIdx.x;
    const int tid = threadIdx.x;
    __shared__ float r1[256], r2[256];
    float s1 = 0.f, s2 = 0.f;
    for (int i = tid; i < npart; i += 256) {
        s1 += psum[(size_t)i * C + c];
        s2 += psum2[(size_t)i * C + c];
    }
    r1[tid] = s1; r2[tid] = s2;
    __syncthreads();
    for (int s = 128; s > 0; s >>= 1) {
        if (tid < s) { r1[tid] += r1[tid + s]; r2[tid] += r2[tid + s]; }
        __syncthreads();
    }
    if (tid == 0) {
        float mean = r1[0] * inv_cnt;
        float var = r2[0] * inv_cnt - mean * mean;
        float a = g[c] * rsqrtf(var + 1e-5f);
        alpha[c] = a;
        beta[c] = bb[c] - mean * a;
    }
}

// ---------------- edge finalize: pick max/min by sign(alpha), affine+leaky ----------------
template <int C>
__global__ __launch_bounds__(256) void edge_finalize_kernel(const float* __restrict__ mmax,
                                                            const float* __restrict__ mmin,
                                                            const float* __restrict__ alpha,
                                                            const float* __restrict__ beta,
                                                            float* __restrict__ xc_slice) {
    constexpr int CQ = C / 4;
    int i4 = blockIdx.x * 256 + threadIdx.x;
    if (i4 < TOT * CQ) {
        int p = i4 / CQ, cq = i4 - p * CQ;
        float4 M4 = reinterpret_cast<const float4*>(mmax)[i4];
        float4 m4 = reinterpret_cast<const float4*>(mmin)[i4];
        float4 a4 = reinterpret_cast<const float4*>(alpha)[cq];
        float4 b4 = reinterpret_cast<const float4*>(beta)[cq];
        float4 o;
        o.x = leaky(a4.x * (a4.x >= 0.f ? M4.x : m4.x) + b4.x);
        o.y = leaky(a4.y * (a4.y >= 0.f ? M4.y : m4.y) + b4.y);
        o.z = leaky(a4.z * (a4.z >= 0.f ? M4.z : m4.z) + b4.z);
        o.w = leaky(a4.w * (a4.w >= 0.f ? M4.w : m4.w) + b4.w);
        *reinterpret_cast<float4*>(xc_slice + (size_t)p * 256 + cq * 4) = o;
    }
}

// ---------------- Wf transpose: [256][1024] -> [1024][256] ----------------
__global__ __launch_bounds__(256) void wft_build_kernel(const float* __restrict__ Wf,
                                                        float* __restrict__ Wft) {
    int i = blockIdx.x * 256 + threadIdx.x;
    if (i < 256 * 1024) {
        int e = i / 1024, o = i - e * 1024;
        Wft[(size_t)o * 256 + e] = Wf[i];
    }
}

// ---------------- conv_final GEMM (128x128 tile, 8x8/thread) + stat partials ----------------
__global__ __launch_bounds__(256, 4) void fc_gemm_kernel(const float* __restrict__ xc,
                                                         const float* __restrict__ Wft,
                                                         float* __restrict__ psum,
                                                         float* __restrict__ psum2,
                                                         float* __restrict__ pmax,
                                                         float* __restrict__ pmin) {
    constexpr int KC = 32, LP = KC + 1;
    __shared__ float As[128 * LP];
    __shared__ float Bs[128 * LP];
    const int tid = threadIdx.x;
    const int tr = tid >> 4, tc = tid & 15;
    const int pt = blockIdx.x;    // point tile (0..255)
    const int ct = blockIdx.y;    // channel tile (0..7)
    float acc[8][8] = {};
    for (int k0 = 0; k0 < 256; k0 += KC) {
        __syncthreads();
        stage_tile<KC>(xc, 256, pt * 128, k0, As);
        stage_tile<KC>(Wft, 256, ct * 128, k0, Bs);
        __syncthreads();
        #pragma unroll 4
        for (int k = 0; k < KC; ++k) {
            float a[8], bv[8];
            #pragma unroll
            for (int i = 0; i < 8; ++i) a[i] = As[(tr + 16 * i) * LP + k];
            #pragma unroll
            for (int j = 0; j < 8; ++j) bv[j] = Bs[(tc + 16 * j) * LP + k];
            #pragma unroll
            for (int i = 0; i < 8; ++i)
                #pragma unroll
                for (int j = 0; j < 8; ++j)
                    acc[i][j] += a[i] * bv[j];
        }
    }
    // per-thread partials over its 8 points for each of its 8 channels
    float s1p[8] = {}, s2p[8] = {}, mxp[8], mnp[8];
    #pragma unroll
    for (int j = 0; j < 8; ++j) { mxp[j] = -FLT_MAX; mnp[j] = FLT_MAX; }
    #pragma unroll
    for (int i = 0; i < 8; ++i)
        #pragma unroll
        for (int j = 0; j < 8; ++j) {
            float v = acc[i][j];
            s1p[j] += v; s2p[j] += v * v;
            mxp[j] = fmaxf(mxp[j], v); mnp[j] = fminf(mnp[j], v);
        }
    // reduce over the 16 tr-threads per channel; reuse As as [16][128]
    float* red = As;
    __syncthreads();
    const size_t go = (size_t)pt * 1024 + ct * 128;
    #pragma unroll
    for (int j = 0; j < 8; ++j) red[tr * 128 + tc + 16 * j] = s1p[j];
    __syncthreads();
    if (tid < 128) {
        float v = red[tid];
        for (int t = 1; t < 16; ++t) v += red[t * 128 + tid];
        psum[go + tid] = v;
    }
    __syncthreads();
    #pragma unroll
    for (int j = 0; j < 8; ++j) red[tr * 128 + tc + 16 * j] = s2p[j];
    __syncthreads();
    if (tid < 128) {
        float v = red[tid];
        for (int t = 1; t < 16; ++t) v += red[t * 128 + tid];
        psum2[go + tid] = v;
    }
    __syncthreads();
    #pragma unroll
    for (int j = 0; j < 8; ++j) red[tr * 128 + tc + 16 * j] = mxp[j];
    __syncthreads();
    if (tid < 128) {
        float v = red[tid];
        for (int t = 1; t < 16; ++t) v = fmaxf(v, red[t * 128 + tid]);
        pmax[go + tid] = v;
    }
    __syncthreads();
    #pragma unroll
    for (int j = 0; j < 8; ++j) red[tr * 128 + tc + 16 * j] = mnp[j];
    __syncthreads();
    if (tid < 128) {
        float v = red[tid];
        for (int t = 1; t < 16; ++t) v = fminf(v, red[t * 128 + tid]);
        pmin[go + tid] = v;
    }
}

// ---------------- gfeat finalize (16 point-tile partials per batch) ----------------
__global__ __launch_bounds__(256) void gfeat_final_kernel(const float* __restrict__ pmax,
                                                          const float* __restrict__ pmin,
                                                          const float* __restrict__ alpha,
                                                          const float* __restrict__ beta,
                                                          float* __restrict__ gfeat) {
    int i = blockIdx.x * 256 + threadIdx.x;
    if (i < NB * 1024) {
        int b = i >> 10, c = i & 1023;
        float mx = -FLT_MAX, mn = FLT_MAX;
        for (int j = 0; j < 16; ++j) {
            size_t o = (size_t)(b * 16 + j) * 1024 + c;
            mx = fmaxf(mx, pmax[o]);
            mn = fminf(mn, pmin[o]);
        }
        float a = alpha[c];
        gfeat[i] = leaky(a * (a >= 0.f ? mx : mn) + beta[c]);
    }
}

// ---------------- tiny classifier ----------------
__global__ __launch_bounds__(256) void gemm_small(const float* __restrict__ A,
                                                  const float* __restrict__ W,
                                                  const float* __restrict__ bias,
                                                  float* __restrict__ out,
                                                  int M, int Kd, int Nd) {
    int i = blockIdx.x * 256 + threadIdx.x;
    if (i < M * Nd) {
        int m = i / Nd, c = i - m * Nd;
        float s = bias[c];
        const float* a = A + (size_t)m * Kd;
        for (int e = 0; e < Kd; ++e) s += a[e] * W[(size_t)e * Nd + c];
        out[i] = s;
    }
}

__global__ __launch_bounds__(256) void bn_rows_kernel(const float* __restrict__ z,
                                                      const float* __restrict__ g,
                                                      const float* __restrict__ bb,
                                                      float* __restrict__ out, int C) {
    int c = blockIdx.x * 256 + threadIdx.x;
    if (c < C) {
        float s = 0.f, s2 = 0.f;
        for (int b = 0; b < NB; ++b) {
            float v = z[(size_t)b * C + c];
            s += v; s2 += v * v;
        }
        float mean = s * (1.f / NB);
        float var = s2 * (1.f / NB) - mean * mean;
        float a = g[c] * rsqrtf(var + 1e-5f);
        float be = bb[c] - mean * a;
        for (int b = 0; b < NB; ++b) {
            float v = a * z[(size_t)b * C + c] + be;
            out[(size_t)b * C + c] = leaky(v);
        }
    }
}

static void run_knn(const float* x, int ldx, int nk, const float* sq, unsigned* keys,
                    int CB, int* idx, hipStream_t stream) {
    for (int b0 = 0; b0 < NB; b0 += CB) {
        dim3 g(NP / 128, NP / 128, CB);
        if (nk == 4)
            dist_gemm_kernel<4><<<g, 256, 0, stream>>>(x, ldx, sq, b0, keys);
        else
            dist_gemm_kernel<64><<<g, 256, 0, stream>>>(x, ldx, sq, b0, keys);
        knn_select_kernel<<<CB * NP / 4, 256, 0, stream>>>(keys, b0, idx);
    }
}

} // namespace

extern "C" void kernel_launch(void* const* d_in, const int* in_sizes, int n_in,
                              void* d_out, int out_size, void* d_ws, size_t ws_size,
                              hipStream_t stream) {
    (void)in_sizes; (void)n_in; (void)out_size;
    const float* pos = (const float*)d_in[0];
    const float* W1  = (const float*)d_in[1];
    const float* g1  = (const float*)d_in[2];
    const float* b1  = (const float*)d_in[3];
    const float* W2  = (const float*)d_in[4];
    const float* g2  = (const float*)d_in[5];
    const float* b2  = (const float*)d_in[6];
    const float* W3  = (const float*)d_in[7];
    const float* g3  = (const float*)d_in[8];
    const float* b3  = (const float*)d_in[9];
    const float* Wf  = (const float*)d_in[10];
    const float* gf  = (const float*)d_in[11];
    const float* bf  = (const float*)d_in[12];
    const float* W4  = (const float*)d_in[13];
    const float* b4  = (const float*)d_in[14];
    const float* g4  = (const float*)d_in[15];
    const float* be4 = (const float*)d_in[16];
    const float* W5  = (const float*)d_in[17];
    const float* b5  = (const float*)d_in[18];
    const float* g5  = (const float*)d_in[19];
    const float* be5 = (const float*)d_in[20];
    const float* W6  = (const float*)d_in[21];
    const float* b6  = (const float*)d_in[22];
    float* out = (float*)d_out;

    float* ws = (float*)d_ws;
    size_t off = 0;
    int*   idx    = (int*)ws;      off += (size_t)TOT * KK;          // 2.6 MB
    float* pos4   = ws + off;      off += (size_t)TOT * 4;
    float* sq     = ws + off;      off += (size_t)TOT;
    float* Wt     = ws + off;      off += 256 * 64;
    float* Wft    = ws + off;      off += 1024 * 256;                // 1 MB
    float* basexw = ws + off;      off += (size_t)TOT * 256;         // 32 MB
    float* mmax   = ws + off;      off += (size_t)TOT * 128;         // 16 MB
    float* mmin   = ws + off;      off += (size_t)TOT * 128;         // 16 MB
    float* xc     = ws + off;      off += (size_t)TOT * 256;         // 32 MB
    float* psum   = ws + off;      off += (size_t)512 * 1024;        // 2 MB
    float* psum2  = ws + off;      off += (size_t)512 * 1024;
    float* pmax   = ws + off;      off += (size_t)512 * 1024;
    float* pmin   = ws + off;      off += (size_t)512 * 1024;
    float* alpha  = ws + off;      off += 1024;
    float* beta   = ws + off;      off += 1024;
    float* gfeat  = ws + off;      off += NB * 1024;
    float* z4     = ws + off;      off += NB * 512;
    float* h4     = ws + off;      off += NB * 512;
    float* z5     = ws + off;      off += NB * 256;
    float* h5     = ws + off;      off += NB * 256;
    unsigned* keys = (unsigned*)(ws + off);
    const size_t avail = (ws_size > off * 4) ? (ws_size - off * 4) : 0;
    const size_t per_batch = (size_t)NP * NP * 4;
    int CB = 1;
    for (int cb : {16, 8, 4, 2}) {
        if ((size_t)cb * per_batch <= avail) { CB = cb; break; }
    }

    const int npts_blk = (TOT + 255) / 256;

    // ---------- Layer 1 (D=3 padded to 4, C=64) ----------
    pos4_kernel<<<npts_blk, 256, 0, stream>>>(pos, pos4);
    sq4_kernel<<<npts_blk, 256, 0, stream>>>(pos4, 4, 1, sq);
    run_knn(pos4, 4, 4, sq, keys, CB, idx, stream);
    wt_build_kernel<<<2, 256, 0, stream>>>(W1, Wt, 3, 4, 64);
    xw_gemm_kernel<1, 128><<<TOT / 16, 256, 0, stream>>>(pos4, 4, Wt, basexw);
    edge_pass_kernel<64><<<EBLK, 256, 0, stream>>>(basexw, idx, psum, psum2, mmax, mmin);
    bn_reduce_kernel<<<64, 256, 0, stream>>>(psum, psum2, EBLK, 64, g1, b1,
                                             1.f / (float)(TOT * KK), alpha, beta);
    edge_finalize_kernel<64><<<TOT * 16 / 256, 256, 0, stream>>>(mmax, mmin, alpha, beta, xc + 0);

    // ---------- Layer 2 (D=64, C=64), input x1 = xc[:,0:64] ----------
    sq4_kernel<<<npts_blk, 256, 0, stream>>>(xc + 0, 256, 16, sq);
    run_knn(xc + 0, 256, 64, sq, keys, CB, idx, stream);
    wt_build_kernel<<<32, 256, 0, stream>>>(W2, Wt, 64, 64, 64);
    xw_gemm_kernel<16, 128><<<TOT / 16, 256, 0, stream>>>(xc + 0, 256, Wt, basexw);
    edge_pass_kernel<64><<<EBLK, 256, 0, stream>>>(basexw, idx, psum, psum2, mmax, mmin);
    bn_reduce_kernel<<<64, 256, 0, stream>>>(psum, psum2, EBLK, 64, g2, b2,
                                             1.f / (float)(TOT * KK), alpha, beta);
    edge_finalize_kernel<64><<<TOT * 16 / 256, 256, 0, stream>>>(mmax, mmin, alpha, beta, xc + 64);

    // ---------- Layer 3 (D=64, C=128), input x2 = xc[:,64:128] ----------
    sq4_kernel<<<npts_blk, 256, 0, stream>>>(xc + 64, 256, 16, sq);
    run_knn(xc + 64, 256, 64, sq, keys, CB, idx, stream);
    wt_build_kernel<<<64, 256, 0, stream>>>(W3, Wt, 64, 64, 128);
    xw_gemm_kernel<16, 256><<<TOT / 16, 256, 0, stream>>>(xc + 64, 256, Wt, basexw);
    edge_pass_kernel<128><<<EBLK, 256, 0, stream>>>(basexw, idx, psum, psum2, mmax, mmin);
    bn_reduce_kernel<<<128, 256, 0, stream>>>(psum, psum2, EBLK, 128, g3, b3,
                                              1.f / (float)(TOT * KK), alpha, beta);
    edge_finalize_kernel<128><<<TOT * 32 / 256, 256, 0, stream>>>(mmax, mmin, alpha, beta, xc + 128);

    // ---------- conv_final + global max pool ----------
    wft_build_kernel<<<1024, 256, 0, stream>>>(Wf, Wft);
    {
        dim3 g(TOT / 128, 1024 / 128, 1);
        fc_gemm_kernel<<<g, 256, 0, stream>>>(xc, Wft, psum, psum2, pmax, pmin);
    }
    bn_reduce_kernel<<<1024, 256, 0, stream>>>(psum, psum2, 256, 1024, gf, bf,
                                               1.f / (float)TOT, alpha, beta);
    gfeat_final_kernel<<<64, 256, 0, stream>>>(pmax, pmin, alpha, beta, gfeat);

    // ---------- classifier ----------
    gemm_small<<<(NB * 512 + 255) / 256, 256, 0, stream>>>(gfeat, W4, b4, z4, NB, 1024, 512);
    bn_rows_kernel<<<2, 256, 0, stream>>>(z4, g4, be4, h4, 512);
    gemm_small<<<(NB * 256 + 255) / 256, 256, 0, stream>>>(h4, W5, b5, z5, NB, 512, 256);
    bn_rows_kernel<<<1, 256, 0, stream>>>(z5, g5, be5, h5, 256);
    gemm_small<<<(NB * 40 + 255) / 256, 256, 0, stream>>>(h5, W6, b6, out, NB, 256, 40);
}

// Round 6
// 1438.078 us; speedup vs baseline: 3.3769x; 1.3545x over previous
//
#include <hip/hip_runtime.h>
#include <float.h>
#include <math.h>

namespace {

constexpr int NB = 16;
constexpr int NP = 2048;
constexpr int KK = 20;
constexpr int TOT = NB * NP;   // 32768
constexpr int EBLK = 1024;     // edge pass grid

__device__ __forceinline__ float leaky(float v) { return fmaxf(v, 0.2f * v); }

// ---------------- pos -> pos4 (pad to 4 comps) ----------------
__global__ __launch_bounds__(256) void pos4_kernel(const float* __restrict__ pos,
                                                   float* __restrict__ pos4) {
    int i = blockIdx.x * 256 + threadIdx.x;
    if (i < TOT) {
        pos4[i * 4 + 0] = pos[i * 3 + 0];
        pos4[i * 4 + 1] = pos[i * 3 + 1];
        pos4[i * 4 + 2] = pos[i * 3 + 2];
        pos4[i * 4 + 3] = 0.f;
    }
}

// ---------------- squared norms (float4 rows) ----------------
__global__ __launch_bounds__(256) void sq4_kernel(const float* __restrict__ x, int ldx, int nj4,
                                                  float* __restrict__ sq) {
    int i = blockIdx.x * 256 + threadIdx.x;
    if (i < TOT) {
        const float4* r = reinterpret_cast<const float4*>(x + (size_t)i * ldx);
        float s = 0.f;
        for (int j4 = 0; j4 < nj4; ++j4) {
            float4 v = r[j4];
            s += v.x * v.x + v.y * v.y + v.z * v.z + v.w * v.w;
        }
        sq[i] = s;
    }
}

// ---------------- shared GEMM tile staging: 128 rows x KC floats, pad KC+1 ----------------
template <int KC>
__device__ __forceinline__ void stage_tile(const float* __restrict__ src, int ldx,
                                           int row0, int k0, float* __restrict__ dst) {
    constexpr int F4 = KC / 4;
    const int tid = threadIdx.x;
    #pragma unroll
    for (int i = tid; i < 128 * F4; i += 256) {
        const int r = i / F4, c4 = i % F4;
        float4 v = *reinterpret_cast<const float4*>(src + (size_t)(row0 + r) * ldx + k0 + c4 * 4);
        float* d = dst + r * (KC + 1) + c4 * 4;
        d[0] = v.x; d[1] = v.y; d[2] = v.z; d[3] = v.w;
    }
}

// ---------------- distance GEMM -> monotone uint keys ----------------
// 128x128 tile, 8x8/thread (interleaved cols: r=tr+16i, c=tc+16j), K-chunk 32.
template <int KTOT>
__global__ __launch_bounds__(256, 4) void dist_gemm_kernel(const float* __restrict__ x, int ldx,
                                                           const float* __restrict__ sq,
                                                           int b0,
                                                           unsigned* __restrict__ keys) {
    constexpr int KC = (KTOT < 32) ? KTOT : 32;
    constexpr int LP = KC + 1;
    __shared__ float As[128 * LP];
    __shared__ float Bs[128 * LP];
    const int tid = threadIdx.x;
    const int tr = tid >> 4, tc = tid & 15;
    const int m0 = blockIdx.y * 128, n0 = blockIdx.x * 128;
    const int bofs = (b0 + blockIdx.z) * NP;
    const float* xb = x + (size_t)bofs * ldx;
    float acc[8][8] = {};
    for (int k0 = 0; k0 < KTOT; k0 += KC) {
        __syncthreads();
        stage_tile<KC>(xb, ldx, m0, k0, As);
        stage_tile<KC>(xb, ldx, n0, k0, Bs);
        __syncthreads();
        #pragma unroll 4
        for (int k = 0; k < KC; ++k) {
            float a[8], bv[8];
            #pragma unroll
            for (int i = 0; i < 8; ++i) a[i] = As[(tr + 16 * i) * LP + k];
            #pragma unroll
            for (int j = 0; j < 8; ++j) bv[j] = Bs[(tc + 16 * j) * LP + k];
            #pragma unroll
            for (int i = 0; i < 8; ++i)
                #pragma unroll
                for (int j = 0; j < 8; ++j)
                    acc[i][j] += a[i] * bv[j];
        }
    }
    float sa[8], sb[8];
    #pragma unroll
    for (int i = 0; i < 8; ++i) sa[i] = sq[bofs + m0 + tr + 16 * i];
    #pragma unroll
    for (int j = 0; j < 8; ++j) sb[j] = sq[bofs + n0 + tc + 16 * j];
    #pragma unroll
    for (int i = 0; i < 8; ++i) {
        unsigned* kr = keys + ((size_t)blockIdx.z * NP + m0 + tr + 16 * i) * NP + n0;
        #pragma unroll
        for (int j = 0; j < 8; ++j) {
            float d = sa[i] + sb[j] - 2.f * acc[i][j];
            unsigned bits = __float_as_uint(d);
            kr[tc + 16 * j] = (bits & 0x80000000u) ? ~bits : (bits | 0x80000000u);
        }
    }
}

// ---------------- kNN select: ballot binary search, wave per query ----------------
__global__ __launch_bounds__(256) void knn_select_kernel(const unsigned* __restrict__ keys,
                                                         int b0,
                                                         int* __restrict__ idx_out) {
    const int tid = threadIdx.x;
    const int w = tid >> 6, lane = tid & 63;
    const int ql = blockIdx.x * 4 + w;        // chunk-local query
    const int bc = ql / NP;
    const int b = b0 + bc;
    const int bofs = b * NP;
    const unsigned* kr = keys + (size_t)ql * NP;

    unsigned keysr[32];
    #pragma unroll
    for (int u = 0; u < 32; ++u) keysr[u] = kr[u * 64 + lane];

    unsigned lmn = 0xFFFFFFFFu;
    #pragma unroll
    for (int u = 0; u < 32; ++u) lmn = min(lmn, keysr[u]);
    unsigned M = lmn, lo = lmn;
    #pragma unroll
    for (int off = 1; off < 64; off <<= 1) {
        unsigned tM = __shfl_xor(M, off);
        unsigned tl = __shfl_xor(lo, off);
        M = max(M, tM);
        lo = min(lo, tl);
    }
    unsigned hi = M;
    while (lo < hi) {
        unsigned mid = lo + ((hi - lo) >> 1);
        int cnt = 0;
        #pragma unroll
        for (int u = 0; u < 32; ++u)
            cnt += __popcll(__ballot(keysr[u] <= mid));
        if (cnt >= KK) hi = mid; else lo = mid + 1;
    }
    const unsigned T = lo;

    unsigned nl = 0;
    #pragma unroll
    for (int u = 0; u < 32; ++u) nl += (keysr[u] < T) ? 1u : 0u;
    unsigned sc2 = nl;
    #pragma unroll
    for (int off = 1; off < 64; off <<= 1) {
        unsigned t = __shfl_up(sc2, off);
        if (lane >= off) sc2 += t;
    }
    unsigned cstrict = __shfl(sc2, 63);
    unsigned o = sc2 - nl;
    int* op = idx_out + (size_t)(bofs + (ql - bc * NP)) * KK;
    #pragma unroll
    for (int u = 0; u < 32; ++u) {
        if (keysr[u] < T) { op[o] = bofs + u * 64 + lane; ++o; }
    }
    int rem = KK - (int)cstrict;
    int ebase = (int)cstrict;
    #pragma unroll
    for (int u = 0; u < 32; ++u) {
        if (rem > 0) {
            bool eq = (keysr[u] == T);
            unsigned long long bm = __ballot(eq);
            int before = __popcll(bm & ((1ull << lane) - 1ull));
            if (eq && before < rem) op[ebase + before] = bofs + u * 64 + lane;
            int take = __popcll(bm);
            if (take > rem) take = rem;
            ebase += take;
            rem -= take;
        }
    }
}

// ---------------- Wt[c][j] build: [Wd | Wtail] transposed, zero-padded ----------------
__global__ __launch_bounds__(256) void wt_build_kernel(const float* __restrict__ W,
                                                       float* __restrict__ Wt,
                                                       int D, int Dp, int C) {
    int i = blockIdx.x * 256 + threadIdx.x;
    if (i < 2 * C * Dp) {
        int c = i / Dp, j = i % Dp;
        float v = 0.f;
        if (j < D) {
            v = (c < C) ? (W[j * C + c] - W[(D + j) * C + c])
                        : W[(D + j) * C + (c - C)];
        }
        Wt[i] = v;
    }
}

// ---------------- X[TOT,Dp] @ Wt^T -> basexw[TOT,2C] ----------------
template <int NJ4, int C2>
__global__ __launch_bounds__(256) void xw_gemm_kernel(const float* __restrict__ x, int ldx,
                                                      const float* __restrict__ Wt,
                                                      float* __restrict__ bx) {
    constexpr int PG = 256 / C2;   // point groups
    constexpr int PTS = 16 / PG;   // points per thread
    __shared__ float4 Xs[16][NJ4];
    const int tid = threadIdx.x;
    const int p0 = blockIdx.x * 16;
    for (int i = tid; i < 16 * NJ4; i += 256) {
        int r = i / NJ4, j4 = i % NJ4;
        Xs[r][j4] = *reinterpret_cast<const float4*>(x + (size_t)(p0 + r) * ldx + j4 * 4);
    }
    __syncthreads();
    const int c = tid % C2, pg = tid / C2;
    const float4* wrow = reinterpret_cast<const float4*>(Wt + (size_t)c * (NJ4 * 4));
    float acc[PTS];
    #pragma unroll
    for (int u = 0; u < PTS; ++u) acc[u] = 0.f;
    #pragma unroll
    for (int j4 = 0; j4 < NJ4; ++j4) {
        float4 w4 = wrow[j4];
        #pragma unroll
        for (int u = 0; u < PTS; ++u) {
            float4 x4 = Xs[pg * PTS + u][j4];
            acc[u] += x4.x * w4.x + x4.y * w4.y + x4.z * w4.z + x4.w * w4.w;
        }
    }
    #pragma unroll
    for (int u = 0; u < PTS; ++u)
        bx[(size_t)(p0 + pg * PTS + u) * C2 + c] = acc[u];
}

// ---------------- edge pass: gather XW, stats + per-point max/min ----------------
template <int C>
__global__ __launch_bounds__(256) void edge_pass_kernel(const float* __restrict__ bx,
                                                        const int* __restrict__ idx,
                                                        float* __restrict__ psum,
                                                        float* __restrict__ psum2,
                                                        float* __restrict__ mmax,
                                                        float* __restrict__ mmin) {
    constexpr int PT = 256 / C;
    constexpr int C2 = 2 * C;
    __shared__ int sidx[PT][KK];
    __shared__ float red[256];
    const int tid = threadIdx.x;
    const int c = tid % C;
    const int pl = tid / C;
    float s1 = 0.f, s2 = 0.f;
    const int NT = TOT / PT;
    for (int t = blockIdx.x; t < NT; t += EBLK) {
        const int p0 = t * PT;
        __syncthreads();
        if (tid < PT * KK) sidx[tid / KK][tid % KK] = idx[(size_t)p0 * KK + tid];
        __syncthreads();
        const int p = p0 + pl;
        const float bv = bx[(size_t)p * C2 + c];
        float A = 0.f, Q = 0.f, M = -FLT_MAX, mn = FLT_MAX;
        #pragma unroll
        for (int k = 0; k < KK; ++k) {
            float v = bx[(size_t)sidx[pl][k] * C2 + C + c];
            A += v; Q += v * v; M = fmaxf(M, v); mn = fminf(mn, v);
        }
        s1 += (float)KK * bv + A;
        s2 += (float)KK * bv * bv + 2.f * bv * A + Q;
        mmax[(size_t)p * C + c] = bv + M;
        mmin[(size_t)p * C + c] = bv + mn;
    }
    red[tid] = s1;
    __syncthreads();
    if (tid < C) {
        float v = red[tid];
        #pragma unroll
        for (int u = 1; u < PT; ++u) v += red[tid + u * C];
        psum[(size_t)blockIdx.x * C + tid] = v;
    }
    __syncthreads();
    red[tid] = s2;
    __syncthreads();
    if (tid < C) {
        float v = red[tid];
        #pragma unroll
        for (int u = 1; u < PT; ++u) v += red[tid + u * C];
        psum2[(size_t)blockIdx.x * C + tid] = v;
    }
}

// ---------------- BN stats reduce -> alpha/beta ----------------
__global__ __launch_bounds__(256) void bn_reduce_kernel(
        const float* __restrict__ psum, const float* __restrict__ psum2,
        int npart, int C, const float* __restrict__ g, const float* __restrict__ bb,
        float inv_cnt, float* __restrict__ alpha, float* __restrict__ beta) {
    const int c = blockIdx.x;
    const int tid = threadIdx.x;
    __shared__ float r1[256], r2[256];
    float s1 = 0.f, s2 = 0.f;
    for (int i = tid; i < npart; i += 256) {
        s1 += psum[(size_t)i * C + c];
        s2 += psum2[(size_t)i * C + c];
    }
    r1[tid] = s1; r2[tid] = s2;
    __syncthreads();
    for (int s = 128; s > 0; s >>= 1) {
        if (tid < s) { r1[tid] += r1[tid + s]; r2[tid] += r2[tid + s]; }
        __syncthreads();
    }
    if (tid == 0) {
        float mean = r1[0] * inv_cnt;
        float var = r2[0] * inv_cnt - mean * mean;
        float a = g[c] * rsqrtf(var + 1e-5f);
        alpha[c] = a;
        beta[c] = bb[c] - mean * a;
    }
}

// ---------------- edge finalize: pick max/min by sign(alpha), affine+leaky ----------------
template <int C>
__global__ __launch_bounds__(256) void edge_finalize_kernel(const float* __restrict__ mmax,
                                                            const float* __restrict__ mmin,
                                                            const float* __restrict__ alpha,
                                                            const float* __restrict__ beta,
                                                            float* __restrict__ xc_slice) {
    constexpr int CQ = C / 4;
    int i4 = blockIdx.x * 256 + threadIdx.x;
    if (i4 < TOT * CQ) {
        int p = i4 / CQ, cq = i4 - p * CQ;
        float4 M4 = reinterpret_cast<const float4*>(mmax)[i4];
        float4 m4 = reinterpret_cast<const float4*>(mmin)[i4];
        float4 a4 = reinterpret_cast<const float4*>(alpha)[cq];
        float4 b4 = reinterpret_cast<const float4*>(beta)[cq];
        float4 o;
        o.x = leaky(a4.x * (a4.x >= 0.f ? M4.x : m4.x) + b4.x);
        o.y = leaky(a4.y * (a4.y >= 0.f ? M4.y : m4.y) + b4.y);
        o.z = leaky(a4.z * (a4.z >= 0.f ? M4.z : m4.z) + b4.z);
        o.w = leaky(a4.w * (a4.w >= 0.f ? M4.w : m4.w) + b4.w);
        *reinterpret_cast<float4*>(xc_slice + (size_t)p * 256 + cq * 4) = o;
    }
}

// ---------------- Wf transpose: [256][1024] -> [1024][256] ----------------
__global__ __launch_bounds__(256) void wft_build_kernel(const float* __restrict__ Wf,
                                                        float* __restrict__ Wft) {
    int i = blockIdx.x * 256 + threadIdx.x;
    if (i < 256 * 1024) {
        int e = i / 1024, o = i - e * 1024;
        Wft[(size_t)o * 256 + e] = Wf[i];
    }
}

// ---------------- conv_final GEMM (128x128 tile, 8x8/thread) + stat partials ----------------
__global__ __launch_bounds__(256, 4) void fc_gemm_kernel(const float* __restrict__ xc,
                                                         const float* __restrict__ Wft,
                                                         float* __restrict__ psum,
                                                         float* __restrict__ psum2,
                                                         float* __restrict__ pmax,
                                                         float* __restrict__ pmin) {
    constexpr int KC = 32, LP = KC + 1;
    __shared__ float As[128 * LP];
    __shared__ float Bs[128 * LP];
    const int tid = threadIdx.x;
    const int tr = tid >> 4, tc = tid & 15;
    const int pt = blockIdx.x;    // point tile (0..255)
    const int ct = blockIdx.y;    // channel tile (0..7)
    float acc[8][8] = {};
    for (int k0 = 0; k0 < 256; k0 += KC) {
        __syncthreads();
        stage_tile<KC>(xc, 256, pt * 128, k0, As);
        stage_tile<KC>(Wft, 256, ct * 128, k0, Bs);
        __syncthreads();
        #pragma unroll 4
        for (int k = 0; k < KC; ++k) {
            float a[8], bv[8];
            #pragma unroll
            for (int i = 0; i < 8; ++i) a[i] = As[(tr + 16 * i) * LP + k];
            #pragma unroll
            for (int j = 0; j < 8; ++j) bv[j] = Bs[(tc + 16 * j) * LP + k];
            #pragma unroll
            for (int i = 0; i < 8; ++i)
                #pragma unroll
                for (int j = 0; j < 8; ++j)
                    acc[i][j] += a[i] * bv[j];
        }
    }
    float s1p[8] = {}, s2p[8] = {}, mxp[8], mnp[8];
    #pragma unroll
    for (int j = 0; j < 8; ++j) { mxp[j] = -FLT_MAX; mnp[j] = FLT_MAX; }
    #pragma unroll
    for (int i = 0; i < 8; ++i)
        #pragma unroll
        for (int j = 0; j < 8; ++j) {
            float v = acc[i][j];
            s1p[j] += v; s2p[j] += v * v;
            mxp[j] = fmaxf(mxp[j], v); mnp[j] = fminf(mnp[j], v);
        }
    float* red = As;
    __syncthreads();
    const size_t go = (size_t)pt * 1024 + ct * 128;
    #pragma unroll
    for (int j = 0; j < 8; ++j) red[tr * 128 + tc + 16 * j] = s1p[j];
    __syncthreads();
    if (tid < 128) {
        float v = red[tid];
        for (int t = 1; t < 16; ++t) v += red[t * 128 + tid];
        psum[go + tid] = v;
    }
    __syncthreads();
    #pragma unroll
    for (int j = 0; j < 8; ++j) red[tr * 128 + tc + 16 * j] = s2p[j];
    __syncthreads();
    if (tid < 128) {
        float v = red[tid];
        for (int t = 1; t < 16; ++t) v += red[t * 128 + tid];
        psum2[go + tid] = v;
    }
    __syncthreads();
    #pragma unroll
    for (int j = 0; j < 8; ++j) red[tr * 128 + tc + 16 * j] = mxp[j];
    __syncthreads();
    if (tid < 128) {
        float v = red[tid];
        for (int t = 1; t < 16; ++t) v = fmaxf(v, red[t * 128 + tid]);
        pmax[go + tid] = v;
    }
    __syncthreads();
    #pragma unroll
    for (int j = 0; j < 8; ++j) red[tr * 128 + tc + 16 * j] = mnp[j];
    __syncthreads();
    if (tid < 128) {
        float v = red[tid];
        for (int t = 1; t < 16; ++t) v = fminf(v, red[t * 128 + tid]);
        pmin[go + tid] = v;
    }
}

// ---------------- gfeat finalize (16 point-tile partials per batch) ----------------
__global__ __launch_bounds__(256) void gfeat_final_kernel(const float* __restrict__ pmax,
                                                          const float* __restrict__ pmin,
                                                          const float* __restrict__ alpha,
                                                          const float* __restrict__ beta,
                                                          float* __restrict__ gfeat) {
    int i = blockIdx.x * 256 + threadIdx.x;
    if (i < NB * 1024) {
        int b = i >> 10, c = i & 1023;
        float mx = -FLT_MAX, mn = FLT_MAX;
        for (int j = 0; j < 16; ++j) {
            size_t o = (size_t)(b * 16 + j) * 1024 + c;
            mx = fmaxf(mx, pmax[o]);
            mn = fminf(mn, pmin[o]);
        }
        float a = alpha[c];
        gfeat[i] = leaky(a * (a >= 0.f ? mx : mn) + beta[c]);
    }
}

// ---------------- classifier: split-K skinny GEMM, A is [16][K] ----------------
// grid (ceil(N/64), 2); block 256 = 4 waves; wave g handles k-chunk ks=blockIdx.y*4+g.
// Per-wave LDS staging of A chunk (no barriers). part[ks][16][N].
template <int CHUNK>
__global__ __launch_bounds__(256) void skinny_gemm_kernel(const float* __restrict__ A,
                                                          const float* __restrict__ W,
                                                          float* __restrict__ part,
                                                          int K, int N) {
    __shared__ float Asub[4][16][CHUNK];
    const int tid = threadIdx.x;
    const int g = tid >> 6, lane = tid & 63;
    const int c = blockIdx.x * 64 + lane;
    const int ks = blockIdx.y * 4 + g;
    const int e0 = ks * CHUNK;
    for (int i = lane; i < 16 * CHUNK; i += 64) {
        const int m = i / CHUNK, el = i - m * CHUNK;
        Asub[g][m][el] = A[(size_t)m * K + e0 + el];
    }
    if (c < N) {
        float acc[16];
        #pragma unroll
        for (int m = 0; m < 16; ++m) acc[m] = 0.f;
        #pragma unroll 4
        for (int el = 0; el < CHUNK; ++el) {
            float w = W[(size_t)(e0 + el) * N + c];
            #pragma unroll
            for (int m = 0; m < 16; ++m) acc[m] += Asub[g][m][el] * w;
        }
        #pragma unroll
        for (int m = 0; m < 16; ++m)
            part[((size_t)ks * 16 + m) * N + c] = acc[m];
    }
}

// ---------------- classifier finish: reduce splits + bias (+BN over rows + leaky) ----------------
__global__ __launch_bounds__(256) void fin_kernel(const float* __restrict__ part,
                                                  int S, int N,
                                                  const float* __restrict__ bias,
                                                  const float* __restrict__ g,
                                                  const float* __restrict__ bb,
                                                  int do_bn,
                                                  float* __restrict__ out, int Nout) {
    int c = blockIdx.x * 256 + threadIdx.x;
    if (c >= N) return;
    float z[16];
    #pragma unroll
    for (int m = 0; m < 16; ++m) z[m] = bias[c];
    for (int s = 0; s < S; ++s)
        #pragma unroll
        for (int m = 0; m < 16; ++m) z[m] += part[((size_t)s * 16 + m) * N + c];
    if (do_bn) {
        float s1 = 0.f, s2 = 0.f;
        #pragma unroll
        for (int m = 0; m < 16; ++m) { s1 += z[m]; s2 += z[m] * z[m]; }
        float mean = s1 * (1.f / 16.f);
        float var = s2 * (1.f / 16.f) - mean * mean;
        float a = g[c] * rsqrtf(var + 1e-5f);
        float be = bb[c] - mean * a;
        #pragma unroll
        for (int m = 0; m < 16; ++m) out[(size_t)m * N + c] = leaky(a * z[m] + be);
    } else {
        if (c < Nout)
            #pragma unroll
            for (int m = 0; m < 16; ++m) out[(size_t)m * Nout + c] = z[m];
    }
}

static void run_knn(const float* x, int ldx, int nk, const float* sq, unsigned* keys,
                    int CB, int* idx, hipStream_t stream) {
    for (int b0 = 0; b0 < NB; b0 += CB) {
        dim3 g(NP / 128, NP / 128, CB);
        if (nk == 4)
            dist_gemm_kernel<4><<<g, 256, 0, stream>>>(x, ldx, sq, b0, keys);
        else
            dist_gemm_kernel<64><<<g, 256, 0, stream>>>(x, ldx, sq, b0, keys);
        knn_select_kernel<<<CB * NP / 4, 256, 0, stream>>>(keys, b0, idx);
    }
}

} // namespace

extern "C" void kernel_launch(void* const* d_in, const int* in_sizes, int n_in,
                              void* d_out, int out_size, void* d_ws, size_t ws_size,
                              hipStream_t stream) {
    (void)in_sizes; (void)n_in; (void)out_size;
    const float* pos = (const float*)d_in[0];
    const float* W1  = (const float*)d_in[1];
    const float* g1  = (const float*)d_in[2];
    const float* b1  = (const float*)d_in[3];
    const float* W2  = (const float*)d_in[4];
    const float* g2  = (const float*)d_in[5];
    const float* b2  = (const float*)d_in[6];
    const float* W3  = (const float*)d_in[7];
    const float* g3  = (const float*)d_in[8];
    const float* b3  = (const float*)d_in[9];
    const float* Wf  = (const float*)d_in[10];
    const float* gf  = (const float*)d_in[11];
    const float* bf  = (const float*)d_in[12];
    const float* W4  = (const float*)d_in[13];
    const float* b4  = (const float*)d_in[14];
    const float* g4  = (const float*)d_in[15];
    const float* be4 = (const float*)d_in[16];
    const float* W5  = (const float*)d_in[17];
    const float* b5  = (const float*)d_in[18];
    const float* g5  = (const float*)d_in[19];
    const float* be5 = (const float*)d_in[20];
    const float* W6  = (const float*)d_in[21];
    const float* b6  = (const float*)d_in[22];
    float* out = (float*)d_out;

    float* ws = (float*)d_ws;
    size_t off = 0;
    int*   idx    = (int*)ws;      off += (size_t)TOT * KK;          // 2.6 MB
    float* pos4   = ws + off;      off += (size_t)TOT * 4;
    float* sq     = ws + off;      off += (size_t)TOT;
    float* Wt     = ws + off;      off += 256 * 64;
    float* Wft    = ws + off;      off += 1024 * 256;                // 1 MB
    float* basexw = ws + off;      off += (size_t)TOT * 256;         // 32 MB
    float* mmax   = ws + off;      off += (size_t)TOT * 128;         // 16 MB
    float* mmin   = ws + off;      off += (size_t)TOT * 128;         // 16 MB
    float* xc     = ws + off;      off += (size_t)TOT * 256;         // 32 MB
    float* psum   = ws + off;      off += (size_t)512 * 1024;        // 2 MB
    float* psum2  = ws + off;      off += (size_t)512 * 1024;
    float* pmax   = ws + off;      off += (size_t)512 * 1024;
    float* pmin   = ws + off;      off += (size_t)512 * 1024;
    float* alpha  = ws + off;      off += 1024;
    float* beta   = ws + off;      off += 1024;
    float* gfeat  = ws + off;      off += NB * 1024;
    float* part   = ws + off;      off += 8 * 16 * 512;              // split-K partials
    float* h4     = ws + off;      off += NB * 512;
    float* h5     = ws + off;      off += NB * 256;
    unsigned* keys = (unsigned*)(ws + off);
    const size_t avail = (ws_size > off * 4) ? (ws_size - off * 4) : 0;
    const size_t per_batch = (size_t)NP * NP * 4;
    int CB = 1;
    for (int cb : {16, 8, 4, 2}) {
        if ((size_t)cb * per_batch <= avail) { CB = cb; break; }
    }

    const int npts_blk = (TOT + 255) / 256;

    // ---------- Layer 1 (D=3 padded to 4, C=64) ----------
    pos4_kernel<<<npts_blk, 256, 0, stream>>>(pos, pos4);
    sq4_kernel<<<npts_blk, 256, 0, stream>>>(pos4, 4, 1, sq);
    run_knn(pos4, 4, 4, sq, keys, CB, idx, stream);
    wt_build_kernel<<<2, 256, 0, stream>>>(W1, Wt, 3, 4, 64);
    xw_gemm_kernel<1, 128><<<TOT / 16, 256, 0, stream>>>(pos4, 4, Wt, basexw);
    edge_pass_kernel<64><<<EBLK, 256, 0, stream>>>(basexw, idx, psum, psum2, mmax, mmin);
    bn_reduce_kernel<<<64, 256, 0, stream>>>(psum, psum2, EBLK, 64, g1, b1,
                                             1.f / (float)(TOT * KK), alpha, beta);
    edge_finalize_kernel<64><<<TOT * 16 / 256, 256, 0, stream>>>(mmax, mmin, alpha, beta, xc + 0);

    // ---------- Layer 2 (D=64, C=64), input x1 = xc[:,0:64] ----------
    sq4_kernel<<<npts_blk, 256, 0, stream>>>(xc + 0, 256, 16, sq);
    run_knn(xc + 0, 256, 64, sq, keys, CB, idx, stream);
    wt_build_kernel<<<32, 256, 0, stream>>>(W2, Wt, 64, 64, 64);
    xw_gemm_kernel<16, 128><<<TOT / 16, 256, 0, stream>>>(xc + 0, 256, Wt, basexw);
    edge_pass_kernel<64><<<EBLK, 256, 0, stream>>>(basexw, idx, psum, psum2, mmax, mmin);
    bn_reduce_kernel<<<64, 256, 0, stream>>>(psum, psum2, EBLK, 64, g2, b2,
                                             1.f / (float)(TOT * KK), alpha, beta);
    edge_finalize_kernel<64><<<TOT * 16 / 256, 256, 0, stream>>>(mmax, mmin, alpha, beta, xc + 64);

    // ---------- Layer 3 (D=64, C=128), input x2 = xc[:,64:128] ----------
    sq4_kernel<<<npts_blk, 256, 0, stream>>>(xc + 64, 256, 16, sq);
    run_knn(xc + 64, 256, 64, sq, keys, CB, idx, stream);
    wt_build_kernel<<<64, 256, 0, stream>>>(W3, Wt, 64, 64, 128);
    xw_gemm_kernel<16, 256><<<TOT / 16, 256, 0, stream>>>(xc + 64, 256, Wt, basexw);
    edge_pass_kernel<128><<<EBLK, 256, 0, stream>>>(basexw, idx, psum, psum2, mmax, mmin);
    bn_reduce_kernel<<<128, 256, 0, stream>>>(psum, psum2, EBLK, 128, g3, b3,
                                              1.f / (float)(TOT * KK), alpha, beta);
    edge_finalize_kernel<128><<<TOT * 32 / 256, 256, 0, stream>>>(mmax, mmin, alpha, beta, xc + 128);

    // ---------- conv_final + global max pool ----------
    wft_build_kernel<<<1024, 256, 0, stream>>>(Wf, Wft);
    {
        dim3 g(TOT / 128, 1024 / 128, 1);
        fc_gemm_kernel<<<g, 256, 0, stream>>>(xc, Wft, psum, psum2, pmax, pmin);
    }
    bn_reduce_kernel<<<1024, 256, 0, stream>>>(psum, psum2, 256, 1024, gf, bf,
                                               1.f / (float)TOT, alpha, beta);
    gfeat_final_kernel<<<64, 256, 0, stream>>>(pmax, pmin, alpha, beta, gfeat);

    // ---------- classifier (split-K skinny GEMMs) ----------
    skinny_gemm_kernel<128><<<dim3(8, 2), 256, 0, stream>>>(gfeat, W4, part, 1024, 512);
    fin_kernel<<<2, 256, 0, stream>>>(part, 8, 512, b4, g4, be4, 1, h4, 512);
    skinny_gemm_kernel<64><<<dim3(4, 2), 256, 0, stream>>>(h4, W5, part, 512, 256);
    fin_kernel<<<1, 256, 0, stream>>>(part, 8, 256, b5, g5, be5, 1, h5, 256);
    skinny_gemm_kernel<32><<<dim3(1, 2), 256, 0, stream>>>(h5, W6, part, 256, 40);
    fin_kernel<<<1, 256, 0, stream>>>(part, 8, 40, b6, nullptr, nullptr, 0, out, 40);
}

// Round 7
// 1419.445 us; speedup vs baseline: 3.4212x; 1.0131x over previous
//
#include <hip/hip_runtime.h>
#include <float.h>
#include <math.h>

namespace {

constexpr int NB = 16;
constexpr int NP = 2048;
constexpr int KK = 20;
constexpr int TOT = NB * NP;   // 32768
constexpr int EBLK = 1024;     // edge pass grid

__device__ __forceinline__ float leaky(float v) { return fmaxf(v, 0.2f * v); }

// ---------------- pos -> pos4 (pad to 4 comps) ----------------
__global__ __launch_bounds__(256) void pos4_kernel(const float* __restrict__ pos,
                                                   float* __restrict__ pos4) {
    int i = blockIdx.x * 256 + threadIdx.x;
    if (i < TOT) {
        pos4[i * 4 + 0] = pos[i * 3 + 0];
        pos4[i * 4 + 1] = pos[i * 3 + 1];
        pos4[i * 4 + 2] = pos[i * 3 + 2];
        pos4[i * 4 + 3] = 0.f;
    }
}

// ---------------- squared norms (float4 rows) ----------------
__global__ __launch_bounds__(256) void sq4_kernel(const float* __restrict__ x, int ldx, int nj4,
                                                  float* __restrict__ sq) {
    int i = blockIdx.x * 256 + threadIdx.x;
    if (i < TOT) {
        const float4* r = reinterpret_cast<const float4*>(x + (size_t)i * ldx);
        float s = 0.f;
        for (int j4 = 0; j4 < nj4; ++j4) {
            float4 v = r[j4];
            s += v.x * v.x + v.y * v.y + v.z * v.z + v.w * v.w;
        }
        sq[i] = s;
    }
}

// ---------------- distance GEMM -> monotone uint keys ----------------
// 128x128 tile, 8x8/thread. k-major LDS (T[k][row]) so fragment loads are
// ds_read_b128; split row/col ownership (r, 64+r) gives even bank coverage.
template <int KTOT>
__global__ __launch_bounds__(256) void dist_gemm_kernel(const float* __restrict__ x, int ldx,
                                                        const float* __restrict__ sq,
                                                        int b0,
                                                        unsigned* __restrict__ keys) {
    constexpr int KC = (KTOT < 32) ? KTOT : 32;
    constexpr int F4 = KC / 4;
    __shared__ float Ak[KC][128];
    __shared__ float Bk[KC][128];
    const int tid = threadIdx.x;
    const int tr = tid >> 4, tc = tid & 15;
    const int m0 = blockIdx.y * 128, n0 = blockIdx.x * 128;
    const int bofs = (b0 + blockIdx.z) * NP;
    const float* xb = x + (size_t)bofs * ldx;
    float acc[8][8] = {};
    for (int k0 = 0; k0 < KTOT; k0 += KC) {
        __syncthreads();
        for (int i = tid; i < 128 * F4; i += 256) {
            const int r = i / F4, c4 = i % F4;
            float4 v = *reinterpret_cast<const float4*>(xb + (size_t)(m0 + r) * ldx + k0 + c4 * 4);
            Ak[c4 * 4 + 0][r] = v.x; Ak[c4 * 4 + 1][r] = v.y;
            Ak[c4 * 4 + 2][r] = v.z; Ak[c4 * 4 + 3][r] = v.w;
        }
        for (int i = tid; i < 128 * F4; i += 256) {
            const int r = i / F4, c4 = i % F4;
            float4 v = *reinterpret_cast<const float4*>(xb + (size_t)(n0 + r) * ldx + k0 + c4 * 4);
            Bk[c4 * 4 + 0][r] = v.x; Bk[c4 * 4 + 1][r] = v.y;
            Bk[c4 * 4 + 2][r] = v.z; Bk[c4 * 4 + 3][r] = v.w;
        }
        __syncthreads();
        #pragma unroll
        for (int k = 0; k < KC; ++k) {
            float4 al = *reinterpret_cast<const float4*>(&Ak[k][tr * 4]);
            float4 ah = *reinterpret_cast<const float4*>(&Ak[k][64 + tr * 4]);
            float4 bl = *reinterpret_cast<const float4*>(&Bk[k][tc * 4]);
            float4 bh = *reinterpret_cast<const float4*>(&Bk[k][64 + tc * 4]);
            float a[8] = {al.x, al.y, al.z, al.w, ah.x, ah.y, ah.z, ah.w};
            float bv[8] = {bl.x, bl.y, bl.z, bl.w, bh.x, bh.y, bh.z, bh.w};
            #pragma unroll
            for (int i = 0; i < 8; ++i)
                #pragma unroll
                for (int j = 0; j < 8; ++j)
                    acc[i][j] += a[i] * bv[j];
        }
    }
    float sa[8], sb[8];
    #pragma unroll
    for (int i = 0; i < 8; ++i) sa[i] = sq[bofs + m0 + ((i < 4) ? tr * 4 + i : 64 + tr * 4 + i - 4)];
    #pragma unroll
    for (int j = 0; j < 8; ++j) sb[j] = sq[bofs + n0 + ((j < 4) ? tc * 4 + j : 64 + tc * 4 + j - 4)];
    #pragma unroll
    for (int i = 0; i < 8; ++i) {
        const int row = (i < 4) ? tr * 4 + i : 64 + tr * 4 + i - 4;
        unsigned* kr = keys + ((size_t)blockIdx.z * NP + m0 + row) * NP + n0;
        unsigned kk[8];
        #pragma unroll
        for (int j = 0; j < 8; ++j) {
            float d = sa[i] + sb[j] - 2.f * acc[i][j];
            unsigned bits = __float_as_uint(d);
            kk[j] = (bits & 0x80000000u) ? ~bits : (bits | 0x80000000u);
        }
        *reinterpret_cast<uint4*>(kr + tc * 4) = make_uint4(kk[0], kk[1], kk[2], kk[3]);
        *reinterpret_cast<uint4*>(kr + 64 + tc * 4) = make_uint4(kk[4], kk[5], kk[6], kk[7]);
    }
}

// ---------------- kNN select: ballot binary search, wave per query ----------------
__global__ __launch_bounds__(256) void knn_select_kernel(const unsigned* __restrict__ keys,
                                                         int b0,
                                                         int* __restrict__ idx_out) {
    const int tid = threadIdx.x;
    const int w = tid >> 6, lane = tid & 63;
    const int ql = blockIdx.x * 4 + w;        // chunk-local query
    const int bc = ql / NP;
    const int b = b0 + bc;
    const int bofs = b * NP;
    const unsigned* kr = keys + (size_t)ql * NP;

    unsigned keysr[32];
    #pragma unroll
    for (int u = 0; u < 32; ++u) keysr[u] = kr[u * 64 + lane];

    unsigned lmn = 0xFFFFFFFFu;
    #pragma unroll
    for (int u = 0; u < 32; ++u) lmn = min(lmn, keysr[u]);
    unsigned M = lmn, lo = lmn;
    #pragma unroll
    for (int off = 1; off < 64; off <<= 1) {
        unsigned tM = __shfl_xor(M, off);
        unsigned tl = __shfl_xor(lo, off);
        M = max(M, tM);
        lo = min(lo, tl);
    }
    unsigned hi = M;
    while (lo < hi) {
        unsigned mid = lo + ((hi - lo) >> 1);
        int cnt = 0;
        #pragma unroll
        for (int u = 0; u < 32; ++u)
            cnt += __popcll(__ballot(keysr[u] <= mid));
        if (cnt >= KK) hi = mid; else lo = mid + 1;
    }
    const unsigned T = lo;

    unsigned nl = 0;
    #pragma unroll
    for (int u = 0; u < 32; ++u) nl += (keysr[u] < T) ? 1u : 0u;
    unsigned sc2 = nl;
    #pragma unroll
    for (int off = 1; off < 64; off <<= 1) {
        unsigned t = __shfl_up(sc2, off);
        if (lane >= off) sc2 += t;
    }
    unsigned cstrict = __shfl(sc2, 63);
    unsigned o = sc2 - nl;
    int* op = idx_out + (size_t)(bofs + (ql - bc * NP)) * KK;
    #pragma unroll
    for (int u = 0; u < 32; ++u) {
        if (keysr[u] < T) { op[o] = bofs + u * 64 + lane; ++o; }
    }
    int rem = KK - (int)cstrict;
    int ebase = (int)cstrict;
    #pragma unroll
    for (int u = 0; u < 32; ++u) {
        if (rem > 0) {
            bool eq = (keysr[u] == T);
            unsigned long long bm = __ballot(eq);
            int before = __popcll(bm & ((1ull << lane) - 1ull));
            if (eq && before < rem) op[ebase + before] = bofs + u * 64 + lane;
            int take = __popcll(bm);
            if (take > rem) take = rem;
            ebase += take;
            rem -= take;
        }
    }
}

// ---------------- Wt[c][j] build: [Wd | Wtail] transposed, zero-padded ----------------
__global__ __launch_bounds__(256) void wt_build_kernel(const float* __restrict__ W,
                                                       float* __restrict__ Wt,
                                                       int D, int Dp, int C) {
    int i = blockIdx.x * 256 + threadIdx.x;
    if (i < 2 * C * Dp) {
        int c = i / Dp, j = i % Dp;
        float v = 0.f;
        if (j < D) {
            v = (c < C) ? (W[j * C + c] - W[(D + j) * C + c])
                        : W[(D + j) * C + (c - C)];
        }
        Wt[i] = v;
    }
}

// ---------------- X[TOT,Dp] @ Wt^T -> basexw[TOT,2C] ----------------
template <int NJ4, int C2>
__global__ __launch_bounds__(256) void xw_gemm_kernel(const float* __restrict__ x, int ldx,
                                                      const float* __restrict__ Wt,
                                                      float* __restrict__ bx) {
    constexpr int PG = 256 / C2;   // point groups
    constexpr int PTS = 16 / PG;   // points per thread
    __shared__ float4 Xs[16][NJ4];
    const int tid = threadIdx.x;
    const int p0 = blockIdx.x * 16;
    for (int i = tid; i < 16 * NJ4; i += 256) {
        int r = i / NJ4, j4 = i % NJ4;
        Xs[r][j4] = *reinterpret_cast<const float4*>(x + (size_t)(p0 + r) * ldx + j4 * 4);
    }
    __syncthreads();
    const int c = tid % C2, pg = tid / C2;
    const float4* wrow = reinterpret_cast<const float4*>(Wt + (size_t)c * (NJ4 * 4));
    float acc[PTS];
    #pragma unroll
    for (int u = 0; u < PTS; ++u) acc[u] = 0.f;
    #pragma unroll
    for (int j4 = 0; j4 < NJ4; ++j4) {
        float4 w4 = wrow[j4];
        #pragma unroll
        for (int u = 0; u < PTS; ++u) {
            float4 x4 = Xs[pg * PTS + u][j4];
            acc[u] += x4.x * w4.x + x4.y * w4.y + x4.z * w4.z + x4.w * w4.w;
        }
    }
    #pragma unroll
    for (int u = 0; u < PTS; ++u)
        bx[(size_t)(p0 + pg * PTS + u) * C2 + c] = acc[u];
}

// ---------------- edge pass: gather XW, stats + per-point max/min ----------------
template <int C>
__global__ __launch_bounds__(256) void edge_pass_kernel(const float* __restrict__ bx,
                                                        const int* __restrict__ idx,
                                                        float* __restrict__ psum,
                                                        float* __restrict__ psum2,
                                                        float* __restrict__ mmax,
                                                        float* __restrict__ mmin) {
    constexpr int PT = 256 / C;
    constexpr int C2 = 2 * C;
    __shared__ int sidx[PT][KK];
    __shared__ float red[256];
    const int tid = threadIdx.x;
    const int c = tid % C;
    const int pl = tid / C;
    float s1 = 0.f, s2 = 0.f;
    const int NT = TOT / PT;
    for (int t = blockIdx.x; t < NT; t += EBLK) {
        const int p0 = t * PT;
        __syncthreads();
        if (tid < PT * KK) sidx[tid / KK][tid % KK] = idx[(size_t)p0 * KK + tid];
        __syncthreads();
        const int p = p0 + pl;
        const float bv = bx[(size_t)p * C2 + c];
        float A = 0.f, Q = 0.f, M = -FLT_MAX, mn = FLT_MAX;
        #pragma unroll
        for (int k = 0; k < KK; ++k) {
            float v = bx[(size_t)sidx[pl][k] * C2 + C + c];
            A += v; Q += v * v; M = fmaxf(M, v); mn = fminf(mn, v);
        }
        s1 += (float)KK * bv + A;
        s2 += (float)KK * bv * bv + 2.f * bv * A + Q;
        mmax[(size_t)p * C + c] = bv + M;
        mmin[(size_t)p * C + c] = bv + mn;
    }
    red[tid] = s1;
    __syncthreads();
    if (tid < C) {
        float v = red[tid];
        #pragma unroll
        for (int u = 1; u < PT; ++u) v += red[tid + u * C];
        psum[(size_t)blockIdx.x * C + tid] = v;
    }
    __syncthreads();
    red[tid] = s2;
    __syncthreads();
    if (tid < C) {
        float v = red[tid];
        #pragma unroll
        for (int u = 1; u < PT; ++u) v += red[tid + u * C];
        psum2[(size_t)blockIdx.x * C + tid] = v;
    }
}

// ---------------- BN stats reduce -> alpha/beta ----------------
__global__ __launch_bounds__(256) void bn_reduce_kernel(
        const float* __restrict__ psum, const float* __restrict__ psum2,
        int npart, int C, const float* __restrict__ g, const float* __restrict__ bb,
        float inv_cnt, float* __restrict__ alpha, float* __restrict__ beta) {
    const int c = blockIdx.x;
    const int tid = threadIdx.x;
    __shared__ float r1[256], r2[256];
    float s1 = 0.f, s2 = 0.f;
    for (int i = tid; i < npart; i += 256) {
        s1 += psum[(size_t)i * C + c];
        s2 += psum2[(size_t)i * C + c];
    }
    r1[tid] = s1; r2[tid] = s2;
    __syncthreads();
    for (int s = 128; s > 0; s >>= 1) {
        if (tid < s) { r1[tid] += r1[tid + s]; r2[tid] += r2[tid + s]; }
        __syncthreads();
    }
    if (tid == 0) {
        float mean = r1[0] * inv_cnt;
        float var = r2[0] * inv_cnt - mean * mean;
        float a = g[c] * rsqrtf(var + 1e-5f);
        alpha[c] = a;
        beta[c] = bb[c] - mean * a;
    }
}

// ---------------- edge finalize: pick max/min by sign(alpha), affine+leaky ----------------
template <int C>
__global__ __launch_bounds__(256) void edge_finalize_kernel(const float* __restrict__ mmax,
                                                            const float* __restrict__ mmin,
                                                            const float* __restrict__ alpha,
                                                            const float* __restrict__ beta,
                                                            float* __restrict__ xc_slice) {
    constexpr int CQ = C / 4;
    int i4 = blockIdx.x * 256 + threadIdx.x;
    if (i4 < TOT * CQ) {
        int p = i4 / CQ, cq = i4 - p * CQ;
        float4 M4 = reinterpret_cast<const float4*>(mmax)[i4];
        float4 m4 = reinterpret_cast<const float4*>(mmin)[i4];
        float4 a4 = reinterpret_cast<const float4*>(alpha)[cq];
        float4 b4 = reinterpret_cast<const float4*>(beta)[cq];
        float4 o;
        o.x = leaky(a4.x * (a4.x >= 0.f ? M4.x : m4.x) + b4.x);
        o.y = leaky(a4.y * (a4.y >= 0.f ? M4.y : m4.y) + b4.y);
        o.z = leaky(a4.z * (a4.z >= 0.f ? M4.z : m4.z) + b4.z);
        o.w = leaky(a4.w * (a4.w >= 0.f ? M4.w : m4.w) + b4.w);
        *reinterpret_cast<float4*>(xc_slice + (size_t)p * 256 + cq * 4) = o;
    }
}

// ---------------- Wf transpose: [256][1024] -> [1024][256] ----------------
__global__ __launch_bounds__(256) void wft_build_kernel(const float* __restrict__ Wf,
                                                        float* __restrict__ Wft) {
    int i = blockIdx.x * 256 + threadIdx.x;
    if (i < 256 * 1024) {
        int e = i / 1024, o = i - e * 1024;
        Wft[(size_t)o * 256 + e] = Wf[i];
    }
}

// ---------------- conv_final GEMM (128 pts x 256 ch, 8x8/thread, 512 thr) + stats ----------------
__global__ __launch_bounds__(512) void fc_gemm_kernel(const float* __restrict__ xc,
                                                      const float* __restrict__ Wft,
                                                      float* __restrict__ psum,
                                                      float* __restrict__ psum2,
                                                      float* __restrict__ pmax,
                                                      float* __restrict__ pmin) {
    constexpr int KC = 32;
    __shared__ float Ak[KC][128];   // 16 KB
    __shared__ float Bk[KC][256];   // 32 KB
    const int tid = threadIdx.x;
    const int tr = tid >> 5;        // 0..15 (point groups)
    const int tc = tid & 31;        // 0..31 (channel groups)
    const int pt = blockIdx.x;      // point tile (0..255)
    const int ct = blockIdx.y;      // channel tile (0..3)
    float acc[8][8] = {};
    for (int k0 = 0; k0 < 256; k0 += KC) {
        __syncthreads();
        for (int i = tid; i < 128 * 8; i += 512) {
            const int r = i >> 3, c4 = i & 7;
            float4 v = *reinterpret_cast<const float4*>(xc + (size_t)(pt * 128 + r) * 256 + k0 + c4 * 4);
            Ak[c4 * 4 + 0][r] = v.x; Ak[c4 * 4 + 1][r] = v.y;
            Ak[c4 * 4 + 2][r] = v.z; Ak[c4 * 4 + 3][r] = v.w;
        }
        for (int i = tid; i < 256 * 8; i += 512) {
            const int r = i >> 3, c4 = i & 7;
            float4 v = *reinterpret_cast<const float4*>(Wft + (size_t)(ct * 256 + r) * 256 + k0 + c4 * 4);
            Bk[c4 * 4 + 0][r] = v.x; Bk[c4 * 4 + 1][r] = v.y;
            Bk[c4 * 4 + 2][r] = v.z; Bk[c4 * 4 + 3][r] = v.w;
        }
        __syncthreads();
        #pragma unroll
        for (int k = 0; k < KC; ++k) {
            float4 al = *reinterpret_cast<const float4*>(&Ak[k][tr * 4]);
            float4 ah = *reinterpret_cast<const float4*>(&Ak[k][64 + tr * 4]);
            float4 bl = *reinterpret_cast<const float4*>(&Bk[k][tc * 4]);
            float4 bh = *reinterpret_cast<const float4*>(&Bk[k][128 + tc * 4]);
            float a[8] = {al.x, al.y, al.z, al.w, ah.x, ah.y, ah.z, ah.w};
            float bv[8] = {bl.x, bl.y, bl.z, bl.w, bh.x, bh.y, bh.z, bh.w};
            #pragma unroll
            for (int i = 0; i < 8; ++i)
                #pragma unroll
                for (int j = 0; j < 8; ++j)
                    acc[i][j] += a[i] * bv[j];
        }
    }
    // per-thread channel partials over its 8 points
    float s1p[8] = {}, s2p[8] = {}, mxp[8], mnp[8];
    #pragma unroll
    for (int j = 0; j < 8; ++j) { mxp[j] = -FLT_MAX; mnp[j] = FLT_MAX; }
    #pragma unroll
    for (int i = 0; i < 8; ++i)
        #pragma unroll
        for (int j = 0; j < 8; ++j) {
            float v = acc[i][j];
            s1p[j] += v; s2p[j] += v * v;
            mxp[j] = fmaxf(mxp[j], v); mnp[j] = fminf(mnp[j], v);
        }
    // reduce across 16 point-groups; reuse Ak as red[16][256] (4096 floats)
    float* red = &Ak[0][0];
    const size_t go = (size_t)pt * 1024 + ct * 256;
    int col[8];
    #pragma unroll
    for (int j = 0; j < 8; ++j) col[j] = (j < 4) ? tc * 4 + j : 128 + tc * 4 + (j - 4);

    __syncthreads();
    #pragma unroll
    for (int j = 0; j < 8; ++j) red[tr * 256 + col[j]] = s1p[j];
    __syncthreads();
    if (tid < 256) {
        float v = red[tid];
        for (int t = 1; t < 16; ++t) v += red[t * 256 + tid];
        psum[go + tid] = v;
    }
    __syncthreads();
    #pragma unroll
    for (int j = 0; j < 8; ++j) red[tr * 256 + col[j]] = s2p[j];
    __syncthreads();
    if (tid < 256) {
        float v = red[tid];
        for (int t = 1; t < 16; ++t) v += red[t * 256 + tid];
        psum2[go + tid] = v;
    }
    __syncthreads();
    #pragma unroll
    for (int j = 0; j < 8; ++j) red[tr * 256 + col[j]] = mxp[j];
    __syncthreads();
    if (tid < 256) {
        float v = red[tid];
        for (int t = 1; t < 16; ++t) v = fmaxf(v, red[t * 256 + tid]);
        pmax[go + tid] = v;
    }
    __syncthreads();
    #pragma unroll
    for (int j = 0; j < 8; ++j) red[tr * 256 + col[j]] = mnp[j];
    __syncthreads();
    if (tid < 256) {
        float v = red[tid];
        for (int t = 1; t < 16; ++t) v = fminf(v, red[t * 256 + tid]);
        pmin[go + tid] = v;
    }
}

// ---------------- gfeat finalize (16 point-tile partials per batch) ----------------
__global__ __launch_bounds__(256) void gfeat_final_kernel(const float* __restrict__ pmax,
                                                          const float* __restrict__ pmin,
                                                          const float* __restrict__ alpha,
                                                          const float* __restrict__ beta,
                                                          float* __restrict__ gfeat) {
    int i = blockIdx.x * 256 + threadIdx.x;
    if (i < NB * 1024) {
        int b = i >> 10, c = i & 1023;
        float mx = -FLT_MAX, mn = FLT_MAX;
        for (int j = 0; j < 16; ++j) {
            size_t o = (size_t)(b * 16 + j) * 1024 + c;
            mx = fmaxf(mx, pmax[o]);
            mn = fminf(mn, pmin[o]);
        }
        float a = alpha[c];
        gfeat[i] = leaky(a * (a >= 0.f ? mx : mn) + beta[c]);
    }
}

// ---------------- classifier: split-K skinny GEMM, A is [16][K] ----------------
template <int CHUNK>
__global__ __launch_bounds__(256) void skinny_gemm_kernel(const float* __restrict__ A,
                                                          const float* __restrict__ W,
                                                          float* __restrict__ part,
                                                          int K, int N) {
    __shared__ float Asub[4][16][CHUNK];
    const int tid = threadIdx.x;
    const int g = tid >> 6, lane = tid & 63;
    const int c = blockIdx.x * 64 + lane;
    const int ks = blockIdx.y * 4 + g;
    const int e0 = ks * CHUNK;
    for (int i = lane; i < 16 * CHUNK; i += 64) {
        const int m = i / CHUNK, el = i - m * CHUNK;
        Asub[g][m][el] = A[(size_t)m * K + e0 + el];
    }
    if (c < N) {
        float acc[16];
        #pragma unroll
        for (int m = 0; m < 16; ++m) acc[m] = 0.f;
        #pragma unroll 4
        for (int el = 0; el < CHUNK; ++el) {
            float w = W[(size_t)(e0 + el) * N + c];
            #pragma unroll
            for (int m = 0; m < 16; ++m) acc[m] += Asub[g][m][el] * w;
        }
        #pragma unroll
        for (int m = 0; m < 16; ++m)
            part[((size_t)ks * 16 + m) * N + c] = acc[m];
    }
}

// ---------------- classifier finish: reduce splits + bias (+BN over rows + leaky) ----------------
__global__ __launch_bounds__(256) void fin_kernel(const float* __restrict__ part,
                                                  int S, int N,
                                                  const float* __restrict__ bias,
                                                  const float* __restrict__ g,
                                                  const float* __restrict__ bb,
                                                  int do_bn,
                                                  float* __restrict__ out, int Nout) {
    int c = blockIdx.x * 256 + threadIdx.x;
    if (c >= N) return;
    float z[16];
    #pragma unroll
    for (int m = 0; m < 16; ++m) z[m] = bias[c];
    for (int s = 0; s < S; ++s)
        #pragma unroll
        for (int m = 0; m < 16; ++m) z[m] += part[((size_t)s * 16 + m) * N + c];
    if (do_bn) {
        float s1 = 0.f, s2 = 0.f;
        #pragma unroll
        for (int m = 0; m < 16; ++m) { s1 += z[m]; s2 += z[m] * z[m]; }
        float mean = s1 * (1.f / 16.f);
        float var = s2 * (1.f / 16.f) - mean * mean;
        float a = g[c] * rsqrtf(var + 1e-5f);
        float be = bb[c] - mean * a;
        #pragma unroll
        for (int m = 0; m < 16; ++m) out[(size_t)m * N + c] = leaky(a * z[m] + be);
    } else {
        if (c < Nout)
            #pragma unroll
            for (int m = 0; m < 16; ++m) out[(size_t)m * Nout + c] = z[m];
    }
}

static void run_knn(const float* x, int ldx, int nk, const float* sq, unsigned* keys,
                    int CB, int* idx, hipStream_t stream) {
    for (int b0 = 0; b0 < NB; b0 += CB) {
        dim3 g(NP / 128, NP / 128, CB);
        if (nk == 4)
            dist_gemm_kernel<4><<<g, 256, 0, stream>>>(x, ldx, sq, b0, keys);
        else
            dist_gemm_kernel<64><<<g, 256, 0, stream>>>(x, ldx, sq, b0, keys);
        knn_select_kernel<<<CB * NP / 4, 256, 0, stream>>>(keys, b0, idx);
    }
}

} // namespace

extern "C" void kernel_launch(void* const* d_in, const int* in_sizes, int n_in,
                              void* d_out, int out_size, void* d_ws, size_t ws_size,
                              hipStream_t stream) {
    (void)in_sizes; (void)n_in; (void)out_size;
    const float* pos = (const float*)d_in[0];
    const float* W1  = (const float*)d_in[1];
    const float* g1  = (const float*)d_in[2];
    const float* b1  = (const float*)d_in[3];
    const float* W2  = (const float*)d_in[4];
    const float* g2  = (const float*)d_in[5];
    const float* b2  = (const float*)d_in[6];
    const float* W3  = (const float*)d_in[7];
    const float* g3  = (const float*)d_in[8];
    const float* b3  = (const float*)d_in[9];
    const float* Wf  = (const float*)d_in[10];
    const float* gf  = (const float*)d_in[11];
    const float* bf  = (const float*)d_in[12];
    const float* W4  = (const float*)d_in[13];
    const float* b4  = (const float*)d_in[14];
    const float* g4  = (const float*)d_in[15];
    const float* be4 = (const float*)d_in[16];
    const float* W5  = (const float*)d_in[17];
    const float* b5  = (const float*)d_in[18];
    const float* g5  = (const float*)d_in[19];
    const float* be5 = (const float*)d_in[20];
    const float* W6  = (const float*)d_in[21];
    const float* b6  = (const float*)d_in[22];
    float* out = (float*)d_out;

    float* ws = (float*)d_ws;
    size_t off = 0;
    int*   idx    = (int*)ws;      off += (size_t)TOT * KK;          // 2.6 MB
    float* pos4   = ws + off;      off += (size_t)TOT * 4;
    float* sq     = ws + off;      off += (size_t)TOT;
    float* Wt     = ws + off;      off += 256 * 64;
    float* Wft    = ws + off;      off += 1024 * 256;                // 1 MB
    float* basexw = ws + off;      off += (size_t)TOT * 256;         // 32 MB
    float* mmax   = ws + off;      off += (size_t)TOT * 128;         // 16 MB
    float* mmin   = ws + off;      off += (size_t)TOT * 128;         // 16 MB
    float* xc     = ws + off;      off += (size_t)TOT * 256;         // 32 MB
    float* psum   = ws + off;      off += (size_t)512 * 1024;        // 2 MB
    float* psum2  = ws + off;      off += (size_t)512 * 1024;
    float* pmax   = ws + off;      off += (size_t)512 * 1024;
    float* pmin   = ws + off;      off += (size_t)512 * 1024;
    float* alpha  = ws + off;      off += 1024;
    float* beta   = ws + off;      off += 1024;
    float* gfeat  = ws + off;      off += NB * 1024;
    float* part   = ws + off;      off += 8 * 16 * 512;              // split-K partials
    float* h4     = ws + off;      off += NB * 512;
    float* h5     = ws + off;      off += NB * 256;
    unsigned* keys = (unsigned*)(ws + off);
    const size_t avail = (ws_size > off * 4) ? (ws_size - off * 4) : 0;
    const size_t per_batch = (size_t)NP * NP * 4;
    int CB = 1;
    for (int cb : {4, 2}) {        // cap at 4 so keys (64 MB) stay L3-resident
        if ((size_t)cb * per_batch <= avail) { CB = cb; break; }
    }

    const int npts_blk = (TOT + 255) / 256;

    // ---------- Layer 1 (D=3 padded to 4, C=64) ----------
    pos4_kernel<<<npts_blk, 256, 0, stream>>>(pos, pos4);
    sq4_kernel<<<npts_blk, 256, 0, stream>>>(pos4, 4, 1, sq);
    run_knn(pos4, 4, 4, sq, keys, CB, idx, stream);
    wt_build_kernel<<<2, 256, 0, stream>>>(W1, Wt, 3, 4, 64);
    xw_gemm_kernel<1, 128><<<TOT / 16, 256, 0, stream>>>(pos4, 4, Wt, basexw);
    edge_pass_kernel<64><<<EBLK, 256, 0, stream>>>(basexw, idx, psum, psum2, mmax, mmin);
    bn_reduce_kernel<<<64, 256, 0, stream>>>(psum, psum2, EBLK, 64, g1, b1,
                                             1.f / (float)(TOT * KK), alpha, beta);
    edge_finalize_kernel<64><<<TOT * 16 / 256, 256, 0, stream>>>(mmax, mmin, alpha, beta, xc + 0);

    // ---------- Layer 2 (D=64, C=64), input x1 = xc[:,0:64] ----------
    sq4_kernel<<<npts_blk, 256, 0, stream>>>(xc + 0, 256, 16, sq);
    run_knn(xc + 0, 256, 64, sq, keys, CB, idx, stream);
    wt_build_kernel<<<32, 256, 0, stream>>>(W2, Wt, 64, 64, 64);
    xw_gemm_kernel<16, 128><<<TOT / 16, 256, 0, stream>>>(xc + 0, 256, Wt, basexw);
    edge_pass_kernel<64><<<EBLK, 256, 0, stream>>>(basexw, idx, psum, psum2, mmax, mmin);
    bn_reduce_kernel<<<64, 256, 0, stream>>>(psum, psum2, EBLK, 64, g2, b2,
                                             1.f / (float)(TOT * KK), alpha, beta);
    edge_finalize_kernel<64><<<TOT * 16 / 256, 256, 0, stream>>>(mmax, mmin, alpha, beta, xc + 64);

    // ---------- Layer 3 (D=64, C=128), input x2 = xc[:,64:128] ----------
    sq4_kernel<<<npts_blk, 256, 0, stream>>>(xc + 64, 256, 16, sq);
    run_knn(xc + 64, 256, 64, sq, keys, CB, idx, stream);
    wt_build_kernel<<<64, 256, 0, stream>>>(W3, Wt, 64, 64, 128);
    xw_gemm_kernel<16, 256><<<TOT / 16, 256, 0, stream>>>(xc + 64, 256, Wt, basexw);
    edge_pass_kernel<128><<<EBLK, 256, 0, stream>>>(basexw, idx, psum, psum2, mmax, mmin);
    bn_reduce_kernel<<<128, 256, 0, stream>>>(psum, psum2, EBLK, 128, g3, b3,
                                              1.f / (float)(TOT * KK), alpha, beta);
    edge_finalize_kernel<128><<<TOT * 32 / 256, 256, 0, stream>>>(mmax, mmin, alpha, beta, xc + 128);

    // ---------- conv_final + global max pool ----------
    wft_build_kernel<<<1024, 256, 0, stream>>>(Wf, Wft);
    {
        dim3 g(TOT / 128, 4, 1);
        fc_gemm_kernel<<<g, 512, 0, stream>>>(xc, Wft, psum, psum2, pmax, pmin);
    }
    bn_reduce_kernel<<<1024, 256, 0, stream>>>(psum, psum2, 256, 1024, gf, bf,
                                               1.f / (float)TOT, alpha, beta);
    gfeat_final_kernel<<<64, 256, 0, stream>>>(pmax, pmin, alpha, beta, gfeat);

    // ---------- classifier (split-K skinny GEMMs) ----------
    skinny_gemm_kernel<128><<<dim3(8, 2), 256, 0, stream>>>(gfeat, W4, part, 1024, 512);
    fin_kernel<<<2, 256, 0, stream>>>(part, 8, 512, b4, g4, be4, 1, h4, 512);
    skinny_gemm_kernel<64><<<dim3(4, 2), 256, 0, stream>>>(h4, W5, part, 512, 256);
    fin_kernel<<<1, 256, 0, stream>>>(part, 8, 256, b5, g5, be5, 1, h5, 256);
    skinny_gemm_kernel<32><<<dim3(1, 2), 256, 0, stream>>>(h5, W6, part, 256, 40);
    fin_kernel<<<1, 256, 0, stream>>>(part, 8, 40, b6, nullptr, nullptr, 0, out, 40);
}

// Round 8
// 1247.068 us; speedup vs baseline: 3.8941x; 1.1382x over previous
//
#include <hip/hip_runtime.h>
#include <float.h>
#include <math.h>

namespace {

constexpr int NB = 16;
constexpr int NP = 2048;
constexpr int KK = 20;
constexpr int TOT = NB * NP;   // 32768
constexpr int EBLK = 1024;     // edge pass grid

typedef short short8v __attribute__((ext_vector_type(8)));   // 8 bf16 (4 VGPRs)
typedef float f32x16 __attribute__((ext_vector_type(16)));

__device__ __forceinline__ float leaky(float v) { return fmaxf(v, 0.2f * v); }

__device__ __forceinline__ unsigned short bf16_rne(float x) {
    unsigned u = __float_as_uint(x);
    unsigned r = u + 0x7FFFu + ((u >> 16) & 1u);
    return (unsigned short)(r >> 16);
}
__device__ __forceinline__ float bf16_f(unsigned short h) {
    return __uint_as_float(((unsigned)h) << 16);
}

// ---------------- pos -> pos4 (pad to 4 comps) ----------------
__global__ __launch_bounds__(256) void pos4_kernel(const float* __restrict__ pos,
                                                   float* __restrict__ pos4) {
    int i = blockIdx.x * 256 + threadIdx.x;
    if (i < TOT) {
        pos4[i * 4 + 0] = pos[i * 3 + 0];
        pos4[i * 4 + 1] = pos[i * 3 + 1];
        pos4[i * 4 + 2] = pos[i * 3 + 2];
        pos4[i * 4 + 3] = 0.f;
    }
}

// ---------------- squared norms (float4 rows) ----------------
__global__ __launch_bounds__(256) void sq4_kernel(const float* __restrict__ x, int ldx, int nj4,
                                                  float* __restrict__ sq) {
    int i = blockIdx.x * 256 + threadIdx.x;
    if (i < TOT) {
        const float4* r = reinterpret_cast<const float4*>(x + (size_t)i * ldx);
        float s = 0.f;
        for (int j4 = 0; j4 < nj4; ++j4) {
            float4 v = r[j4];
            s += v.x * v.x + v.y * v.y + v.z * v.z + v.w * v.w;
        }
        sq[i] = s;
    }
}

// ---------------- distance GEMM -> monotone uint keys ----------------
// 128x128 tile, 8x8/thread, k-major LDS with XOR swizzle:
// element (k, r) stored at Ak[k][r ^ (((k>>2)&3)<<3)].
// Writes: bank = (r ^ 8*(c4&3)) -> 32 distinct banks over 64 lanes (free).
// Reads: contiguous float4 (16B aligned since swizzle is a multiple of 8 floats).
template <int KTOT>
__global__ __launch_bounds__(256) void dist_gemm_kernel(const float* __restrict__ x, int ldx,
                                                        const float* __restrict__ sq,
                                                        int b0,
                                                        unsigned* __restrict__ keys) {
    constexpr int KC = (KTOT < 32) ? KTOT : 32;
    constexpr int F4 = KC / 4;
    __shared__ float Ak[KC][128];
    __shared__ float Bk[KC][128];
    const int tid = threadIdx.x;
    const int tr = tid >> 4, tc = tid & 15;
    const int m0 = blockIdx.y * 128, n0 = blockIdx.x * 128;
    const int bofs = (b0 + blockIdx.z) * NP;
    const float* xb = x + (size_t)bofs * ldx;
    float acc[8][8] = {};
    for (int k0 = 0; k0 < KTOT; k0 += KC) {
        __syncthreads();
        for (int i = tid; i < 128 * F4; i += 256) {
            const int r = i / F4, c4 = i % F4;
            const int rs = r ^ ((c4 & 3) << 3);
            float4 v = *reinterpret_cast<const float4*>(xb + (size_t)(m0 + r) * ldx + k0 + c4 * 4);
            Ak[c4 * 4 + 0][rs] = v.x; Ak[c4 * 4 + 1][rs] = v.y;
            Ak[c4 * 4 + 2][rs] = v.z; Ak[c4 * 4 + 3][rs] = v.w;
        }
        for (int i = tid; i < 128 * F4; i += 256) {
            const int r = i / F4, c4 = i % F4;
            const int rs = r ^ ((c4 & 3) << 3);
            float4 v = *reinterpret_cast<const float4*>(xb + (size_t)(n0 + r) * ldx + k0 + c4 * 4);
            Bk[c4 * 4 + 0][rs] = v.x; Bk[c4 * 4 + 1][rs] = v.y;
            Bk[c4 * 4 + 2][rs] = v.z; Bk[c4 * 4 + 3][rs] = v.w;
        }
        __syncthreads();
        #pragma unroll
        for (int k = 0; k < KC; ++k) {
            const int sw = ((k >> 2) & 3) << 3;
            const int ia = (tr * 4) ^ sw;
            const int ib = (tc * 4) ^ sw;
            float4 al = *reinterpret_cast<const float4*>(&Ak[k][ia]);
            float4 ah = *reinterpret_cast<const float4*>(&Ak[k][64 + ia]);
            float4 bl = *reinterpret_cast<const float4*>(&Bk[k][ib]);
            float4 bh = *reinterpret_cast<const float4*>(&Bk[k][64 + ib]);
            float a[8] = {al.x, al.y, al.z, al.w, ah.x, ah.y, ah.z, ah.w};
            float bv[8] = {bl.x, bl.y, bl.z, bl.w, bh.x, bh.y, bh.z, bh.w};
            #pragma unroll
            for (int i = 0; i < 8; ++i)
                #pragma unroll
                for (int j = 0; j < 8; ++j)
                    acc[i][j] += a[i] * bv[j];
        }
    }
    float sa[8], sb[8];
    #pragma unroll
    for (int i = 0; i < 8; ++i) sa[i] = sq[bofs + m0 + ((i < 4) ? tr * 4 + i : 64 + tr * 4 + i - 4)];
    #pragma unroll
    for (int j = 0; j < 8; ++j) sb[j] = sq[bofs + n0 + ((j < 4) ? tc * 4 + j : 64 + tc * 4 + j - 4)];
    #pragma unroll
    for (int i = 0; i < 8; ++i) {
        const int row = (i < 4) ? tr * 4 + i : 64 + tr * 4 + i - 4;
        unsigned* kr = keys + ((size_t)blockIdx.z * NP + m0 + row) * NP + n0;
        unsigned kk[8];
        #pragma unroll
        for (int j = 0; j < 8; ++j) {
            float d = sa[i] + sb[j] - 2.f * acc[i][j];
            unsigned bits = __float_as_uint(d);
            kk[j] = (bits & 0x80000000u) ? ~bits : (bits | 0x80000000u);
        }
        *reinterpret_cast<uint4*>(kr + tc * 4) = make_uint4(kk[0], kk[1], kk[2], kk[3]);
        *reinterpret_cast<uint4*>(kr + 64 + tc * 4) = make_uint4(kk[4], kk[5], kk[6], kk[7]);
    }
}

// ---------------- kNN select: ballot binary search, wave per query ----------------
__global__ __launch_bounds__(256) void knn_select_kernel(const unsigned* __restrict__ keys,
                                                         int b0,
                                                         int* __restrict__ idx_out) {
    const int tid = threadIdx.x;
    const int w = tid >> 6, lane = tid & 63;
    const int ql = blockIdx.x * 4 + w;        // chunk-local query
    const int bc = ql / NP;
    const int b = b0 + bc;
    const int bofs = b * NP;
    const unsigned* kr = keys + (size_t)ql * NP;

    unsigned keysr[32];
    #pragma unroll
    for (int u = 0; u < 32; ++u) keysr[u] = kr[u * 64 + lane];

    unsigned lmn = 0xFFFFFFFFu;
    #pragma unroll
    for (int u = 0; u < 32; ++u) lmn = min(lmn, keysr[u]);
    unsigned M = lmn, lo = lmn;
    #pragma unroll
    for (int off = 1; off < 64; off <<= 1) {
        unsigned tM = __shfl_xor(M, off);
        unsigned tl = __shfl_xor(lo, off);
        M = max(M, tM);
        lo = min(lo, tl);
    }
    unsigned hi = M;
    while (lo < hi) {
        unsigned mid = lo + ((hi - lo) >> 1);
        int cnt = 0;
        #pragma unroll
        for (int u = 0; u < 32; ++u)
            cnt += __popcll(__ballot(keysr[u] <= mid));
        if (cnt >= KK) hi = mid; else lo = mid + 1;
    }
    const unsigned T = lo;

    unsigned nl = 0;
    #pragma unroll
    for (int u = 0; u < 32; ++u) nl += (keysr[u] < T) ? 1u : 0u;
    unsigned sc2 = nl;
    #pragma unroll
    for (int off = 1; off < 64; off <<= 1) {
        unsigned t = __shfl_up(sc2, off);
        if (lane >= off) sc2 += t;
    }
    unsigned cstrict = __shfl(sc2, 63);
    unsigned o = sc2 - nl;
    int* op = idx_out + (size_t)(bofs + (ql - bc * NP)) * KK;
    #pragma unroll
    for (int u = 0; u < 32; ++u) {
        if (keysr[u] < T) { op[o] = bofs + u * 64 + lane; ++o; }
    }
    int rem = KK - (int)cstrict;
    int ebase = (int)cstrict;
    #pragma unroll
    for (int u = 0; u < 32; ++u) {
        if (rem > 0) {
            bool eq = (keysr[u] == T);
            unsigned long long bm = __ballot(eq);
            int before = __popcll(bm & ((1ull << lane) - 1ull));
            if (eq && before < rem) op[ebase + before] = bofs + u * 64 + lane;
            int take = __popcll(bm);
            if (take > rem) take = rem;
            ebase += take;
            rem -= take;
        }
    }
}

// ---------------- Wt[c][j] build: [Wd | Wtail] transposed, zero-padded ----------------
__global__ __launch_bounds__(256) void wt_build_kernel(const float* __restrict__ W,
                                                       float* __restrict__ Wt,
                                                       int D, int Dp, int C) {
    int i = blockIdx.x * 256 + threadIdx.x;
    if (i < 2 * C * Dp) {
        int c = i / Dp, j = i % Dp;
        float v = 0.f;
        if (j < D) {
            v = (c < C) ? (W[j * C + c] - W[(D + j) * C + c])
                        : W[(D + j) * C + (c - C)];
        }
        Wt[i] = v;
    }
}

// ---------------- X[TOT,Dp] @ Wt^T -> basexw[TOT,2C] ----------------
template <int NJ4, int C2>
__global__ __launch_bounds__(256) void xw_gemm_kernel(const float* __restrict__ x, int ldx,
                                                      const float* __restrict__ Wt,
                                                      float* __restrict__ bx) {
    constexpr int PG = 256 / C2;   // point groups
    constexpr int PTS = 16 / PG;   // points per thread
    __shared__ float4 Xs[16][NJ4];
    const int tid = threadIdx.x;
    const int p0 = blockIdx.x * 16;
    for (int i = tid; i < 16 * NJ4; i += 256) {
        int r = i / NJ4, j4 = i % NJ4;
        Xs[r][j4] = *reinterpret_cast<const float4*>(x + (size_t)(p0 + r) * ldx + j4 * 4);
    }
    __syncthreads();
    const int c = tid % C2, pg = tid / C2;
    const float4* wrow = reinterpret_cast<const float4*>(Wt + (size_t)c * (NJ4 * 4));
    float acc[PTS];
    #pragma unroll
    for (int u = 0; u < PTS; ++u) acc[u] = 0.f;
    #pragma unroll
    for (int j4 = 0; j4 < NJ4; ++j4) {
        float4 w4 = wrow[j4];
        #pragma unroll
        for (int u = 0; u < PTS; ++u) {
            float4 x4 = Xs[pg * PTS + u][j4];
            acc[u] += x4.x * w4.x + x4.y * w4.y + x4.z * w4.z + x4.w * w4.w;
        }
    }
    #pragma unroll
    for (int u = 0; u < PTS; ++u)
        bx[(size_t)(p0 + pg * PTS + u) * C2 + c] = acc[u];
}

// ---------------- edge pass: gather XW, stats + per-point max/min ----------------
template <int C>
__global__ __launch_bounds__(256) void edge_pass_kernel(const float* __restrict__ bx,
                                                        const int* __restrict__ idx,
                                                        float* __restrict__ psum,
                                                        float* __restrict__ psum2,
                                                        float* __restrict__ mmax,
                                                        float* __restrict__ mmin) {
    constexpr int PT = 256 / C;
    constexpr int C2 = 2 * C;
    __shared__ int sidx[PT][KK];
    __shared__ float red[256];
    const int tid = threadIdx.x;
    const int c = tid % C;
    const int pl = tid / C;
    float s1 = 0.f, s2 = 0.f;
    const int NT = TOT / PT;
    for (int t = blockIdx.x; t < NT; t += EBLK) {
        const int p0 = t * PT;
        __syncthreads();
        if (tid < PT * KK) sidx[tid / KK][tid % KK] = idx[(size_t)p0 * KK + tid];
        __syncthreads();
        const int p = p0 + pl;
        const float bv = bx[(size_t)p * C2 + c];
        float A = 0.f, Q = 0.f, M = -FLT_MAX, mn = FLT_MAX;
        #pragma unroll
        for (int k = 0; k < KK; ++k) {
            float v = bx[(size_t)sidx[pl][k] * C2 + C + c];
            A += v; Q += v * v; M = fmaxf(M, v); mn = fminf(mn, v);
        }
        s1 += (float)KK * bv + A;
        s2 += (float)KK * bv * bv + 2.f * bv * A + Q;
        mmax[(size_t)p * C + c] = bv + M;
        mmin[(size_t)p * C + c] = bv + mn;
    }
    red[tid] = s1;
    __syncthreads();
    if (tid < C) {
        float v = red[tid];
        #pragma unroll
        for (int u = 1; u < PT; ++u) v += red[tid + u * C];
        psum[(size_t)blockIdx.x * C + tid] = v;
    }
    __syncthreads();
    red[tid] = s2;
    __syncthreads();
    if (tid < C) {
        float v = red[tid];
        #pragma unroll
        for (int u = 1; u < PT; ++u) v += red[tid + u * C];
        psum2[(size_t)blockIdx.x * C + tid] = v;
    }
}

// ---------------- BN stats reduce -> alpha/beta ----------------
__global__ __launch_bounds__(256) void bn_reduce_kernel(
        const float* __restrict__ psum, const float* __restrict__ psum2,
        int npart, int C, const float* __restrict__ g, const float* __restrict__ bb,
        float inv_cnt, float* __restrict__ alpha, float* __restrict__ beta) {
    const int c = blockIdx.x;
    const int tid = threadIdx.x;
    __shared__ float r1[256], r2[256];
    float s1 = 0.f, s2 = 0.f;
    for (int i = tid; i < npart; i += 256) {
        s1 += psum[(size_t)i * C + c];
        s2 += psum2[(size_t)i * C + c];
    }
    r1[tid] = s1; r2[tid] = s2;
    __syncthreads();
    for (int s = 128; s > 0; s >>= 1) {
        if (tid < s) { r1[tid] += r1[tid + s]; r2[tid] += r2[tid + s]; }
        __syncthreads();
    }
    if (tid == 0) {
        float mean = r1[0] * inv_cnt;
        float var = r2[0] * inv_cnt - mean * mean;
        float a = g[c] * rsqrtf(var + 1e-5f);
        alpha[c] = a;
        beta[c] = bb[c] - mean * a;
    }
}

// ---------------- edge finalize: pick by sign(alpha), affine+leaky; write f32 + bf16 hi/lo ----------------
template <int C>
__global__ __launch_bounds__(256) void edge_finalize_kernel(const float* __restrict__ mmax,
                                                            const float* __restrict__ mmin,
                                                            const float* __restrict__ alpha,
                                                            const float* __restrict__ beta,
                                                            float* __restrict__ xcf, int ldf,
                                                            unsigned short* __restrict__ xch,
                                                            unsigned short* __restrict__ xcl,
                                                            int ch_off) {
    constexpr int CQ = C / 4;
    int i4 = blockIdx.x * 256 + threadIdx.x;
    if (i4 < TOT * CQ) {
        int p = i4 / CQ, cq = i4 - p * CQ;
        float4 M4 = reinterpret_cast<const float4*>(mmax)[i4];
        float4 m4 = reinterpret_cast<const float4*>(mmin)[i4];
        float4 a4 = reinterpret_cast<const float4*>(alpha)[cq];
        float4 b4 = reinterpret_cast<const float4*>(beta)[cq];
        float4 o;
        o.x = leaky(a4.x * (a4.x >= 0.f ? M4.x : m4.x) + b4.x);
        o.y = leaky(a4.y * (a4.y >= 0.f ? M4.y : m4.y) + b4.y);
        o.z = leaky(a4.z * (a4.z >= 0.f ? M4.z : m4.z) + b4.z);
        o.w = leaky(a4.w * (a4.w >= 0.f ? M4.w : m4.w) + b4.w);
        if (xcf)
            *reinterpret_cast<float4*>(xcf + (size_t)p * ldf + cq * 4) = o;
        ushort4 hh, ll;
        hh.x = bf16_rne(o.x); ll.x = bf16_rne(o.x - bf16_f(hh.x));
        hh.y = bf16_rne(o.y); ll.y = bf16_rne(o.y - bf16_f(hh.y));
        hh.z = bf16_rne(o.z); ll.z = bf16_rne(o.z - bf16_f(hh.z));
        hh.w = bf16_rne(o.w); ll.w = bf16_rne(o.w - bf16_f(hh.w));
        const size_t oo = (size_t)p * 256 + ch_off + cq * 4;
        *reinterpret_cast<ushort4*>(xch + oo) = hh;
        *reinterpret_cast<ushort4*>(xcl + oo) = ll;
    }
}

// ---------------- Wf -> bf16 hi/lo, transposed to [1024][256] ----------------
__global__ __launch_bounds__(256) void wfhl_build_kernel(const float* __restrict__ Wf,
                                                         unsigned short* __restrict__ wfh,
                                                         unsigned short* __restrict__ wfl) {
    int i = blockIdx.x * 256 + threadIdx.x;
    if (i < 256 * 1024) {
        int e = i / 1024, o = i - e * 1024;
        float v = Wf[i];
        unsigned short h = bf16_rne(v);
        wfh[(size_t)o * 256 + e] = h;
        wfl[(size_t)o * 256 + e] = bf16_rne(v - bf16_f(h));
    }
}

// ---------------- conv_final via MFMA bf16x3 + stat partials ----------------
// block 256 thr = 4 waves; 128 pts x 128 ch tile; wave (wr,wc) owns 64x64 via
// 2x2 frags of 32x32x16 bf16. acc += ah*bh + ah*bl + al*bh (ll term dropped).
__global__ __launch_bounds__(256) void fc_mfma_kernel(const unsigned short* __restrict__ xch,
                                                      const unsigned short* __restrict__ xcl,
                                                      const unsigned short* __restrict__ wfh,
                                                      const unsigned short* __restrict__ wfl,
                                                      float* __restrict__ psum,
                                                      float* __restrict__ psum2,
                                                      float* __restrict__ pmax,
                                                      float* __restrict__ pmin) {
    __shared__ __align__(16) unsigned short Ah[128 * 64];
    __shared__ __align__(16) unsigned short Al[128 * 64];
    __shared__ __align__(16) unsigned short Bh[128 * 64];
    __shared__ __align__(16) unsigned short Bl[128 * 64];
    const int tid = threadIdx.x;
    const int w = tid >> 6, lane = tid & 63;
    const int wr = w >> 1, wc = w & 1;
    const int pt = blockIdx.x, ct = blockIdx.y;
    f32x16 acc00 = {}, acc01 = {}, acc10 = {}, acc11 = {};
    for (int kc = 0; kc < 4; ++kc) {
        const int k0 = kc * 64;
        __syncthreads();
        for (int i = tid; i < 1024; i += 256) {
            const int r = i >> 3, slot = i & 7;
            const int ls = r * 64 + ((slot ^ (r & 7)) << 3);   // ushort index, 16B granule
            const size_t ga = (size_t)(pt * 128 + r) * 256 + k0 + slot * 8;
            const size_t gb = (size_t)(ct * 128 + r) * 256 + k0 + slot * 8;
            *reinterpret_cast<uint4*>(&Ah[ls]) = *reinterpret_cast<const uint4*>(&xch[ga]);
            *reinterpret_cast<uint4*>(&Al[ls]) = *reinterpret_cast<const uint4*>(&xcl[ga]);
            *reinterpret_cast<uint4*>(&Bh[ls]) = *reinterpret_cast<const uint4*>(&wfh[gb]);
            *reinterpret_cast<uint4*>(&Bl[ls]) = *reinterpret_cast<const uint4*>(&wfl[gb]);
        }
        __syncthreads();
        const int h = lane >> 5;
        const int ar0 = wr * 64 + (lane & 31), ar1 = ar0 + 32;
        const int bc0 = wc * 64 + (lane & 31), bc1 = bc0 + 32;
        #pragma unroll
        for (int s = 0; s < 4; ++s) {
            const int sl = s * 2 + h;
            const int ia0 = ar0 * 64 + ((sl ^ (ar0 & 7)) << 3);
            const int ia1 = ar1 * 64 + ((sl ^ (ar1 & 7)) << 3);
            const int ib0 = bc0 * 64 + ((sl ^ (bc0 & 7)) << 3);
            const int ib1 = bc1 * 64 + ((sl ^ (bc1 & 7)) << 3);
            short8v a0h = *reinterpret_cast<const short8v*>(&Ah[ia0]);
            short8v a1h = *reinterpret_cast<const short8v*>(&Ah[ia1]);
            short8v a0l = *reinterpret_cast<const short8v*>(&Al[ia0]);
            short8v a1l = *reinterpret_cast<const short8v*>(&Al[ia1]);
            short8v b0h = *reinterpret_cast<const short8v*>(&Bh[ib0]);
            short8v b1h = *reinterpret_cast<const short8v*>(&Bh[ib1]);
            short8v b0l = *reinterpret_cast<const short8v*>(&Bl[ib0]);
            short8v b1l = *reinterpret_cast<const short8v*>(&Bl[ib1]);
            acc00 = __builtin_amdgcn_mfma_f32_32x32x16_bf16(a0h, b0h, acc00, 0, 0, 0);
            acc01 = __builtin_amdgcn_mfma_f32_32x32x16_bf16(a0h, b1h, acc01, 0, 0, 0);
            acc10 = __builtin_amdgcn_mfma_f32_32x32x16_bf16(a1h, b0h, acc10, 0, 0, 0);
            acc11 = __builtin_amdgcn_mfma_f32_32x32x16_bf16(a1h, b1h, acc11, 0, 0, 0);
            acc00 = __builtin_amdgcn_mfma_f32_32x32x16_bf16(a0h, b0l, acc00, 0, 0, 0);
            acc01 = __builtin_amdgcn_mfma_f32_32x32x16_bf16(a0h, b1l, acc01, 0, 0, 0);
            acc10 = __builtin_amdgcn_mfma_f32_32x32x16_bf16(a1h, b0l, acc10, 0, 0, 0);
            acc11 = __builtin_amdgcn_mfma_f32_32x32x16_bf16(a1h, b1l, acc11, 0, 0, 0);
            acc00 = __builtin_amdgcn_mfma_f32_32x32x16_bf16(a0l, b0h, acc00, 0, 0, 0);
            acc01 = __builtin_amdgcn_mfma_f32_32x32x16_bf16(a0l, b1h, acc01, 0, 0, 0);
            acc10 = __builtin_amdgcn_mfma_f32_32x32x16_bf16(a1l, b0h, acc10, 0, 0, 0);
            acc11 = __builtin_amdgcn_mfma_f32_32x32x16_bf16(a1l, b1h, acc11, 0, 0, 0);
        }
    }
    // stats: every value in accXY belongs to channel col = lane&31 of its fc group.
    float* red = reinterpret_cast<float*>(Ah);   // [2 wr][128 ch][4 stats]
    __syncthreads();
    #pragma unroll
    for (int fc = 0; fc < 2; ++fc) {
        float s1 = 0.f, s2 = 0.f, mx = -FLT_MAX, mn = FLT_MAX;
        #pragma unroll
        for (int e = 0; e < 16; ++e) {
            float v0 = (fc == 0) ? acc00[e] : acc01[e];
            float v1 = (fc == 0) ? acc10[e] : acc11[e];
            s1 += v0 + v1;
            s2 += v0 * v0 + v1 * v1;
            mx = fmaxf(mx, fmaxf(v0, v1));
            mn = fminf(mn, fminf(v0, v1));
        }
        s1 += __shfl_xor(s1, 32);
        s2 += __shfl_xor(s2, 32);
        mx = fmaxf(mx, __shfl_xor(mx, 32));
        mn = fminf(mn, __shfl_xor(mn, 32));
        if (lane < 32) {
            const int ch = wc * 64 + fc * 32 + lane;
            float4 st; st.x = s1; st.y = s2; st.z = mx; st.w = mn;
            *reinterpret_cast<float4*>(&red[(wr * 128 + ch) * 4]) = st;
        }
    }
    __syncthreads();
    if (tid < 128) {
        float4 s0 = *reinterpret_cast<const float4*>(&red[tid * 4]);
        float4 s1 = *reinterpret_cast<const float4*>(&red[(128 + tid) * 4]);
        const size_t go = (size_t)pt * 1024 + ct * 128 + tid;
        psum[go]  = s0.x + s1.x;
        psum2[go] = s0.y + s1.y;
        pmax[go]  = fmaxf(s0.z, s1.z);
        pmin[go]  = fminf(s0.w, s1.w);
    }
}

// ---------------- gfeat finalize (16 point-tile partials per batch) ----------------
__global__ __launch_bounds__(256) void gfeat_final_kernel(const float* __restrict__ pmax,
                                                          const float* __restrict__ pmin,
                                                          const float* __restrict__ alpha,
                                                          const float* __restrict__ beta,
                                                          float* __restrict__ gfeat) {
    int i = blockIdx.x * 256 + threadIdx.x;
    if (i < NB * 1024) {
        int b = i >> 10, c = i & 1023;
        float mx = -FLT_MAX, mn = FLT_MAX;
        for (int j = 0; j < 16; ++j) {
            size_t o = (size_t)(b * 16 + j) * 1024 + c;
            mx = fmaxf(mx, pmax[o]);
            mn = fminf(mn, pmin[o]);
        }
        float a = alpha[c];
        gfeat[i] = leaky(a * (a >= 0.f ? mx : mn) + beta[c]);
    }
}

// ---------------- classifier: split-K skinny GEMM, A is [16][K] ----------------
template <int CHUNK>
__global__ __launch_bounds__(256) void skinny_gemm_kernel(const float* __restrict__ A,
                                                          const float* __restrict__ W,
                                                          float* __restrict__ part,
                                                          int K, int N) {
    __shared__ float Asub[4][16][CHUNK];
    const int tid = threadIdx.x;
    const int g = tid >> 6, lane = tid & 63;
    const int c = blockIdx.x * 64 + lane;
    const int ks = blockIdx.y * 4 + g;
    const int e0 = ks * CHUNK;
    for (int i = lane; i < 16 * CHUNK; i += 64) {
        const int m = i / CHUNK, el = i - m * CHUNK;
        Asub[g][m][el] = A[(size_t)m * K + e0 + el];
    }
    if (c < N) {
        float acc[16];
        #pragma unroll
        for (int m = 0; m < 16; ++m) acc[m] = 0.f;
        #pragma unroll 4
        for (int el = 0; el < CHUNK; ++el) {
            float w = W[(size_t)(e0 + el) * N + c];
            #pragma unroll
            for (int m = 0; m < 16; ++m) acc[m] += Asub[g][m][el] * w;
        }
        #pragma unroll
        for (int m = 0; m < 16; ++m)
            part[((size_t)ks * 16 + m) * N + c] = acc[m];
    }
}

// ---------------- classifier finish: reduce splits + bias (+BN over rows + leaky) ----------------
__global__ __launch_bounds__(256) void fin_kernel(const float* __restrict__ part,
                                                  int S, int N,
                                                  const float* __restrict__ bias,
                                                  const float* __restrict__ g,
                                                  const float* __restrict__ bb,
                                                  int do_bn,
                                                  float* __restrict__ out, int Nout) {
    int c = blockIdx.x * 256 + threadIdx.x;
    if (c >= N) return;
    float z[16];
    #pragma unroll
    for (int m = 0; m < 16; ++m) z[m] = bias[c];
    for (int s = 0; s < S; ++s)
        #pragma unroll
        for (int m = 0; m < 16; ++m) z[m] += part[((size_t)s * 16 + m) * N + c];
    if (do_bn) {
        float s1 = 0.f, s2 = 0.f;
        #pragma unroll
        for (int m = 0; m < 16; ++m) { s1 += z[m]; s2 += z[m] * z[m]; }
        float mean = s1 * (1.f / 16.f);
        float var = s2 * (1.f / 16.f) - mean * mean;
        float a = g[c] * rsqrtf(var + 1e-5f);
        float be = bb[c] - mean * a;
        #pragma unroll
        for (int m = 0; m < 16; ++m) out[(size_t)m * N + c] = leaky(a * z[m] + be);
    } else {
        if (c < Nout)
            #pragma unroll
            for (int m = 0; m < 16; ++m) out[(size_t)m * Nout + c] = z[m];
    }
}

static void run_knn(const float* x, int ldx, int nk, const float* sq, unsigned* keys,
                    int CB, int* idx, hipStream_t stream) {
    for (int b0 = 0; b0 < NB; b0 += CB) {
        dim3 g(NP / 128, NP / 128, CB);
        if (nk == 4)
            dist_gemm_kernel<4><<<g, 256, 0, stream>>>(x, ldx, sq, b0, keys);
        else
            dist_gemm_kernel<64><<<g, 256, 0, stream>>>(x, ldx, sq, b0, keys);
        knn_select_kernel<<<CB * NP / 4, 256, 0, stream>>>(keys, b0, idx);
    }
}

} // namespace

extern "C" void kernel_launch(void* const* d_in, const int* in_sizes, int n_in,
                              void* d_out, int out_size, void* d_ws, size_t ws_size,
                              hipStream_t stream) {
    (void)in_sizes; (void)n_in; (void)out_size;
    const float* pos = (const float*)d_in[0];
    const float* W1  = (const float*)d_in[1];
    const float* g1  = (const float*)d_in[2];
    const float* b1  = (const float*)d_in[3];
    const float* W2  = (const float*)d_in[4];
    const float* g2  = (const float*)d_in[5];
    const float* b2  = (const float*)d_in[6];
    const float* W3  = (const float*)d_in[7];
    const float* g3  = (const float*)d_in[8];
    const float* b3  = (const float*)d_in[9];
    const float* Wf  = (const float*)d_in[10];
    const float* gf  = (const float*)d_in[11];
    const float* bf  = (const float*)d_in[12];
    const float* W4  = (const float*)d_in[13];
    const float* b4  = (const float*)d_in[14];
    const float* g4  = (const float*)d_in[15];
    const float* be4 = (const float*)d_in[16];
    const float* W5  = (const float*)d_in[17];
    const float* b5  = (const float*)d_in[18];
    const float* g5  = (const float*)d_in[19];
    const float* be5 = (const float*)d_in[20];
    const float* W6  = (const float*)d_in[21];
    const float* b6  = (const float*)d_in[22];
    float* out = (float*)d_out;

    float* ws = (float*)d_ws;
    size_t off = 0;
    int*   idx    = (int*)ws;      off += (size_t)TOT * KK;          // 2.6 MB
    float* pos4   = ws + off;      off += (size_t)TOT * 4;
    float* sq     = ws + off;      off += (size_t)TOT;
    float* Wt     = ws + off;      off += 256 * 64;
    float* basexw = ws + off;      off += (size_t)TOT * 256;         // 32 MB
    float* mmax   = ws + off;      off += (size_t)TOT * 128;         // 16 MB
    float* mmin   = ws + off;      off += (size_t)TOT * 128;         // 16 MB
    float* xc12   = ws + off;      off += (size_t)TOT * 128;         // 16 MB (x1|x2 f32)
    unsigned short* xch = (unsigned short*)(ws + off); off += (size_t)TOT * 128;  // 16 MB bf16 hi
    unsigned short* xcl = (unsigned short*)(ws + off); off += (size_t)TOT * 128;  // 16 MB bf16 lo
    unsigned short* wfh = (unsigned short*)(ws + off); off += (size_t)1024 * 128;
    unsigned short* wfl = (unsigned short*)(ws + off); off += (size_t)1024 * 128;
    float* psum   = ws + off;      off += (size_t)512 * 1024;        // 2 MB
    float* psum2  = ws + off;      off += (size_t)512 * 1024;
    float* pmax   = ws + off;      off += (size_t)512 * 1024;
    float* pmin   = ws + off;      off += (size_t)512 * 1024;
    float* alpha  = ws + off;      off += 1024;
    float* beta   = ws + off;      off += 1024;
    float* gfeat  = ws + off;      off += NB * 1024;
    float* part   = ws + off;      off += 8 * 16 * 512;              // split-K partials
    float* h4     = ws + off;      off += NB * 512;
    float* h5     = ws + off;      off += NB * 256;
    unsigned* keys = (unsigned*)(ws + off);
    const size_t avail = (ws_size > off * 4) ? (ws_size - off * 4) : 0;
    const size_t per_batch = (size_t)NP * NP * 4;
    int CB = 1;
    for (int cb : {4, 2}) {        // cap at 4 so keys (64 MB) stay L3-resident
        if ((size_t)cb * per_batch <= avail) { CB = cb; break; }
    }

    const int npts_blk = (TOT + 255) / 256;

    // ---------- Layer 1 (D=3 padded to 4, C=64) ----------
    pos4_kernel<<<npts_blk, 256, 0, stream>>>(pos, pos4);
    sq4_kernel<<<npts_blk, 256, 0, stream>>>(pos4, 4, 1, sq);
    run_knn(pos4, 4, 4, sq, keys, CB, idx, stream);
    wt_build_kernel<<<2, 256, 0, stream>>>(W1, Wt, 3, 4, 64);
    xw_gemm_kernel<1, 128><<<TOT / 16, 256, 0, stream>>>(pos4, 4, Wt, basexw);
    edge_pass_kernel<64><<<EBLK, 256, 0, stream>>>(basexw, idx, psum, psum2, mmax, mmin);
    bn_reduce_kernel<<<64, 256, 0, stream>>>(psum, psum2, EBLK, 64, g1, b1,
                                             1.f / (float)(TOT * KK), alpha, beta);
    edge_finalize_kernel<64><<<TOT * 16 / 256, 256, 0, stream>>>(
        mmax, mmin, alpha, beta, xc12 + 0, 128, xch, xcl, 0);

    // ---------- Layer 2 (D=64, C=64), input x1 = xc12[:,0:64] ----------
    sq4_kernel<<<npts_blk, 256, 0, stream>>>(xc12 + 0, 128, 16, sq);
    run_knn(xc12 + 0, 128, 64, sq, keys, CB, idx, stream);
    wt_build_kernel<<<32, 256, 0, stream>>>(W2, Wt, 64, 64, 64);
    xw_gemm_kernel<16, 128><<<TOT / 16, 256, 0, stream>>>(xc12 + 0, 128, Wt, basexw);
    edge_pass_kernel<64><<<EBLK, 256, 0, stream>>>(basexw, idx, psum, psum2, mmax, mmin);
    bn_reduce_kernel<<<64, 256, 0, stream>>>(psum, psum2, EBLK, 64, g2, b2,
                                             1.f / (float)(TOT * KK), alpha, beta);
    edge_finalize_kernel<64><<<TOT * 16 / 256, 256, 0, stream>>>(
        mmax, mmin, alpha, beta, xc12 + 64, 128, xch, xcl, 64);

    // ---------- Layer 3 (D=64, C=128), input x2 = xc12[:,64:128] ----------
    sq4_kernel<<<npts_blk, 256, 0, stream>>>(xc12 + 64, 128, 16, sq);
    run_knn(xc12 + 64, 128, 64, sq, keys, CB, idx, stream);
    wt_build_kernel<<<64, 256, 0, stream>>>(W3, Wt, 64, 64, 128);
    xw_gemm_kernel<16, 256><<<TOT / 16, 256, 0, stream>>>(xc12 + 64, 128, Wt, basexw);
    edge_pass_kernel<128><<<EBLK, 256, 0, stream>>>(basexw, idx, psum, psum2, mmax, mmin);
    bn_reduce_kernel<<<128, 256, 0, stream>>>(psum, psum2, EBLK, 128, g3, b3,
                                              1.f / (float)(TOT * KK), alpha, beta);
    edge_finalize_kernel<128><<<TOT * 32 / 256, 256, 0, stream>>>(
        mmax, mmin, alpha, beta, nullptr, 0, xch, xcl, 128);

    // ---------- conv_final (MFMA bf16x3) + global max pool ----------
    wfhl_build_kernel<<<1024, 256, 0, stream>>>(Wf, wfh, wfl);
    {
        dim3 g(TOT / 128, 8, 1);
        fc_mfma_kernel<<<g, 256, 0, stream>>>(xch, xcl, wfh, wfl, psum, psum2, pmax, pmin);
    }
    bn_reduce_kernel<<<1024, 256, 0, stream>>>(psum, psum2, 256, 1024, gf, bf,
                                               1.f / (float)TOT, alpha, beta);
    gfeat_final_kernel<<<64, 256, 0, stream>>>(pmax, pmin, alpha, beta, gfeat);

    // ---------- classifier (split-K skinny GEMMs) ----------
    skinny_gemm_kernel<128><<<dim3(8, 2), 256, 0, stream>>>(gfeat, W4, part, 1024, 512);
    fin_kernel<<<2, 256, 0, stream>>>(part, 8, 512, b4, g4, be4, 1, h4, 512);
    skinny_gemm_kernel<64><<<dim3(4, 2), 256, 0, stream>>>(h4, W5, part, 512, 256);
    fin_kernel<<<1, 256, 0, stream>>>(part, 8, 256, b5, g5, be5, 1, h5, 256);
    skinny_gemm_kernel<32><<<dim3(1, 2), 256, 0, stream>>>(h5, W6, part, 256, 40);
    fin_kernel<<<1, 256, 0, stream>>>(part, 8, 40, b6, nullptr, nullptr, 0, out, 40);
}

// Round 9
// 1231.374 us; speedup vs baseline: 3.9438x; 1.0127x over previous
//
#include <hip/hip_runtime.h>
#include <float.h>
#include <math.h>

namespace {

constexpr int NB = 16;
constexpr int NP = 2048;
constexpr int KK = 20;
constexpr int TOT = NB * NP;   // 32768
constexpr int EBLK = 1024;     // edge pass grid

typedef short short8v __attribute__((ext_vector_type(8)));   // 8 bf16 (4 VGPRs)
typedef float f32x16 __attribute__((ext_vector_type(16)));

__device__ __forceinline__ float leaky(float v) { return fmaxf(v, 0.2f * v); }

__device__ __forceinline__ unsigned short bf16_rne(float x) {
    unsigned u = __float_as_uint(x);
    unsigned r = u + 0x7FFFu + ((u >> 16) & 1u);
    return (unsigned short)(r >> 16);
}
__device__ __forceinline__ float bf16_f(unsigned short h) {
    return __uint_as_float(((unsigned)h) << 16);
}
__device__ __forceinline__ unsigned mono_key(float d) {
    unsigned bits = __float_as_uint(d);
    return (bits & 0x80000000u) ? ~bits : (bits | 0x80000000u);
}

// ---------------- pos -> pos4 (pad to 4) + squared norm ----------------
__global__ __launch_bounds__(256) void pos4sq_kernel(const float* __restrict__ pos,
                                                     float* __restrict__ pos4,
                                                     float* __restrict__ sq) {
    int i = blockIdx.x * 256 + threadIdx.x;
    if (i < TOT) {
        float x = pos[i * 3 + 0], y = pos[i * 3 + 1], z = pos[i * 3 + 2];
        pos4[i * 4 + 0] = x;
        pos4[i * 4 + 1] = y;
        pos4[i * 4 + 2] = z;
        pos4[i * 4 + 3] = 0.f;
        sq[i] = x * x + y * y + z * z;
    }
}

// ---------------- symmetric distance GEMM -> monotone uint keys ----------------
// Lower-triangle 128x128 tiles (tm >= tn); each block writes its tile AND the
// transposed mirror (contiguous uint4 quads, no LDS). Values bitwise match a
// full-grid computation (add/mul commute, identical k-order).
template <int KTOT>
__global__ __launch_bounds__(256) void dist_sym_kernel(const float* __restrict__ x, int ldx,
                                                       const float* __restrict__ sq,
                                                       int b0,
                                                       unsigned* __restrict__ keys) {
    constexpr int KC = (KTOT < 32) ? KTOT : 32;
    constexpr int F4 = KC / 4;
    __shared__ float Ak[KC][128];
    __shared__ float Bk[KC][128];
    const int tid = threadIdx.x;
    const int tr = tid >> 4, tc = tid & 15;
    // triangle decode: t -> (tm >= tn)
    int tm = (int)((sqrtf(8.f * blockIdx.x + 1.f) - 1.f) * 0.5f);
    while ((tm + 1) * (tm + 2) / 2 <= (int)blockIdx.x) ++tm;
    while (tm * (tm + 1) / 2 > (int)blockIdx.x) --tm;
    const int tn = blockIdx.x - tm * (tm + 1) / 2;
    const int m0 = tm * 128, n0 = tn * 128;
    const int bofs = (b0 + blockIdx.y) * NP;
    const float* xb = x + (size_t)bofs * ldx;
    float acc[8][8] = {};
    for (int k0 = 0; k0 < KTOT; k0 += KC) {
        __syncthreads();
        for (int i = tid; i < 128 * F4; i += 256) {
            const int r = i / F4, c4 = i % F4;
            const int rs = r ^ ((c4 & 3) << 3);
            float4 v = *reinterpret_cast<const float4*>(xb + (size_t)(m0 + r) * ldx + k0 + c4 * 4);
            Ak[c4 * 4 + 0][rs] = v.x; Ak[c4 * 4 + 1][rs] = v.y;
            Ak[c4 * 4 + 2][rs] = v.z; Ak[c4 * 4 + 3][rs] = v.w;
        }
        for (int i = tid; i < 128 * F4; i += 256) {
            const int r = i / F4, c4 = i % F4;
            const int rs = r ^ ((c4 & 3) << 3);
            float4 v = *reinterpret_cast<const float4*>(xb + (size_t)(n0 + r) * ldx + k0 + c4 * 4);
            Bk[c4 * 4 + 0][rs] = v.x; Bk[c4 * 4 + 1][rs] = v.y;
            Bk[c4 * 4 + 2][rs] = v.z; Bk[c4 * 4 + 3][rs] = v.w;
        }
        __syncthreads();
        #pragma unroll
        for (int k = 0; k < KC; ++k) {
            const int sw = ((k >> 2) & 3) << 3;
            const int ia = (tr * 4) ^ sw;
            const int ib = (tc * 4) ^ sw;
            float4 al = *reinterpret_cast<const float4*>(&Ak[k][ia]);
            float4 ah = *reinterpret_cast<const float4*>(&Ak[k][64 + ia]);
            float4 bl = *reinterpret_cast<const float4*>(&Bk[k][ib]);
            float4 bh = *reinterpret_cast<const float4*>(&Bk[k][64 + ib]);
            float a[8] = {al.x, al.y, al.z, al.w, ah.x, ah.y, ah.z, ah.w};
            float bv[8] = {bl.x, bl.y, bl.z, bl.w, bh.x, bh.y, bh.z, bh.w};
            #pragma unroll
            for (int i = 0; i < 8; ++i)
                #pragma unroll
                for (int j = 0; j < 8; ++j)
                    acc[i][j] += a[i] * bv[j];
        }
    }
    float sa[8], sb[8];
    #pragma unroll
    for (int i = 0; i < 8; ++i) sa[i] = sq[bofs + m0 + ((i < 4) ? tr * 4 + i : 64 + tr * 4 + i - 4)];
    #pragma unroll
    for (int j = 0; j < 8; ++j) sb[j] = sq[bofs + n0 + ((j < 4) ? tc * 4 + j : 64 + tc * 4 + j - 4)];
    // direct writes (rows m-range, cols n-range)
    #pragma unroll
    for (int i = 0; i < 8; ++i) {
        const int row = (i < 4) ? tr * 4 + i : 64 + tr * 4 + i - 4;
        unsigned* kr = keys + ((size_t)blockIdx.y * NP + m0 + row) * NP + n0;
        unsigned kk[8];
        #pragma unroll
        for (int j = 0; j < 8; ++j) kk[j] = mono_key(sa[i] + sb[j] - 2.f * acc[i][j]);
        *reinterpret_cast<uint4*>(kr + tc * 4) = make_uint4(kk[0], kk[1], kk[2], kk[3]);
        *reinterpret_cast<uint4*>(kr + 64 + tc * 4) = make_uint4(kk[4], kk[5], kk[6], kk[7]);
    }
    // mirror writes (rows n-range, cols m-range) — contiguous quads per column
    if (tm != tn) {
        #pragma unroll
        for (int j = 0; j < 8; ++j) {
            const int col = (j < 4) ? tc * 4 + j : 64 + tc * 4 + j - 4;
            unsigned* mr = keys + ((size_t)blockIdx.y * NP + n0 + col) * NP + m0;
            unsigned lo[4], hi[4];
            #pragma unroll
            for (int i = 0; i < 4; ++i) {
                lo[i] = mono_key(sa[i] + sb[j] - 2.f * acc[i][j]);
                hi[i] = mono_key(sa[i + 4] + sb[j] - 2.f * acc[i + 4][j]);
            }
            *reinterpret_cast<uint4*>(mr + tr * 4) = make_uint4(lo[0], lo[1], lo[2], lo[3]);
            *reinterpret_cast<uint4*>(mr + 64 + tr * 4) = make_uint4(hi[0], hi[1], hi[2], hi[3]);
        }
    }
}

// ---------------- kNN select: ballot binary search, wave per query ----------------
__global__ __launch_bounds__(256) void knn_select_kernel(const unsigned* __restrict__ keys,
                                                         int b0,
                                                         int* __restrict__ idx_out) {
    const int tid = threadIdx.x;
    const int w = tid >> 6, lane = tid & 63;
    const int ql = blockIdx.x * 4 + w;        // chunk-local query
    const int bc = ql / NP;
    const int b = b0 + bc;
    const int bofs = b * NP;
    const unsigned* kr = keys + (size_t)ql * NP;

    unsigned keysr[32];
    #pragma unroll
    for (int u = 0; u < 32; ++u) keysr[u] = kr[u * 64 + lane];

    unsigned lmn = 0xFFFFFFFFu;
    #pragma unroll
    for (int u = 0; u < 32; ++u) lmn = min(lmn, keysr[u]);
    unsigned M = lmn, lo = lmn;
    #pragma unroll
    for (int off = 1; off < 64; off <<= 1) {
        unsigned tM = __shfl_xor(M, off);
        unsigned tl = __shfl_xor(lo, off);
        M = max(M, tM);
        lo = min(lo, tl);
    }
    unsigned hi = M;
    while (lo < hi) {
        unsigned mid = lo + ((hi - lo) >> 1);
        int cnt = 0;
        #pragma unroll
        for (int u = 0; u < 32; ++u)
            cnt += __popcll(__ballot(keysr[u] <= mid));
        if (cnt >= KK) hi = mid; else lo = mid + 1;
    }
    const unsigned T = lo;

    unsigned nl = 0;
    #pragma unroll
    for (int u = 0; u < 32; ++u) nl += (keysr[u] < T) ? 1u : 0u;
    unsigned sc2 = nl;
    #pragma unroll
    for (int off = 1; off < 64; off <<= 1) {
        unsigned t = __shfl_up(sc2, off);
        if (lane >= off) sc2 += t;
    }
    unsigned cstrict = __shfl(sc2, 63);
    unsigned o = sc2 - nl;
    int* op = idx_out + (size_t)(bofs + (ql - bc * NP)) * KK;
    #pragma unroll
    for (int u = 0; u < 32; ++u) {
        if (keysr[u] < T) { op[o] = bofs + u * 64 + lane; ++o; }
    }
    int rem = KK - (int)cstrict;
    int ebase = (int)cstrict;
    #pragma unroll
    for (int u = 0; u < 32; ++u) {
        if (rem > 0) {
            bool eq = (keysr[u] == T);
            unsigned long long bm = __ballot(eq);
            int before = __popcll(bm & ((1ull << lane) - 1ull));
            if (eq && before < rem) op[ebase + before] = bofs + u * 64 + lane;
            int take = __popcll(bm);
            if (take > rem) take = rem;
            ebase += take;
            rem -= take;
        }
    }
}

// ---------------- Wt[c][j] build: [Wd | Wtail] transposed, zero-padded ----------------
__global__ __launch_bounds__(256) void wt_build_kernel(const float* __restrict__ W,
                                                       float* __restrict__ Wt,
                                                       int D, int Dp, int C) {
    int i = blockIdx.x * 256 + threadIdx.x;
    if (i < 2 * C * Dp) {
        int c = i / Dp, j = i % Dp;
        float v = 0.f;
        if (j < D) {
            v = (c < C) ? (W[j * C + c] - W[(D + j) * C + c])
                        : W[(D + j) * C + (c - C)];
        }
        Wt[i] = v;
    }
}

// ---------------- X[TOT,Dp] @ Wt^T -> basexw[TOT,2C] ----------------
template <int NJ4, int C2>
__global__ __launch_bounds__(256) void xw_gemm_kernel(const float* __restrict__ x, int ldx,
                                                      const float* __restrict__ Wt,
                                                      float* __restrict__ bx) {
    constexpr int PG = 256 / C2;   // point groups
    constexpr int PTS = 16 / PG;   // points per thread
    __shared__ float4 Xs[16][NJ4];
    const int tid = threadIdx.x;
    const int p0 = blockIdx.x * 16;
    for (int i = tid; i < 16 * NJ4; i += 256) {
        int r = i / NJ4, j4 = i % NJ4;
        Xs[r][j4] = *reinterpret_cast<const float4*>(x + (size_t)(p0 + r) * ldx + j4 * 4);
    }
    __syncthreads();
    const int c = tid % C2, pg = tid / C2;
    const float4* wrow = reinterpret_cast<const float4*>(Wt + (size_t)c * (NJ4 * 4));
    float acc[PTS];
    #pragma unroll
    for (int u = 0; u < PTS; ++u) acc[u] = 0.f;
    #pragma unroll
    for (int j4 = 0; j4 < NJ4; ++j4) {
        float4 w4 = wrow[j4];
        #pragma unroll
        for (int u = 0; u < PTS; ++u) {
            float4 x4 = Xs[pg * PTS + u][j4];
            acc[u] += x4.x * w4.x + x4.y * w4.y + x4.z * w4.z + x4.w * w4.w;
        }
    }
    #pragma unroll
    for (int u = 0; u < PTS; ++u)
        bx[(size_t)(p0 + pg * PTS + u) * C2 + c] = acc[u];
}

// ---------------- edge pass: gather XW, stats + per-point max/min ----------------
template <int C>
__global__ __launch_bounds__(256) void edge_pass_kernel(const float* __restrict__ bx,
                                                        const int* __restrict__ idx,
                                                        float* __restrict__ psum,
                                                        float* __restrict__ psum2,
                                                        float* __restrict__ mmax,
                                                        float* __restrict__ mmin) {
    constexpr int PT = 256 / C;
    constexpr int C2 = 2 * C;
    __shared__ int sidx[PT][KK];
    __shared__ float red[256];
    const int tid = threadIdx.x;
    const int c = tid % C;
    const int pl = tid / C;
    float s1 = 0.f, s2 = 0.f;
    const int NT = TOT / PT;
    for (int t = blockIdx.x; t < NT; t += EBLK) {
        const int p0 = t * PT;
        __syncthreads();
        if (tid < PT * KK) sidx[tid / KK][tid % KK] = idx[(size_t)p0 * KK + tid];
        __syncthreads();
        const int p = p0 + pl;
        const float bv = bx[(size_t)p * C2 + c];
        float A = 0.f, Q = 0.f, M = -FLT_MAX, mn = FLT_MAX;
        #pragma unroll
        for (int k = 0; k < KK; ++k) {
            float v = bx[(size_t)sidx[pl][k] * C2 + C + c];
            A += v; Q += v * v; M = fmaxf(M, v); mn = fminf(mn, v);
        }
        s1 += (float)KK * bv + A;
        s2 += (float)KK * bv * bv + 2.f * bv * A + Q;
        mmax[(size_t)p * C + c] = bv + M;
        mmin[(size_t)p * C + c] = bv + mn;
    }
    red[tid] = s1;
    __syncthreads();
    if (tid < C) {
        float v = red[tid];
        #pragma unroll
        for (int u = 1; u < PT; ++u) v += red[tid + u * C];
        psum[(size_t)blockIdx.x * C + tid] = v;
    }
    __syncthreads();
    red[tid] = s2;
    __syncthreads();
    if (tid < C) {
        float v = red[tid];
        #pragma unroll
        for (int u = 1; u < PT; ++u) v += red[tid + u * C];
        psum2[(size_t)blockIdx.x * C + tid] = v;
    }
}

// ---------------- BN stats reduce -> alpha/beta ----------------
__global__ __launch_bounds__(256) void bn_reduce_kernel(
        const float* __restrict__ psum, const float* __restrict__ psum2,
        int npart, int C, const float* __restrict__ g, const float* __restrict__ bb,
        float inv_cnt, float* __restrict__ alpha, float* __restrict__ beta) {
    const int c = blockIdx.x;
    const int tid = threadIdx.x;
    __shared__ float r1[256], r2[256];
    float s1 = 0.f, s2 = 0.f;
    for (int i = tid; i < npart; i += 256) {
        s1 += psum[(size_t)i * C + c];
        s2 += psum2[(size_t)i * C + c];
    }
    r1[tid] = s1; r2[tid] = s2;
    __syncthreads();
    for (int s = 128; s > 0; s >>= 1) {
        if (tid < s) { r1[tid] += r1[tid + s]; r2[tid] += r2[tid + s]; }
        __syncthreads();
    }
    if (tid == 0) {
        float mean = r1[0] * inv_cnt;
        float var = r2[0] * inv_cnt - mean * mean;
        float a = g[c] * rsqrtf(var + 1e-5f);
        alpha[c] = a;
        beta[c] = bb[c] - mean * a;
    }
}

// ---------------- edge finalize: pick by sign(alpha), affine+leaky; f32 + bf16 hi/lo (+sq) ----------------
template <int C>
__global__ __launch_bounds__(256) void edge_finalize_kernel(const float* __restrict__ mmax,
                                                            const float* __restrict__ mmin,
                                                            const float* __restrict__ alpha,
                                                            const float* __restrict__ beta,
                                                            float* __restrict__ xcf, int ldf,
                                                            unsigned short* __restrict__ xch,
                                                            unsigned short* __restrict__ xcl,
                                                            int ch_off,
                                                            float* __restrict__ sq_out) {
    constexpr int CQ = C / 4;
    __shared__ float red[256];
    const int tid = threadIdx.x;
    int i4 = blockIdx.x * 256 + tid;
    float4 o = make_float4(0.f, 0.f, 0.f, 0.f);
    int p = 0;
    if (i4 < TOT * CQ) {
        int cq; p = i4 / CQ; cq = i4 - p * CQ;
        float4 M4 = reinterpret_cast<const float4*>(mmax)[i4];
        float4 m4 = reinterpret_cast<const float4*>(mmin)[i4];
        float4 a4 = reinterpret_cast<const float4*>(alpha)[cq];
        float4 b4 = reinterpret_cast<const float4*>(beta)[cq];
        o.x = leaky(a4.x * (a4.x >= 0.f ? M4.x : m4.x) + b4.x);
        o.y = leaky(a4.y * (a4.y >= 0.f ? M4.y : m4.y) + b4.y);
        o.z = leaky(a4.z * (a4.z >= 0.f ? M4.z : m4.z) + b4.z);
        o.w = leaky(a4.w * (a4.w >= 0.f ? M4.w : m4.w) + b4.w);
        if (xcf)
            *reinterpret_cast<float4*>(xcf + (size_t)p * ldf + cq * 4) = o;
        ushort4 hh, ll;
        hh.x = bf16_rne(o.x); ll.x = bf16_rne(o.x - bf16_f(hh.x));
        hh.y = bf16_rne(o.y); ll.y = bf16_rne(o.y - bf16_f(hh.y));
        hh.z = bf16_rne(o.z); ll.z = bf16_rne(o.z - bf16_f(hh.z));
        hh.w = bf16_rne(o.w); ll.w = bf16_rne(o.w - bf16_f(hh.w));
        const size_t oo = (size_t)p * 256 + ch_off + cq * 4;
        *reinterpret_cast<ushort4*>(xch + oo) = hh;
        *reinterpret_cast<ushort4*>(xcl + oo) = ll;
    }
    if (sq_out) {   // only used for C=64 (CQ=16, 16 pts/block, exact grid)
        red[tid] = o.x * o.x + o.y * o.y + o.z * o.z + o.w * o.w;
        __syncthreads();
        if ((tid & (CQ - 1)) == 0) {
            float s = red[tid];
            #pragma unroll
            for (int u = 1; u < CQ; ++u) s += red[tid + u];
            sq_out[p] = s;
        }
    }
}

// ---------------- Wf -> bf16 hi/lo, transposed to [1024][256] ----------------
__global__ __launch_bounds__(256) void wfhl_build_kernel(const float* __restrict__ Wf,
                                                         unsigned short* __restrict__ wfh,
                                                         unsigned short* __restrict__ wfl) {
    int i = blockIdx.x * 256 + threadIdx.x;
    if (i < 256 * 1024) {
        int e = i / 1024, o = i - e * 1024;
        float v = Wf[i];
        unsigned short h = bf16_rne(v);
        wfh[(size_t)o * 256 + e] = h;
        wfl[(size_t)o * 256 + e] = bf16_rne(v - bf16_f(h));
    }
}

// ---------------- conv_final via MFMA bf16x3 + stat partials ----------------
__global__ __launch_bounds__(256) void fc_mfma_kernel(const unsigned short* __restrict__ xch,
                                                      const unsigned short* __restrict__ xcl,
                                                      const unsigned short* __restrict__ wfh,
                                                      const unsigned short* __restrict__ wfl,
                                                      float* __restrict__ psum,
                                                      float* __restrict__ psum2,
                                                      float* __restrict__ pmax,
                                                      float* __restrict__ pmin) {
    __shared__ __align__(16) unsigned short Ah[128 * 64];
    __shared__ __align__(16) unsigned short Al[128 * 64];
    __shared__ __align__(16) unsigned short Bh[128 * 64];
    __shared__ __align__(16) unsigned short Bl[128 * 64];
    const int tid = threadIdx.x;
    const int w = tid >> 6, lane = tid & 63;
    const int wr = w >> 1, wc = w & 1;
    const int pt = blockIdx.x, ct = blockIdx.y;
    f32x16 acc00 = {}, acc01 = {}, acc10 = {}, acc11 = {};
    for (int kc = 0; kc < 4; ++kc) {
        const int k0 = kc * 64;
        __syncthreads();
        for (int i = tid; i < 1024; i += 256) {
            const int r = i >> 3, slot = i & 7;
            const int ls = r * 64 + ((slot ^ (r & 7)) << 3);
            const size_t ga = (size_t)(pt * 128 + r) * 256 + k0 + slot * 8;
            const size_t gb = (size_t)(ct * 128 + r) * 256 + k0 + slot * 8;
            *reinterpret_cast<uint4*>(&Ah[ls]) = *reinterpret_cast<const uint4*>(&xch[ga]);
            *reinterpret_cast<uint4*>(&Al[ls]) = *reinterpret_cast<const uint4*>(&xcl[ga]);
            *reinterpret_cast<uint4*>(&Bh[ls]) = *reinterpret_cast<const uint4*>(&wfh[gb]);
            *reinterpret_cast<uint4*>(&Bl[ls]) = *reinterpret_cast<const uint4*>(&wfl[gb]);
        }
        __syncthreads();
        const int h = lane >> 5;
        const int ar0 = wr * 64 + (lane & 31), ar1 = ar0 + 32;
        const int bc0 = wc * 64 + (lane & 31), bc1 = bc0 + 32;
        #pragma unroll
        for (int s = 0; s < 4; ++s) {
            const int sl = s * 2 + h;
            const int ia0 = ar0 * 64 + ((sl ^ (ar0 & 7)) << 3);
            const int ia1 = ar1 * 64 + ((sl ^ (ar1 & 7)) << 3);
            const int ib0 = bc0 * 64 + ((sl ^ (bc0 & 7)) << 3);
            const int ib1 = bc1 * 64 + ((sl ^ (bc1 & 7)) << 3);
            short8v a0h = *reinterpret_cast<const short8v*>(&Ah[ia0]);
            short8v a1h = *reinterpret_cast<const short8v*>(&Ah[ia1]);
            short8v a0l = *reinterpret_cast<const short8v*>(&Al[ia0]);
            short8v a1l = *reinterpret_cast<const short8v*>(&Al[ia1]);
            short8v b0h = *reinterpret_cast<const short8v*>(&Bh[ib0]);
            short8v b1h = *reinterpret_cast<const short8v*>(&Bh[ib1]);
            short8v b0l = *reinterpret_cast<const short8v*>(&Bl[ib0]);
            short8v b1l = *reinterpret_cast<const short8v*>(&Bl[ib1]);
            acc00 = __builtin_amdgcn_mfma_f32_32x32x16_bf16(a0h, b0h, acc00, 0, 0, 0);
            acc01 = __builtin_amdgcn_mfma_f32_32x32x16_bf16(a0h, b1h, acc01, 0, 0, 0);
            acc10 = __builtin_amdgcn_mfma_f32_32x32x16_bf16(a1h, b0h, acc10, 0, 0, 0);
            acc11 = __builtin_amdgcn_mfma_f32_32x32x16_bf16(a1h, b1h, acc11, 0, 0, 0);
            acc00 = __builtin_amdgcn_mfma_f32_32x32x16_bf16(a0h, b0l, acc00, 0, 0, 0);
            acc01 = __builtin_amdgcn_mfma_f32_32x32x16_bf16(a0h, b1l, acc01, 0, 0, 0);
            acc10 = __builtin_amdgcn_mfma_f32_32x32x16_bf16(a1h, b0l, acc10, 0, 0, 0);
            acc11 = __builtin_amdgcn_mfma_f32_32x32x16_bf16(a1h, b1l, acc11, 0, 0, 0);
            acc00 = __builtin_amdgcn_mfma_f32_32x32x16_bf16(a0l, b0h, acc00, 0, 0, 0);
            acc01 = __builtin_amdgcn_mfma_f32_32x32x16_bf16(a0l, b1h, acc01, 0, 0, 0);
            acc10 = __builtin_amdgcn_mfma_f32_32x32x16_bf16(a1l, b0h, acc10, 0, 0, 0);
            acc11 = __builtin_amdgcn_mfma_f32_32x32x16_bf16(a1l, b1h, acc11, 0, 0, 0);
        }
    }
    float* red = reinterpret_cast<float*>(Ah);   // [2 wr][128 ch][4 stats]
    __syncthreads();
    #pragma unroll
    for (int fc = 0; fc < 2; ++fc) {
        float s1 = 0.f, s2 = 0.f, mx = -FLT_MAX, mn = FLT_MAX;
        #pragma unroll
        for (int e = 0; e < 16; ++e) {
            float v0 = (fc == 0) ? acc00[e] : acc01[e];
            float v1 = (fc == 0) ? acc10[e] : acc11[e];
            s1 += v0 + v1;
            s2 += v0 * v0 + v1 * v1;
            mx = fmaxf(mx, fmaxf(v0, v1));
            mn = fminf(mn, fminf(v0, v1));
        }
        s1 += __shfl_xor(s1, 32);
        s2 += __shfl_xor(s2, 32);
        mx = fmaxf(mx, __shfl_xor(mx, 32));
        mn = fminf(mn, __shfl_xor(mn, 32));
        if (lane < 32) {
            const int ch = wc * 64 + fc * 32 + lane;
            float4 st; st.x = s1; st.y = s2; st.z = mx; st.w = mn;
            *reinterpret_cast<float4*>(&red[(wr * 128 + ch) * 4]) = st;
        }
    }
    __syncthreads();
    if (tid < 128) {
        float4 s0 = *reinterpret_cast<const float4*>(&red[tid * 4]);
        float4 s1 = *reinterpret_cast<const float4*>(&red[(128 + tid) * 4]);
        const size_t go = (size_t)pt * 1024 + ct * 128 + tid;
        psum[go]  = s0.x + s1.x;
        psum2[go] = s0.y + s1.y;
        pmax[go]  = fmaxf(s0.z, s1.z);
        pmin[go]  = fminf(s0.w, s1.w);
    }
}

// ---------------- gfeat finalize (16 point-tile partials per batch) ----------------
__global__ __launch_bounds__(256) void gfeat_final_kernel(const float* __restrict__ pmax,
                                                          const float* __restrict__ pmin,
                                                          const float* __restrict__ alpha,
                                                          const float* __restrict__ beta,
                                                          float* __restrict__ gfeat) {
    int i = blockIdx.x * 256 + threadIdx.x;
    if (i < NB * 1024) {
        int b = i >> 10, c = i & 1023;
        float mx = -FLT_MAX, mn = FLT_MAX;
        for (int j = 0; j < 16; ++j) {
            size_t o = (size_t)(b * 16 + j) * 1024 + c;
            mx = fmaxf(mx, pmax[o]);
            mn = fminf(mn, pmin[o]);
        }
        float a = alpha[c];
        gfeat[i] = leaky(a * (a >= 0.f ? mx : mn) + beta[c]);
    }
}

// ---------------- classifier: split-K skinny GEMM, A is [16][K] ----------------
template <int CHUNK>
__global__ __launch_bounds__(256) void skinny_gemm_kernel(const float* __restrict__ A,
                                                          const float* __restrict__ W,
                                                          float* __restrict__ part,
                                                          int K, int N) {
    __shared__ float Asub[4][16][CHUNK];
    const int tid = threadIdx.x;
    const int g = tid >> 6, lane = tid & 63;
    const int c = blockIdx.x * 64 + lane;
    const int ks = blockIdx.y * 4 + g;
    const int e0 = ks * CHUNK;
    for (int i = lane; i < 16 * CHUNK; i += 64) {
        const int m = i / CHUNK, el = i - m * CHUNK;
        Asub[g][m][el] = A[(size_t)m * K + e0 + el];
    }
    if (c < N) {
        float acc[16];
        #pragma unroll
        for (int m = 0; m < 16; ++m) acc[m] = 0.f;
        #pragma unroll 4
        for (int el = 0; el < CHUNK; ++el) {
            float w = W[(size_t)(e0 + el) * N + c];
            #pragma unroll
            for (int m = 0; m < 16; ++m) acc[m] += Asub[g][m][el] * w;
        }
        #pragma unroll
        for (int m = 0; m < 16; ++m)
            part[((size_t)ks * 16 + m) * N + c] = acc[m];
    }
}

// ---------------- classifier finish: reduce splits + bias (+BN over rows + leaky) ----------------
__global__ __launch_bounds__(256) void fin_kernel(const float* __restrict__ part,
                                                  int S, int N,
                                                  const float* __restrict__ bias,
                                                  const float* __restrict__ g,
                                                  const float* __restrict__ bb,
                                                  int do_bn,
                                                  float* __restrict__ out, int Nout) {
    int c = blockIdx.x * 256 + threadIdx.x;
    if (c >= N) return;
    float z[16];
    #pragma unroll
    for (int m = 0; m < 16; ++m) z[m] = bias[c];
    for (int s = 0; s < S; ++s)
        #pragma unroll
        for (int m = 0; m < 16; ++m) z[m] += part[((size_t)s * 16 + m) * N + c];
    if (do_bn) {
        float s1 = 0.f, s2 = 0.f;
        #pragma unroll
        for (int m = 0; m < 16; ++m) { s1 += z[m]; s2 += z[m] * z[m]; }
        float mean = s1 * (1.f / 16.f);
        float var = s2 * (1.f / 16.f) - mean * mean;
        float a = g[c] * rsqrtf(var + 1e-5f);
        float be = bb[c] - mean * a;
        #pragma unroll
        for (int m = 0; m < 16; ++m) out[(size_t)m * N + c] = leaky(a * z[m] + be);
    } else {
        if (c < Nout)
            #pragma unroll
            for (int m = 0; m < 16; ++m) out[(size_t)m * Nout + c] = z[m];
    }
}

static void run_knn(const float* x, int ldx, int nk, const float* sq, unsigned* keys,
                    int CB, int* idx, hipStream_t stream) {
    for (int b0 = 0; b0 < NB; b0 += CB) {
        dim3 g(136, CB);   // lower-triangle tile pairs (16*17/2)
        if (nk == 4)
            dist_sym_kernel<4><<<g, 256, 0, stream>>>(x, ldx, sq, b0, keys);
        else
            dist_sym_kernel<64><<<g, 256, 0, stream>>>(x, ldx, sq, b0, keys);
        knn_select_kernel<<<CB * NP / 4, 256, 0, stream>>>(keys, b0, idx);
    }
}

} // namespace

extern "C" void kernel_launch(void* const* d_in, const int* in_sizes, int n_in,
                              void* d_out, int out_size, void* d_ws, size_t ws_size,
                              hipStream_t stream) {
    (void)in_sizes; (void)n_in; (void)out_size;
    const float* pos = (const float*)d_in[0];
    const float* W1  = (const float*)d_in[1];
    const float* g1  = (const float*)d_in[2];
    const float* b1  = (const float*)d_in[3];
    const float* W2  = (const float*)d_in[4];
    const float* g2  = (const float*)d_in[5];
    const float* b2  = (const float*)d_in[6];
    const float* W3  = (const float*)d_in[7];
    const float* g3  = (const float*)d_in[8];
    const float* b3  = (const float*)d_in[9];
    const float* Wf  = (const float*)d_in[10];
    const float* gf  = (const float*)d_in[11];
    const float* bf  = (const float*)d_in[12];
    const float* W4  = (const float*)d_in[13];
    const float* b4  = (const float*)d_in[14];
    const float* g4  = (const float*)d_in[15];
    const float* be4 = (const float*)d_in[16];
    const float* W5  = (const float*)d_in[17];
    const float* b5  = (const float*)d_in[18];
    const float* g5  = (const float*)d_in[19];
    const float* be5 = (const float*)d_in[20];
    const float* W6  = (const float*)d_in[21];
    const float* b6  = (const float*)d_in[22];
    float* out = (float*)d_out;

    float* ws = (float*)d_ws;
    size_t off = 0;
    int*   idx    = (int*)ws;      off += (size_t)TOT * KK;          // 2.6 MB
    float* pos4   = ws + off;      off += (size_t)TOT * 4;
    float* sq     = ws + off;      off += (size_t)TOT;
    float* Wt     = ws + off;      off += 256 * 64;
    float* basexw = ws + off;      off += (size_t)TOT * 256;         // 32 MB
    float* mmax   = ws + off;      off += (size_t)TOT * 128;         // 16 MB
    float* mmin   = ws + off;      off += (size_t)TOT * 128;         // 16 MB
    float* xc12   = ws + off;      off += (size_t)TOT * 128;         // 16 MB (x1|x2 f32)
    unsigned short* xch = (unsigned short*)(ws + off); off += (size_t)TOT * 128;  // 16 MB bf16 hi
    unsigned short* xcl = (unsigned short*)(ws + off); off += (size_t)TOT * 128;  // 16 MB bf16 lo
    unsigned short* wfh = (unsigned short*)(ws + off); off += (size_t)1024 * 128;
    unsigned short* wfl = (unsigned short*)(ws + off); off += (size_t)1024 * 128;
    float* psum   = ws + off;      off += (size_t)512 * 1024;        // 2 MB
    float* psum2  = ws + off;      off += (size_t)512 * 1024;
    float* pmax   = ws + off;      off += (size_t)512 * 1024;
    float* pmin   = ws + off;      off += (size_t)512 * 1024;
    float* alpha  = ws + off;      off += 1024;
    float* beta   = ws + off;      off += 1024;
    float* gfeat  = ws + off;      off += NB * 1024;
    float* part   = ws + off;      off += 8 * 16 * 512;              // split-K partials
    float* h4     = ws + off;      off += NB * 512;
    float* h5     = ws + off;      off += NB * 256;
    unsigned* keys = (unsigned*)(ws + off);
    const size_t avail = (ws_size > off * 4) ? (ws_size - off * 4) : 0;
    const size_t per_batch = (size_t)NP * NP * 4;
    int CB = 1;
    for (int cb : {4, 2}) {        // keys (64 MB at CB=4) stay L3-resident
        if ((size_t)cb * per_batch <= avail) { CB = cb; break; }
    }

    const int npts_blk = (TOT + 255) / 256;

    // ---------- Layer 1 (D=3 padded to 4, C=64) ----------
    pos4sq_kernel<<<npts_blk, 256, 0, stream>>>(pos, pos4, sq);
    run_knn(pos4, 4, 4, sq, keys, CB, idx, stream);
    wt_build_kernel<<<2, 256, 0, stream>>>(W1, Wt, 3, 4, 64);
    xw_gemm_kernel<1, 128><<<TOT / 16, 256, 0, stream>>>(pos4, 4, Wt, basexw);
    edge_pass_kernel<64><<<EBLK, 256, 0, stream>>>(basexw, idx, psum, psum2, mmax, mmin);
    bn_reduce_kernel<<<64, 256, 0, stream>>>(psum, psum2, EBLK, 64, g1, b1,
                                             1.f / (float)(TOT * KK), alpha, beta);
    edge_finalize_kernel<64><<<TOT * 16 / 256, 256, 0, stream>>>(
        mmax, mmin, alpha, beta, xc12 + 0, 128, xch, xcl, 0, sq);   // sq for layer 2

    // ---------- Layer 2 (D=64, C=64), input x1 = xc12[:,0:64] ----------
    run_knn(xc12 + 0, 128, 64, sq, keys, CB, idx, stream);
    wt_build_kernel<<<32, 256, 0, stream>>>(W2, Wt, 64, 64, 64);
    xw_gemm_kernel<16, 128><<<TOT / 16, 256, 0, stream>>>(xc12 + 0, 128, Wt, basexw);
    edge_pass_kernel<64><<<EBLK, 256, 0, stream>>>(basexw, idx, psum, psum2, mmax, mmin);
    bn_reduce_kernel<<<64, 256, 0, stream>>>(psum, psum2, EBLK, 64, g2, b2,
                                             1.f / (float)(TOT * KK), alpha, beta);
    edge_finalize_kernel<64><<<TOT * 16 / 256, 256, 0, stream>>>(
        mmax, mmin, alpha, beta, xc12 + 64, 128, xch, xcl, 64, sq); // sq for layer 3

    // ---------- Layer 3 (D=64, C=128), input x2 = xc12[:,64:128] ----------
    run_knn(xc12 + 64, 128, 64, sq, keys, CB, idx, stream);
    wt_build_kernel<<<64, 256, 0, stream>>>(W3, Wt, 64, 64, 128);
    xw_gemm_kernel<16, 256><<<TOT / 16, 256, 0, stream>>>(xc12 + 64, 128, Wt, basexw);
    edge_pass_kernel<128><<<EBLK, 256, 0, stream>>>(basexw, idx, psum, psum2, mmax, mmin);
    bn_reduce_kernel<<<128, 256, 0, stream>>>(psum, psum2, EBLK, 128, g3, b3,
                                              1.f / (float)(TOT * KK), alpha, beta);
    edge_finalize_kernel<128><<<TOT * 32 / 256, 256, 0, stream>>>(
        mmax, mmin, alpha, beta, nullptr, 0, xch, xcl, 128, nullptr);

    // ---------- conv_final (MFMA bf16x3) + global max pool ----------
    wfhl_build_kernel<<<1024, 256, 0, stream>>>(Wf, wfh, wfl);
    {
        dim3 g(TOT / 128, 8, 1);
        fc_mfma_kernel<<<g, 256, 0, stream>>>(xch, xcl, wfh, wfl, psum, psum2, pmax, pmin);
    }
    bn_reduce_kernel<<<1024, 256, 0, stream>>>(psum, psum2, 256, 1024, gf, bf,
                                               1.f / (float)TOT, alpha, beta);
    gfeat_final_kernel<<<64, 256, 0, stream>>>(pmax, pmin, alpha, beta, gfeat);

    // ---------- classifier (split-K skinny GEMMs) ----------
    skinny_gemm_kernel<128><<<dim3(8, 2), 256, 0, stream>>>(gfeat, W4, part, 1024, 512);
    fin_kernel<<<2, 256, 0, stream>>>(part, 8, 512, b4, g4, be4, 1, h4, 512);
    skinny_gemm_kernel<64><<<dim3(4, 2), 256, 0, stream>>>(h4, W5, part, 512, 256);
    fin_kernel<<<1, 256, 0, stream>>>(part, 8, 256, b5, g5, be5, 1, h5, 256);
    skinny_gemm_kernel<32><<<dim3(1, 2), 256, 0, stream>>>(h5, W6, part, 256, 40);
    fin_kernel<<<1, 256, 0, stream>>>(part, 8, 40, b6, nullptr, nullptr, 0, out, 40);
}

// Round 10
// 962.462 us; speedup vs baseline: 5.0457x; 1.2794x over previous
//
#include <hip/hip_runtime.h>
#include <float.h>
#include <math.h>

namespace {

constexpr int NB = 16;
constexpr int NP = 2048;
constexpr int KK = 20;
constexpr int TOT = NB * NP;   // 32768
constexpr int EBLK = 1024;     // edge pass grid

typedef short short8v __attribute__((ext_vector_type(8)));   // 8 bf16 (4 VGPRs)
typedef float f32x16 __attribute__((ext_vector_type(16)));

__device__ __forceinline__ float leaky(float v) { return fmaxf(v, 0.2f * v); }

__device__ __forceinline__ unsigned short bf16_rne(float x) {
    unsigned u = __float_as_uint(x);
    unsigned r = u + 0x7FFFu + ((u >> 16) & 1u);
    return (unsigned short)(r >> 16);
}
__device__ __forceinline__ float bf16_f(unsigned short h) {
    return __uint_as_float(((unsigned)h) << 16);
}
__device__ __forceinline__ unsigned mono_key(float d) {
    unsigned bits = __float_as_uint(d);
    return (bits & 0x80000000u) ? ~bits : (bits | 0x80000000u);
}

// ---------------- pos -> pos4 (pad to 4) + squared norm ----------------
__global__ __launch_bounds__(256) void pos4sq_kernel(const float* __restrict__ pos,
                                                     float* __restrict__ pos4,
                                                     float* __restrict__ sq) {
    int i = blockIdx.x * 256 + threadIdx.x;
    if (i < TOT) {
        float x = pos[i * 3 + 0], y = pos[i * 3 + 1], z = pos[i * 3 + 2];
        pos4[i * 4 + 0] = x;
        pos4[i * 4 + 1] = y;
        pos4[i * 4 + 2] = z;
        pos4[i * 4 + 3] = 0.f;
        sq[i] = x * x + y * y + z * z;
    }
}

// ---------------- symmetric distance GEMM -> 16-bit truncated monotone keys ----------------
// Lower-triangle 128x128 tiles (tm >= tn); writes tile + transposed mirror.
// key16 = (mono_key(d) >> 16): monotone non-decreasing -> order stats commute,
// so select on key16 is provably complete (all true top-20 have key16 <= T16).
template <int KTOT>
__global__ __launch_bounds__(256) void dist_sym16_kernel(const float* __restrict__ x, int ldx,
                                                         const float* __restrict__ sq,
                                                         int b0,
                                                         unsigned short* __restrict__ keys) {
    constexpr int KC = (KTOT < 32) ? KTOT : 32;
    constexpr int F4 = KC / 4;
    __shared__ float Ak[KC][128];
    __shared__ float Bk[KC][128];
    const int tid = threadIdx.x;
    const int tr = tid >> 4, tc = tid & 15;
    int tm = (int)((sqrtf(8.f * blockIdx.x + 1.f) - 1.f) * 0.5f);
    while ((tm + 1) * (tm + 2) / 2 <= (int)blockIdx.x) ++tm;
    while (tm * (tm + 1) / 2 > (int)blockIdx.x) --tm;
    const int tn = blockIdx.x - tm * (tm + 1) / 2;
    const int m0 = tm * 128, n0 = tn * 128;
    const int bofs = (b0 + blockIdx.y) * NP;
    const float* xb = x + (size_t)bofs * ldx;
    float acc[8][8] = {};
    for (int k0 = 0; k0 < KTOT; k0 += KC) {
        __syncthreads();
        for (int i = tid; i < 128 * F4; i += 256) {
            const int r = i / F4, c4 = i % F4;
            const int rs = r ^ ((c4 & 3) << 3);
            float4 v = *reinterpret_cast<const float4*>(xb + (size_t)(m0 + r) * ldx + k0 + c4 * 4);
            Ak[c4 * 4 + 0][rs] = v.x; Ak[c4 * 4 + 1][rs] = v.y;
            Ak[c4 * 4 + 2][rs] = v.z; Ak[c4 * 4 + 3][rs] = v.w;
        }
        for (int i = tid; i < 128 * F4; i += 256) {
            const int r = i / F4, c4 = i % F4;
            const int rs = r ^ ((c4 & 3) << 3);
            float4 v = *reinterpret_cast<const float4*>(xb + (size_t)(n0 + r) * ldx + k0 + c4 * 4);
            Bk[c4 * 4 + 0][rs] = v.x; Bk[c4 * 4 + 1][rs] = v.y;
            Bk[c4 * 4 + 2][rs] = v.z; Bk[c4 * 4 + 3][rs] = v.w;
        }
        __syncthreads();
        #pragma unroll
        for (int k = 0; k < KC; ++k) {
            const int sw = ((k >> 2) & 3) << 3;
            const int ia = (tr * 4) ^ sw;
            const int ib = (tc * 4) ^ sw;
            float4 al = *reinterpret_cast<const float4*>(&Ak[k][ia]);
            float4 ah = *reinterpret_cast<const float4*>(&Ak[k][64 + ia]);
            float4 bl = *reinterpret_cast<const float4*>(&Bk[k][ib]);
            float4 bh = *reinterpret_cast<const float4*>(&Bk[k][64 + ib]);
            float a[8] = {al.x, al.y, al.z, al.w, ah.x, ah.y, ah.z, ah.w};
            float bv[8] = {bl.x, bl.y, bl.z, bl.w, bh.x, bh.y, bh.z, bh.w};
            #pragma unroll
            for (int i = 0; i < 8; ++i)
                #pragma unroll
                for (int j = 0; j < 8; ++j)
                    acc[i][j] += a[i] * bv[j];
        }
    }
    float sa[8], sb[8];
    #pragma unroll
    for (int i = 0; i < 8; ++i) sa[i] = sq[bofs + m0 + ((i < 4) ? tr * 4 + i : 64 + tr * 4 + i - 4)];
    #pragma unroll
    for (int j = 0; j < 8; ++j) sb[j] = sq[bofs + n0 + ((j < 4) ? tc * 4 + j : 64 + tc * 4 + j - 4)];
    #pragma unroll
    for (int i = 0; i < 8; ++i) {
        const int row = (i < 4) ? tr * 4 + i : 64 + tr * 4 + i - 4;
        unsigned short* kr = keys + ((size_t)blockIdx.y * NP + m0 + row) * NP + n0;
        unsigned short kk[8];
        #pragma unroll
        for (int j = 0; j < 8; ++j)
            kk[j] = (unsigned short)(mono_key(sa[i] + sb[j] - 2.f * acc[i][j]) >> 16);
        *reinterpret_cast<ushort4*>(kr + tc * 4) = make_ushort4(kk[0], kk[1], kk[2], kk[3]);
        *reinterpret_cast<ushort4*>(kr + 64 + tc * 4) = make_ushort4(kk[4], kk[5], kk[6], kk[7]);
    }
    if (tm != tn) {
        #pragma unroll
        for (int j = 0; j < 8; ++j) {
            const int col = (j < 4) ? tc * 4 + j : 64 + tc * 4 + j - 4;
            unsigned short* mr = keys + ((size_t)blockIdx.y * NP + n0 + col) * NP + m0;
            unsigned short lo4[4], hi4[4];
            #pragma unroll
            for (int i = 0; i < 4; ++i) {
                lo4[i] = (unsigned short)(mono_key(sa[i] + sb[j] - 2.f * acc[i][j]) >> 16);
                hi4[i] = (unsigned short)(mono_key(sa[i + 4] + sb[j] - 2.f * acc[i + 4][j]) >> 16);
            }
            *reinterpret_cast<ushort4*>(mr + tr * 4) = make_ushort4(lo4[0], lo4[1], lo4[2], lo4[3]);
            *reinterpret_cast<ushort4*>(mr + 64 + tr * 4) = make_ushort4(hi4[0], hi4[1], hi4[2], hi4[3]);
        }
    }
}

// ---------------- select16: candidate set {key16 <= T16}, cap 64 ----------------
__global__ __launch_bounds__(256) void knn_select16_kernel(const unsigned short* __restrict__ keys,
                                                           int b0,
                                                           int* __restrict__ cands,
                                                           int* __restrict__ cnts) {
    const int tid = threadIdx.x;
    const int w = tid >> 6, lane = tid & 63;
    const int ql = blockIdx.x * 4 + w;        // chunk-local query
    const int bc = ql / NP;
    const int qg = b0 * NP + ql;              // global query
    const int bofs = (b0 + bc) * NP;
    const unsigned* kr = reinterpret_cast<const unsigned*>(keys) + (size_t)ql * (NP / 2);

    unsigned kv[16];
    #pragma unroll
    for (int v = 0; v < 16; ++v) kv[v] = kr[v * 64 + lane];

    unsigned lmn = 0xFFFFu;
    #pragma unroll
    for (int v = 0; v < 16; ++v) {
        lmn = min(lmn, kv[v] & 0xFFFFu);
        lmn = min(lmn, kv[v] >> 16);
    }
    unsigned M = lmn, lo = lmn;
    #pragma unroll
    for (int s = 1; s < 64; s <<= 1) {
        unsigned tM = __shfl_xor(M, s);
        unsigned tl = __shfl_xor(lo, s);
        M = max(M, tM);
        lo = min(lo, tl);
    }
    unsigned hi = M;   // count(<= M) >= 64 >= KK
    while (lo < hi) {
        unsigned mid = (lo + hi) >> 1;
        int c = 0;
        #pragma unroll
        for (int v = 0; v < 16; ++v) {
            c += ((kv[v] & 0xFFFFu) <= mid) ? 1 : 0;
            c += ((kv[v] >> 16) <= mid) ? 1 : 0;
        }
        #pragma unroll
        for (int s = 1; s < 64; s <<= 1) c += __shfl_xor(c, s);
        if (c >= KK) hi = mid; else lo = mid + 1;
    }
    const unsigned T = lo;

    unsigned nl = 0;
    #pragma unroll
    for (int v = 0; v < 16; ++v) {
        nl += ((kv[v] & 0xFFFFu) <= T) ? 1u : 0u;
        nl += ((kv[v] >> 16) <= T) ? 1u : 0u;
    }
    unsigned sc = nl;
    #pragma unroll
    for (int s = 1; s < 64; s <<= 1) {
        unsigned t2 = __shfl_up(sc, s);
        if (lane >= s) sc += t2;
    }
    const unsigned total = __shfl(sc, 63);
    unsigned off = sc - nl;
    int* cp = cands + (size_t)qg * 64;
    #pragma unroll
    for (int v = 0; v < 16; ++v) {
        if ((kv[v] & 0xFFFFu) <= T) { if (off < 64u) cp[off] = bofs + (v * 64 + lane) * 2; ++off; }
        if ((kv[v] >> 16) <= T)     { if (off < 64u) cp[off] = bofs + (v * 64 + lane) * 2 + 1; ++off; }
    }
    if (lane == 0) cnts[qg] = (int)total;
}

// ---------------- refine: exact f32 re-rank of candidates, exact tie semantics ----------------
template <int D>
__global__ __launch_bounds__(256) void knn_refine_kernel(const float* __restrict__ x, int ldx,
                                                         const float* __restrict__ sq,
                                                         const int* __restrict__ cands,
                                                         const int* __restrict__ cnts,
                                                         int* __restrict__ idx_out) {
    const int tid = threadIdx.x;
    const int w = tid >> 6, lane = tid & 63;
    const int q = blockIdx.x * 4 + w;
    const int bofs = (q / NP) * NP;
    float qf[D];
    const float* xq = x + (size_t)q * ldx;
    #pragma unroll
    for (int k = 0; k < D; ++k) qf[k] = xq[k];
    const float sqq = sq[q];
    const int cnt = cnts[q];
    int* op = idx_out + (size_t)q * KK;

    if (cnt <= 64) {
        const int cidx = (lane < cnt) ? cands[(size_t)q * 64 + lane] : -1;
        unsigned key = 0xFFFFFFFFu;
        if (cidx >= 0) {
            const float* xc = x + (size_t)cidx * ldx;
            float acc = 0.f;
            #pragma unroll
            for (int k = 0; k < D; ++k) acc += qf[k] * xc[k];   // same form/order as dist
            key = mono_key(sqq + sq[cidx] - 2.f * acc);
        }
        unsigned lo = key, hi = key;
        #pragma unroll
        for (int s = 1; s < 64; s <<= 1) {
            unsigned tl = __shfl_xor(lo, s);
            unsigned th = __shfl_xor(hi, s);
            lo = min(lo, tl);
            hi = max(hi, th);
        }
        while (lo < hi) {
            unsigned mid = lo + ((hi - lo) >> 1);
            int c = __popcll(__ballot(key <= mid));
            if (c >= KK) hi = mid; else lo = mid + 1;
        }
        const unsigned T = lo;
        unsigned long long blt = __ballot(key < T);
        const int strict = __popcll(blt);
        if (key < T) {
            int o = __popcll(blt & ((1ull << lane) - 1ull));
            op[o] = cidx;
        }
        const int rem = KK - strict;
        bool eq = (key == T) && (cidx >= 0);
        bool done = false;
        for (int t = 0; t < rem; ++t) {   // emit ties in ascending global index order
            int v = (eq && !done) ? cidx : 0x7FFFFFFF;
            #pragma unroll
            for (int s = 1; s < 64; s <<= 1) v = min(v, __shfl_xor(v, s));
            if (eq && !done && cidx == v) { op[strict + t] = cidx; done = true; }
        }
    } else {
        // fallback: exact full-row scan (deterministic; ~never taken)
        unsigned keysr[32];
        for (int u = 0; u < 32; ++u) {
            const int c = bofs + u * 64 + lane;
            const float* xc = x + (size_t)c * ldx;
            float acc = 0.f;
            #pragma unroll
            for (int k = 0; k < D; ++k) acc += qf[k] * xc[k];
            keysr[u] = mono_key(sqq + sq[c] - 2.f * acc);
        }
        unsigned lmn = 0xFFFFFFFFu;
        #pragma unroll
        for (int u = 0; u < 32; ++u) lmn = min(lmn, keysr[u]);
        unsigned M = lmn, lo = lmn;
        #pragma unroll
        for (int s = 1; s < 64; s <<= 1) {
            unsigned tM = __shfl_xor(M, s);
            unsigned tl = __shfl_xor(lo, s);
            M = max(M, tM);
            lo = min(lo, tl);
        }
        unsigned hi = M;
        while (lo < hi) {
            unsigned mid = lo + ((hi - lo) >> 1);
            int c = 0;
            #pragma unroll
            for (int u = 0; u < 32; ++u)
                c += __popcll(__ballot(keysr[u] <= mid));
            if (c >= KK) hi = mid; else lo = mid + 1;
        }
        const unsigned T = lo;
        unsigned nl = 0;
        #pragma unroll
        for (int u = 0; u < 32; ++u) nl += (keysr[u] < T) ? 1u : 0u;
        unsigned sc2 = nl;
        #pragma unroll
        for (int s = 1; s < 64; s <<= 1) {
            unsigned t2 = __shfl_up(sc2, s);
            if (lane >= s) sc2 += t2;
        }
        unsigned cstrict = __shfl(sc2, 63);
        unsigned o = sc2 - nl;
        #pragma unroll
        for (int u = 0; u < 32; ++u) {
            if (keysr[u] < T) { op[o] = bofs + u * 64 + lane; ++o; }
        }
        int rem = KK - (int)cstrict;
        int ebase = (int)cstrict;
        #pragma unroll
        for (int u = 0; u < 32; ++u) {
            if (rem > 0) {
                bool eq = (keysr[u] == T);
                unsigned long long bm = __ballot(eq);
                int before = __popcll(bm & ((1ull << lane) - 1ull));
                if (eq && before < rem) op[ebase + before] = bofs + u * 64 + lane;
                int take = __popcll(bm);
                if (take > rem) take = rem;
                ebase += take;
                rem -= take;
            }
        }
    }
}

// ---------------- Wt[c][j] build: [Wd | Wtail] transposed, zero-padded ----------------
__global__ __launch_bounds__(256) void wt_build_kernel(const float* __restrict__ W,
                                                       float* __restrict__ Wt,
                                                       int D, int Dp, int C) {
    int i = blockIdx.x * 256 + threadIdx.x;
    if (i < 2 * C * Dp) {
        int c = i / Dp, j = i % Dp;
        float v = 0.f;
        if (j < D) {
            v = (c < C) ? (W[j * C + c] - W[(D + j) * C + c])
                        : W[(D + j) * C + (c - C)];
        }
        Wt[i] = v;
    }
}

// ---------------- X[TOT,Dp] @ Wt^T -> basexw[TOT,2C] ----------------
template <int NJ4, int C2>
__global__ __launch_bounds__(256) void xw_gemm_kernel(const float* __restrict__ x, int ldx,
                                                      const float* __restrict__ Wt,
                                                      float* __restrict__ bx) {
    constexpr int PG = 256 / C2;   // point groups
    constexpr int PTS = 16 / PG;   // points per thread
    __shared__ float4 Xs[16][NJ4];
    const int tid = threadIdx.x;
    const int p0 = blockIdx.x * 16;
    for (int i = tid; i < 16 * NJ4; i += 256) {
        int r = i / NJ4, j4 = i % NJ4;
        Xs[r][j4] = *reinterpret_cast<const float4*>(x + (size_t)(p0 + r) * ldx + j4 * 4);
    }
    __syncthreads();
    const int c = tid % C2, pg = tid / C2;
    const float4* wrow = reinterpret_cast<const float4*>(Wt + (size_t)c * (NJ4 * 4));
    float acc[PTS];
    #pragma unroll
    for (int u = 0; u < PTS; ++u) acc[u] = 0.f;
    #pragma unroll
    for (int j4 = 0; j4 < NJ4; ++j4) {
        float4 w4 = wrow[j4];
        #pragma unroll
        for (int u = 0; u < PTS; ++u) {
            float4 x4 = Xs[pg * PTS + u][j4];
            acc[u] += x4.x * w4.x + x4.y * w4.y + x4.z * w4.z + x4.w * w4.w;
        }
    }
    #pragma unroll
    for (int u = 0; u < PTS; ++u)
        bx[(size_t)(p0 + pg * PTS + u) * C2 + c] = acc[u];
}

// ---------------- edge pass: gather XW, stats + per-point max/min ----------------
template <int C>
__global__ __launch_bounds__(256) void edge_pass_kernel(const float* __restrict__ bx,
                                                        const int* __restrict__ idx,
                                                        float* __restrict__ psum,
                                                        float* __restrict__ psum2,
                                                        float* __restrict__ mmax,
                                                        float* __restrict__ mmin) {
    constexpr int PT = 256 / C;
    constexpr int C2 = 2 * C;
    __shared__ int sidx[PT][KK];
    __shared__ float red[256];
    const int tid = threadIdx.x;
    const int c = tid % C;
    const int pl = tid / C;
    float s1 = 0.f, s2 = 0.f;
    const int NT = TOT / PT;
    for (int t = blockIdx.x; t < NT; t += EBLK) {
        const int p0 = t * PT;
        __syncthreads();
        if (tid < PT * KK) sidx[tid / KK][tid % KK] = idx[(size_t)p0 * KK + tid];
        __syncthreads();
        const int p = p0 + pl;
        const float bv = bx[(size_t)p * C2 + c];
        float A = 0.f, Q = 0.f, M = -FLT_MAX, mn = FLT_MAX;
        #pragma unroll
        for (int k = 0; k < KK; ++k) {
            float v = bx[(size_t)sidx[pl][k] * C2 + C + c];
            A += v; Q += v * v; M = fmaxf(M, v); mn = fminf(mn, v);
        }
        s1 += (float)KK * bv + A;
        s2 += (float)KK * bv * bv + 2.f * bv * A + Q;
        mmax[(size_t)p * C + c] = bv + M;
        mmin[(size_t)p * C + c] = bv + mn;
    }
    red[tid] = s1;
    __syncthreads();
    if (tid < C) {
        float v = red[tid];
        #pragma unroll
        for (int u = 1; u < PT; ++u) v += red[tid + u * C];
        psum[(size_t)blockIdx.x * C + tid] = v;
    }
    __syncthreads();
    red[tid] = s2;
    __syncthreads();
    if (tid < C) {
        float v = red[tid];
        #pragma unroll
        for (int u = 1; u < PT; ++u) v += red[tid + u * C];
        psum2[(size_t)blockIdx.x * C + tid] = v;
    }
}

// ---------------- BN stats reduce -> alpha/beta ----------------
__global__ __launch_bounds__(256) void bn_reduce_kernel(
        const float* __restrict__ psum, const float* __restrict__ psum2,
        int npart, int C, const float* __restrict__ g, const float* __restrict__ bb,
        float inv_cnt, float* __restrict__ alpha, float* __restrict__ beta) {
    const int c = blockIdx.x;
    const int tid = threadIdx.x;
    __shared__ float r1[256], r2[256];
    float s1 = 0.f, s2 = 0.f;
    for (int i = tid; i < npart; i += 256) {
        s1 += psum[(size_t)i * C + c];
        s2 += psum2[(size_t)i * C + c];
    }
    r1[tid] = s1; r2[tid] = s2;
    __syncthreads();
    for (int s = 128; s > 0; s >>= 1) {
        if (tid < s) { r1[tid] += r1[tid + s]; r2[tid] += r2[tid + s]; }
        __syncthreads();
    }
    if (tid == 0) {
        float mean = r1[0] * inv_cnt;
        float var = r2[0] * inv_cnt - mean * mean;
        float a = g[c] * rsqrtf(var + 1e-5f);
        alpha[c] = a;
        beta[c] = bb[c] - mean * a;
    }
}

// ---------------- edge finalize: pick by sign(alpha), affine+leaky; f32 + bf16 hi/lo (+sq) ----------------
template <int C>
__global__ __launch_bounds__(256) void edge_finalize_kernel(const float* __restrict__ mmax,
                                                            const float* __restrict__ mmin,
                                                            const float* __restrict__ alpha,
                                                            const float* __restrict__ beta,
                                                            float* __restrict__ xcf, int ldf,
                                                            unsigned short* __restrict__ xch,
                                                            unsigned short* __restrict__ xcl,
                                                            int ch_off,
                                                            float* __restrict__ sq_out) {
    constexpr int CQ = C / 4;
    __shared__ float red[256];
    const int tid = threadIdx.x;
    int i4 = blockIdx.x * 256 + tid;
    float4 o = make_float4(0.f, 0.f, 0.f, 0.f);
    int p = 0;
    if (i4 < TOT * CQ) {
        int cq; p = i4 / CQ; cq = i4 - p * CQ;
        float4 M4 = reinterpret_cast<const float4*>(mmax)[i4];
        float4 m4 = reinterpret_cast<const float4*>(mmin)[i4];
        float4 a4 = reinterpret_cast<const float4*>(alpha)[cq];
        float4 b4 = reinterpret_cast<const float4*>(beta)[cq];
        o.x = leaky(a4.x * (a4.x >= 0.f ? M4.x : m4.x) + b4.x);
        o.y = leaky(a4.y * (a4.y >= 0.f ? M4.y : m4.y) + b4.y);
        o.z = leaky(a4.z * (a4.z >= 0.f ? M4.z : m4.z) + b4.z);
        o.w = leaky(a4.w * (a4.w >= 0.f ? M4.w : m4.w) + b4.w);
        if (xcf)
            *reinterpret_cast<float4*>(xcf + (size_t)p * ldf + cq * 4) = o;
        ushort4 hh, ll;
        hh.x = bf16_rne(o.x); ll.x = bf16_rne(o.x - bf16_f(hh.x));
        hh.y = bf16_rne(o.y); ll.y = bf16_rne(o.y - bf16_f(hh.y));
        hh.z = bf16_rne(o.z); ll.z = bf16_rne(o.z - bf16_f(hh.z));
        hh.w = bf16_rne(o.w); ll.w = bf16_rne(o.w - bf16_f(hh.w));
        const size_t oo = (size_t)p * 256 + ch_off + cq * 4;
        *reinterpret_cast<ushort4*>(xch + oo) = hh;
        *reinterpret_cast<ushort4*>(xcl + oo) = ll;
    }
    if (sq_out) {   // only used for C=64 (CQ=16, 16 pts/block, exact grid)
        red[tid] = o.x * o.x + o.y * o.y + o.z * o.z + o.w * o.w;
        __syncthreads();
        if ((tid & (CQ - 1)) == 0) {
            float s = red[tid];
            #pragma unroll
            for (int u = 1; u < CQ; ++u) s += red[tid + u];
            sq_out[p] = s;
        }
    }
}

// ---------------- Wf -> bf16 hi/lo, transposed to [1024][256] ----------------
__global__ __launch_bounds__(256) void wfhl_build_kernel(const float* __restrict__ Wf,
                                                         unsigned short* __restrict__ wfh,
                                                         unsigned short* __restrict__ wfl) {
    int i = blockIdx.x * 256 + threadIdx.x;
    if (i < 256 * 1024) {
        int e = i / 1024, o = i - e * 1024;
        float v = Wf[i];
        unsigned short h = bf16_rne(v);
        wfh[(size_t)o * 256 + e] = h;
        wfl[(size_t)o * 256 + e] = bf16_rne(v - bf16_f(h));
    }
}

// ---------------- conv_final via MFMA bf16x3 + stat partials ----------------
__global__ __launch_bounds__(256) void fc_mfma_kernel(const unsigned short* __restrict__ xch,
                                                      const unsigned short* __restrict__ xcl,
                                                      const unsigned short* __restrict__ wfh,
                                                      const unsigned short* __restrict__ wfl,
                                                      float* __restrict__ psum,
                                                      float* __restrict__ psum2,
                                                      float* __restrict__ pmax,
                                                      float* __restrict__ pmin) {
    __shared__ __align__(16) unsigned short Ah[128 * 64];
    __shared__ __align__(16) unsigned short Al[128 * 64];
    __shared__ __align__(16) unsigned short Bh[128 * 64];
    __shared__ __align__(16) unsigned short Bl[128 * 64];
    const int tid = threadIdx.x;
    const int w = tid >> 6, lane = tid & 63;
    const int wr = w >> 1, wc = w & 1;
    const int pt = blockIdx.x, ct = blockIdx.y;
    f32x16 acc00 = {}, acc01 = {}, acc10 = {}, acc11 = {};
    for (int kc = 0; kc < 4; ++kc) {
        const int k0 = kc * 64;
        __syncthreads();
        for (int i = tid; i < 1024; i += 256) {
            const int r = i >> 3, slot = i & 7;
            const int ls = r * 64 + ((slot ^ (r & 7)) << 3);
            const size_t ga = (size_t)(pt * 128 + r) * 256 + k0 + slot * 8;
            const size_t gb = (size_t)(ct * 128 + r) * 256 + k0 + slot * 8;
            *reinterpret_cast<uint4*>(&Ah[ls]) = *reinterpret_cast<const uint4*>(&xch[ga]);
            *reinterpret_cast<uint4*>(&Al[ls]) = *reinterpret_cast<const uint4*>(&xcl[ga]);
            *reinterpret_cast<uint4*>(&Bh[ls]) = *reinterpret_cast<const uint4*>(&wfh[gb]);
            *reinterpret_cast<uint4*>(&Bl[ls]) = *reinterpret_cast<const uint4*>(&wfl[gb]);
        }
        __syncthreads();
        const int h = lane >> 5;
        const int ar0 = wr * 64 + (lane & 31), ar1 = ar0 + 32;
        const int bc0 = wc * 64 + (lane & 31), bc1 = bc0 + 32;
        #pragma unroll
        for (int s = 0; s < 4; ++s) {
            const int sl = s * 2 + h;
            const int ia0 = ar0 * 64 + ((sl ^ (ar0 & 7)) << 3);
            const int ia1 = ar1 * 64 + ((sl ^ (ar1 & 7)) << 3);
            const int ib0 = bc0 * 64 + ((sl ^ (bc0 & 7)) << 3);
            const int ib1 = bc1 * 64 + ((sl ^ (bc1 & 7)) << 3);
            short8v a0h = *reinterpret_cast<const short8v*>(&Ah[ia0]);
            short8v a1h = *reinterpret_cast<const short8v*>(&Ah[ia1]);
            short8v a0l = *reinterpret_cast<const short8v*>(&Al[ia0]);
            short8v a1l = *reinterpret_cast<const short8v*>(&Al[ia1]);
            short8v b0h = *reinterpret_cast<const short8v*>(&Bh[ib0]);
            short8v b1h = *reinterpret_cast<const short8v*>(&Bh[ib1]);
            short8v b0l = *reinterpret_cast<const short8v*>(&Bl[ib0]);
            short8v b1l = *reinterpret_cast<const short8v*>(&Bl[ib1]);
            acc00 = __builtin_amdgcn_mfma_f32_32x32x16_bf16(a0h, b0h, acc00, 0, 0, 0);
            acc01 = __builtin_amdgcn_mfma_f32_32x32x16_bf16(a0h, b1h, acc01, 0, 0, 0);
            acc10 = __builtin_amdgcn_mfma_f32_32x32x16_bf16(a1h, b0h, acc10, 0, 0, 0);
            acc11 = __builtin_amdgcn_mfma_f32_32x32x16_bf16(a1h, b1h, acc11, 0, 0, 0);
            acc00 = __builtin_amdgcn_mfma_f32_32x32x16_bf16(a0h, b0l, acc00, 0, 0, 0);
            acc01 = __builtin_amdgcn_mfma_f32_32x32x16_bf16(a0h, b1l, acc01, 0, 0, 0);
            acc10 = __builtin_amdgcn_mfma_f32_32x32x16_bf16(a1h, b0l, acc10, 0, 0, 0);
            acc11 = __builtin_amdgcn_mfma_f32_32x32x16_bf16(a1h, b1l, acc11, 0, 0, 0);
            acc00 = __builtin_amdgcn_mfma_f32_32x32x16_bf16(a0l, b0h, acc00, 0, 0, 0);
            acc01 = __builtin_amdgcn_mfma_f32_32x32x16_bf16(a0l, b1h, acc01, 0, 0, 0);
            acc10 = __builtin_amdgcn_mfma_f32_32x32x16_bf16(a1l, b0h, acc10, 0, 0, 0);
            acc11 = __builtin_amdgcn_mfma_f32_32x32x16_bf16(a1l, b1h, acc11, 0, 0, 0);
        }
    }
    float* red = reinterpret_cast<float*>(Ah);   // [2 wr][128 ch][4 stats]
    __syncthreads();
    #pragma unroll
    for (int fc = 0; fc < 2; ++fc) {
        float s1 = 0.f, s2 = 0.f, mx = -FLT_MAX, mn = FLT_MAX;
        #pragma unroll
        for (int e = 0; e < 16; ++e) {
            float v0 = (fc == 0) ? acc00[e] : acc01[e];
            float v1 = (fc == 0) ? acc10[e] : acc11[e];
            s1 += v0 + v1;
            s2 += v0 * v0 + v1 * v1;
            mx = fmaxf(mx, fmaxf(v0, v1));
            mn = fminf(mn, fminf(v0, v1));
        }
        s1 += __shfl_xor(s1, 32);
        s2 += __shfl_xor(s2, 32);
        mx = fmaxf(mx, __shfl_xor(mx, 32));
        mn = fminf(mn, __shfl_xor(mn, 32));
        if (lane < 32) {
            const int ch = wc * 64 + fc * 32 + lane;
            float4 st; st.x = s1; st.y = s2; st.z = mx; st.w = mn;
            *reinterpret_cast<float4*>(&red[(wr * 128 + ch) * 4]) = st;
        }
    }
    __syncthreads();
    if (tid < 128) {
        float4 s0 = *reinterpret_cast<const float4*>(&red[tid * 4]);
        float4 s1 = *reinterpret_cast<const float4*>(&red[(128 + tid) * 4]);
        const size_t go = (size_t)pt * 1024 + ct * 128 + tid;
        psum[go]  = s0.x + s1.x;
        psum2[go] = s0.y + s1.y;
        pmax[go]  = fmaxf(s0.z, s1.z);
        pmin[go]  = fminf(s0.w, s1.w);
    }
}

// ---------------- gfeat finalize (16 point-tile partials per batch) ----------------
__global__ __launch_bounds__(256) void gfeat_final_kernel(const float* __restrict__ pmax,
                                                          const float* __restrict__ pmin,
                                                          const float* __restrict__ alpha,
                                                          const float* __restrict__ beta,
                                                          float* __restrict__ gfeat) {
    int i = blockIdx.x * 256 + threadIdx.x;
    if (i < NB * 1024) {
        int b = i >> 10, c = i & 1023;
        float mx = -FLT_MAX, mn = FLT_MAX;
        for (int j = 0; j < 16; ++j) {
            size_t o = (size_t)(b * 16 + j) * 1024 + c;
            mx = fmaxf(mx, pmax[o]);
            mn = fminf(mn, pmin[o]);
        }
        float a = alpha[c];
        gfeat[i] = leaky(a * (a >= 0.f ? mx : mn) + beta[c]);
    }
}

// ---------------- classifier: split-K skinny GEMM, A is [16][K] ----------------
template <int CHUNK>
__global__ __launch_bounds__(256) void skinny_gemm_kernel(const float* __restrict__ A,
                                                          const float* __restrict__ W,
                                                          float* __restrict__ part,
                                                          int K, int N) {
    __shared__ float Asub[4][16][CHUNK];
    const int tid = threadIdx.x;
    const int g = tid >> 6, lane = tid & 63;
    const int c = blockIdx.x * 64 + lane;
    const int ks = blockIdx.y * 4 + g;
    const int e0 = ks * CHUNK;
    for (int i = lane; i < 16 * CHUNK; i += 64) {
        const int m = i / CHUNK, el = i - m * CHUNK;
        Asub[g][m][el] = A[(size_t)m * K + e0 + el];
    }
    if (c < N) {
        float acc[16];
        #pragma unroll
        for (int m = 0; m < 16; ++m) acc[m] = 0.f;
        #pragma unroll 4
        for (int el = 0; el < CHUNK; ++el) {
            float w = W[(size_t)(e0 + el) * N + c];
            #pragma unroll
            for (int m = 0; m < 16; ++m) acc[m] += Asub[g][m][el] * w;
        }
        #pragma unroll
        for (int m = 0; m < 16; ++m)
            part[((size_t)ks * 16 + m) * N + c] = acc[m];
    }
}

// ---------------- classifier finish: reduce splits + bias (+BN over rows + leaky) ----------------
__global__ __launch_bounds__(256) void fin_kernel(const float* __restrict__ part,
                                                  int S, int N,
                                                  const float* __restrict__ bias,
                                                  const float* __restrict__ g,
                                                  const float* __restrict__ bb,
                                                  int do_bn,
                                                  float* __restrict__ out, int Nout) {
    int c = blockIdx.x * 256 + threadIdx.x;
    if (c >= N) return;
    float z[16];
    #pragma unroll
    for (int m = 0; m < 16; ++m) z[m] = bias[c];
    for (int s = 0; s < S; ++s)
        #pragma unroll
        for (int m = 0; m < 16; ++m) z[m] += part[((size_t)s * 16 + m) * N + c];
    if (do_bn) {
        float s1 = 0.f, s2 = 0.f;
        #pragma unroll
        for (int m = 0; m < 16; ++m) { s1 += z[m]; s2 += z[m] * z[m]; }
        float mean = s1 * (1.f / 16.f);
        float var = s2 * (1.f / 16.f) - mean * mean;
        float a = g[c] * rsqrtf(var + 1e-5f);
        float be = bb[c] - mean * a;
        #pragma unroll
        for (int m = 0; m < 16; ++m) out[(size_t)m * N + c] = leaky(a * z[m] + be);
    } else {
        if (c < Nout)
            #pragma unroll
            for (int m = 0; m < 16; ++m) out[(size_t)m * Nout + c] = z[m];
    }
}

static void run_knn(const float* x, int ldx, int nk, const float* sq,
                    unsigned short* keys16, int CB, int* cands, int* cnts,
                    int* idx, hipStream_t stream) {
    for (int b0 = 0; b0 < NB; b0 += CB) {
        dim3 g(136, CB);   // lower-triangle tile pairs (16*17/2)
        if (nk == 4)
            dist_sym16_kernel<4><<<g, 256, 0, stream>>>(x, ldx, sq, b0, keys16);
        else
            dist_sym16_kernel<64><<<g, 256, 0, stream>>>(x, ldx, sq, b0, keys16);
        knn_select16_kernel<<<CB * NP / 4, 256, 0, stream>>>(keys16, b0, cands, cnts);
    }
    if (nk == 4)
        knn_refine_kernel<4><<<TOT / 4, 256, 0, stream>>>(x, ldx, sq, cands, cnts, idx);
    else
        knn_refine_kernel<64><<<TOT / 4, 256, 0, stream>>>(x, ldx, sq, cands, cnts, idx);
}

} // namespace

extern "C" void kernel_launch(void* const* d_in, const int* in_sizes, int n_in,
                              void* d_out, int out_size, void* d_ws, size_t ws_size,
                              hipStream_t stream) {
    (void)in_sizes; (void)n_in; (void)out_size;
    const float* pos = (const float*)d_in[0];
    const float* W1  = (const float*)d_in[1];
    const float* g1  = (const float*)d_in[2];
    const float* b1  = (const float*)d_in[3];
    const float* W2  = (const float*)d_in[4];
    const float* g2  = (const float*)d_in[5];
    const float* b2  = (const float*)d_in[6];
    const float* W3  = (const float*)d_in[7];
    const float* g3  = (const float*)d_in[8];
    const float* b3  = (const float*)d_in[9];
    const float* Wf  = (const float*)d_in[10];
    const float* gf  = (const float*)d_in[11];
    const float* bf  = (const float*)d_in[12];
    const float* W4  = (const float*)d_in[13];
    const float* b4  = (const float*)d_in[14];
    const float* g4  = (const float*)d_in[15];
    const float* be4 = (const float*)d_in[16];
    const float* W5  = (const float*)d_in[17];
    const float* b5  = (const float*)d_in[18];
    const float* g5  = (const float*)d_in[19];
    const float* be5 = (const float*)d_in[20];
    const float* W6  = (const float*)d_in[21];
    const float* b6  = (const float*)d_in[22];
    float* out = (float*)d_out;

    float* ws = (float*)d_ws;
    size_t off = 0;
    int*   idx    = (int*)ws;      off += (size_t)TOT * KK;          // 2.6 MB
    float* pos4   = ws + off;      off += (size_t)TOT * 4;
    float* sq     = ws + off;      off += (size_t)TOT;
    float* Wt     = ws + off;      off += 256 * 64;
    float* basexw = ws + off;      off += (size_t)TOT * 256;         // 32 MB
    float* mmax   = ws + off;      off += (size_t)TOT * 128;         // 16 MB
    float* mmin   = ws + off;      off += (size_t)TOT * 128;         // 16 MB
    float* xc12   = ws + off;      off += (size_t)TOT * 128;         // 16 MB (x1|x2 f32)
    unsigned short* xch = (unsigned short*)(ws + off); off += (size_t)TOT * 128;  // 16 MB bf16 hi
    unsigned short* xcl = (unsigned short*)(ws + off); off += (size_t)TOT * 128;  // 16 MB bf16 lo
    unsigned short* wfh = (unsigned short*)(ws + off); off += (size_t)1024 * 128;
    unsigned short* wfl = (unsigned short*)(ws + off); off += (size_t)1024 * 128;
    float* psum   = ws + off;      off += (size_t)512 * 1024;        // 2 MB
    float* psum2  = ws + off;      off += (size_t)512 * 1024;
    float* pmax   = ws + off;      off += (size_t)512 * 1024;
    float* pmin   = ws + off;      off += (size_t)512 * 1024;
    float* alpha  = ws + off;      off += 1024;
    float* beta   = ws + off;      off += 1024;
    float* gfeat  = ws + off;      off += NB * 1024;
    float* part   = ws + off;      off += 8 * 16 * 512;              // split-K partials
    float* h4     = ws + off;      off += NB * 512;
    float* h5     = ws + off;      off += NB * 256;
    int*   cands  = (int*)(ws + off); off += (size_t)TOT * 64;       // 8.4 MB
    int*   cnts   = (int*)(ws + off); off += TOT;
    unsigned short* keys16 = (unsigned short*)(ws + off);
    const size_t avail = (ws_size > off * 4) ? (ws_size - off * 4) : 0;
    const size_t per_batch = (size_t)NP * NP * 2;   // 16-bit keys
    int CB = 1;
    for (int cb : {8, 4, 2}) {     // keys16 <= 64 MB, L3-resident
        if ((size_t)cb * per_batch <= avail) { CB = cb; break; }
    }

    const int npts_blk = (TOT + 255) / 256;

    // ---------- Layer 1 (D=3 padded to 4, C=64) ----------
    pos4sq_kernel<<<npts_blk, 256, 0, stream>>>(pos, pos4, sq);
    run_knn(pos4, 4, 4, sq, keys16, CB, cands, cnts, idx, stream);
    wt_build_kernel<<<2, 256, 0, stream>>>(W1, Wt, 3, 4, 64);
    xw_gemm_kernel<1, 128><<<TOT / 16, 256, 0, stream>>>(pos4, 4, Wt, basexw);
    edge_pass_kernel<64><<<EBLK, 256, 0, stream>>>(basexw, idx, psum, psum2, mmax, mmin);
    bn_reduce_kernel<<<64, 256, 0, stream>>>(psum, psum2, EBLK, 64, g1, b1,
                                             1.f / (float)(TOT * KK), alpha, beta);
    edge_finalize_kernel<64><<<TOT * 16 / 256, 256, 0, stream>>>(
        mmax, mmin, alpha, beta, xc12 + 0, 128, xch, xcl, 0, sq);   // sq for layer 2

    // ---------- Layer 2 (D=64, C=64), input x1 = xc12[:,0:64] ----------
    run_knn(xc12 + 0, 128, 64, sq, keys16, CB, cands, cnts, idx, stream);
    wt_build_kernel<<<32, 256, 0, stream>>>(W2, Wt, 64, 64, 64);
    xw_gemm_kernel<16, 128><<<TOT / 16, 256, 0, stream>>>(xc12 + 0, 128, Wt, basexw);
    edge_pass_kernel<64><<<EBLK, 256, 0, stream>>>(basexw, idx, psum, psum2, mmax, mmin);
    bn_reduce_kernel<<<64, 256, 0, stream>>>(psum, psum2, EBLK, 64, g2, b2,
                                             1.f / (float)(TOT * KK), alpha, beta);
    edge_finalize_kernel<64><<<TOT * 16 / 256, 256, 0, stream>>>(
        mmax, mmin, alpha, beta, xc12 + 64, 128, xch, xcl, 64, sq); // sq for layer 3

    // ---------- Layer 3 (D=64, C=128), input x2 = xc12[:,64:128] ----------
    run_knn(xc12 + 64, 128, 64, sq, keys16, CB, cands, cnts, idx, stream);
    wt_build_kernel<<<64, 256, 0, stream>>>(W3, Wt, 64, 64, 128);
    xw_gemm_kernel<16, 256><<<TOT / 16, 256, 0, stream>>>(xc12 + 64, 128, Wt, basexw);
    edge_pass_kernel<128><<<EBLK, 256, 0, stream>>>(basexw, idx, psum, psum2, mmax, mmin);
    bn_reduce_kernel<<<128, 256, 0, stream>>>(psum, psum2, EBLK, 128, g3, b3,
                                              1.f / (float)(TOT * KK), alpha, beta);
    edge_finalize_kernel<128><<<TOT * 32 / 256, 256, 0, stream>>>(
        mmax, mmin, alpha, beta, nullptr, 0, xch, xcl, 128, nullptr);

    // ---------- conv_final (MFMA bf16x3) + global max pool ----------
    wfhl_build_kernel<<<1024, 256, 0, stream>>>(Wf, wfh, wfl);
    {
        dim3 g(TOT / 128, 8, 1);
        fc_mfma_kernel<<<g, 256, 0, stream>>>(xch, xcl, wfh, wfl, psum, psum2, pmax, pmin);
    }
    bn_reduce_kernel<<<1024, 256, 0, stream>>>(psum, psum2, 256, 1024, gf, bf,
                                               1.f / (float)TOT, alpha, beta);
    gfeat_final_kernel<<<64, 256, 0, stream>>>(pmax, pmin, alpha, beta, gfeat);

    // ---------- classifier (split-K skinny GEMMs) ----------
    skinny_gemm_kernel<128><<<dim3(8, 2), 256, 0, stream>>>(gfeat, W4, part, 1024, 512);
    fin_kernel<<<2, 256, 0, stream>>>(part, 8, 512, b4, g4, be4, 1, h4, 512);
    skinny_gemm_kernel<64><<<dim3(4, 2), 256, 0, stream>>>(h4, W5, part, 512, 256);
    fin_kernel<<<1, 256, 0, stream>>>(part, 8, 256, b5, g5, be5, 1, h5, 256);
    skinny_gemm_kernel<32><<<dim3(1, 2), 256, 0, stream>>>(h5, W6, part, 256, 40);
    fin_kernel<<<1, 256, 0, stream>>>(part, 8, 40, b6, nullptr, nullptr, 0, out, 40);
}

// Round 11
// 880.763 us; speedup vs baseline: 5.5137x; 1.0928x over previous
//
#include <hip/hip_runtime.h>
#include <float.h>
#include <math.h>

namespace {

constexpr int NB = 16;
constexpr int NP = 2048;
constexpr int KK = 20;
constexpr int TOT = NB * NP;   // 32768
constexpr int EBLK = 1024;     // edge pass grid

typedef short short8v __attribute__((ext_vector_type(8)));   // 8 bf16 (4 VGPRs)
typedef float f32x16 __attribute__((ext_vector_type(16)));

__device__ __forceinline__ float leaky(float v) { return fmaxf(v, 0.2f * v); }

__device__ __forceinline__ unsigned short bf16_rne(float x) {
    unsigned u = __float_as_uint(x);
    unsigned r = u + 0x7FFFu + ((u >> 16) & 1u);
    return (unsigned short)(r >> 16);
}
__device__ __forceinline__ float bf16_f(unsigned short h) {
    return __uint_as_float(((unsigned)h) << 16);
}
__device__ __forceinline__ unsigned mono_key(float d) {
    unsigned bits = __float_as_uint(d);
    return (bits & 0x80000000u) ? ~bits : (bits | 0x80000000u);
}
__device__ __forceinline__ unsigned short key16(float d) {
    return (unsigned short)(mono_key(d) >> 16);
}

// ---------------- pos -> pos4 (pad to 4) + squared norm ----------------
__global__ __launch_bounds__(256) void pos4sq_kernel(const float* __restrict__ pos,
                                                     float* __restrict__ pos4,
                                                     float* __restrict__ sq) {
    int i = blockIdx.x * 256 + threadIdx.x;
    if (i < TOT) {
        float x = pos[i * 3 + 0], y = pos[i * 3 + 1], z = pos[i * 3 + 2];
        pos4[i * 4 + 0] = x;
        pos4[i * 4 + 1] = y;
        pos4[i * 4 + 2] = z;
        pos4[i * 4 + 3] = 0.f;
        sq[i] = x * x + y * y + z * z;
    }
}

// ---------------- layer-1 exact f32 symmetric distance -> 16-bit keys ----------------
template <int KTOT>
__global__ __launch_bounds__(256) void dist_sym16_kernel(const float* __restrict__ x, int ldx,
                                                         const float* __restrict__ sq,
                                                         int b0,
                                                         unsigned short* __restrict__ keys) {
    constexpr int KC = (KTOT < 32) ? KTOT : 32;
    constexpr int F4 = KC / 4;
    __shared__ float Ak[KC][128];
    __shared__ float Bk[KC][128];
    const int tid = threadIdx.x;
    const int tr = tid >> 4, tc = tid & 15;
    int tm = (int)((sqrtf(8.f * blockIdx.x + 1.f) - 1.f) * 0.5f);
    while ((tm + 1) * (tm + 2) / 2 <= (int)blockIdx.x) ++tm;
    while (tm * (tm + 1) / 2 > (int)blockIdx.x) --tm;
    const int tn = blockIdx.x - tm * (tm + 1) / 2;
    const int m0 = tm * 128, n0 = tn * 128;
    const int bofs = (b0 + blockIdx.y) * NP;
    const float* xb = x + (size_t)bofs * ldx;
    float acc[8][8] = {};
    for (int k0 = 0; k0 < KTOT; k0 += KC) {
        __syncthreads();
        for (int i = tid; i < 128 * F4; i += 256) {
            const int r = i / F4, c4 = i % F4;
            const int rs = r ^ ((c4 & 3) << 3);
            float4 v = *reinterpret_cast<const float4*>(xb + (size_t)(m0 + r) * ldx + k0 + c4 * 4);
            Ak[c4 * 4 + 0][rs] = v.x; Ak[c4 * 4 + 1][rs] = v.y;
            Ak[c4 * 4 + 2][rs] = v.z; Ak[c4 * 4 + 3][rs] = v.w;
        }
        for (int i = tid; i < 128 * F4; i += 256) {
            const int r = i / F4, c4 = i % F4;
            const int rs = r ^ ((c4 & 3) << 3);
            float4 v = *reinterpret_cast<const float4*>(xb + (size_t)(n0 + r) * ldx + k0 + c4 * 4);
            Bk[c4 * 4 + 0][rs] = v.x; Bk[c4 * 4 + 1][rs] = v.y;
            Bk[c4 * 4 + 2][rs] = v.z; Bk[c4 * 4 + 3][rs] = v.w;
        }
        __syncthreads();
        #pragma unroll
        for (int k = 0; k < KC; ++k) {
            const int sw = ((k >> 2) & 3) << 3;
            const int ia = (tr * 4) ^ sw;
            const int ib = (tc * 4) ^ sw;
            float4 al = *reinterpret_cast<const float4*>(&Ak[k][ia]);
            float4 ah = *reinterpret_cast<const float4*>(&Ak[k][64 + ia]);
            float4 bl = *reinterpret_cast<const float4*>(&Bk[k][ib]);
            float4 bh = *reinterpret_cast<const float4*>(&Bk[k][64 + ib]);
            float a[8] = {al.x, al.y, al.z, al.w, ah.x, ah.y, ah.z, ah.w};
            float bv[8] = {bl.x, bl.y, bl.z, bl.w, bh.x, bh.y, bh.z, bh.w};
            #pragma unroll
            for (int i = 0; i < 8; ++i)
                #pragma unroll
                for (int j = 0; j < 8; ++j)
                    acc[i][j] += a[i] * bv[j];
        }
    }
    float sa[8], sb[8];
    #pragma unroll
    for (int i = 0; i < 8; ++i) sa[i] = sq[bofs + m0 + ((i < 4) ? tr * 4 + i : 64 + tr * 4 + i - 4)];
    #pragma unroll
    for (int j = 0; j < 8; ++j) sb[j] = sq[bofs + n0 + ((j < 4) ? tc * 4 + j : 64 + tc * 4 + j - 4)];
    #pragma unroll
    for (int i = 0; i < 8; ++i) {
        const int row = (i < 4) ? tr * 4 + i : 64 + tr * 4 + i - 4;
        unsigned short* kr = keys + ((size_t)blockIdx.y * NP + m0 + row) * NP + n0;
        unsigned short kk[8];
        #pragma unroll
        for (int j = 0; j < 8; ++j) kk[j] = key16(sa[i] + sb[j] - 2.f * acc[i][j]);
        *reinterpret_cast<ushort4*>(kr + tc * 4) = make_ushort4(kk[0], kk[1], kk[2], kk[3]);
        *reinterpret_cast<ushort4*>(kr + 64 + tc * 4) = make_ushort4(kk[4], kk[5], kk[6], kk[7]);
    }
    if (tm != tn) {
        #pragma unroll
        for (int j = 0; j < 8; ++j) {
            const int col = (j < 4) ? tc * 4 + j : 64 + tc * 4 + j - 4;
            unsigned short* mr = keys + ((size_t)blockIdx.y * NP + n0 + col) * NP + m0;
            unsigned short lo4[4], hi4[4];
            #pragma unroll
            for (int i = 0; i < 4; ++i) {
                lo4[i] = key16(sa[i] + sb[j] - 2.f * acc[i][j]);
                hi4[i] = key16(sa[i + 4] + sb[j] - 2.f * acc[i + 4][j]);
            }
            *reinterpret_cast<ushort4*>(mr + tr * 4) = make_ushort4(lo4[0], lo4[1], lo4[2], lo4[3]);
            *reinterpret_cast<ushort4*>(mr + 64 + tr * 4) = make_ushort4(hi4[0], hi4[1], hi4[2], hi4[3]);
        }
    }
}

// ---------------- layers 2/3: MFMA bf16x3 distance -> 16-bit keys (transposed store) ----------------
// Full 16x16 tile grid; block computes 128x128 dots from xch/xcl hi/lo splits.
// C/D frag: col = lane&31, row = (e&3)+8*(e>>2)+4*(lane>>5) -> per lane, quads of
// 4 consecutive rows at fixed col => store transposed keys[col][row] as ushort4.
// Union over the full grid covers every entry once. Approx error << key16 ulp;
// select16's +6 margin + exact refine make the final top-20 exact.
__global__ __launch_bounds__(256) void dist_mfma16_kernel(const unsigned short* __restrict__ xh,
                                                          const unsigned short* __restrict__ xl,
                                                          int ch_off,
                                                          const float* __restrict__ sq,
                                                          int b0,
                                                          unsigned short* __restrict__ keys) {
    __shared__ __align__(16) unsigned short Ah[128 * 64];
    __shared__ __align__(16) unsigned short Al[128 * 64];
    __shared__ __align__(16) unsigned short Bh[128 * 64];
    __shared__ __align__(16) unsigned short Bl[128 * 64];
    const int tid = threadIdx.x;
    const int w = tid >> 6, lane = tid & 63;
    const int wr = w >> 1, wc = w & 1;
    const int tm = blockIdx.x >> 4, tn = blockIdx.x & 15;
    const int m0 = tm * 128, n0 = tn * 128;
    const int bofs = (b0 + blockIdx.y) * NP;
    for (int i = tid; i < 1024; i += 256) {
        const int r = i >> 3, slot = i & 7;
        const int ls = r * 64 + ((slot ^ (r & 7)) << 3);
        const size_t ga = (size_t)(bofs + m0 + r) * 256 + ch_off + slot * 8;
        const size_t gb = (size_t)(bofs + n0 + r) * 256 + ch_off + slot * 8;
        *reinterpret_cast<uint4*>(&Ah[ls]) = *reinterpret_cast<const uint4*>(&xh[ga]);
        *reinterpret_cast<uint4*>(&Al[ls]) = *reinterpret_cast<const uint4*>(&xl[ga]);
        *reinterpret_cast<uint4*>(&Bh[ls]) = *reinterpret_cast<const uint4*>(&xh[gb]);
        *reinterpret_cast<uint4*>(&Bl[ls]) = *reinterpret_cast<const uint4*>(&xl[gb]);
    }
    __syncthreads();
    const int h = lane >> 5;
    const int ar0 = wr * 64 + (lane & 31), ar1 = ar0 + 32;
    const int bc0 = wc * 64 + (lane & 31), bc1 = bc0 + 32;
    f32x16 acc00 = {}, acc01 = {}, acc10 = {}, acc11 = {};
    #pragma unroll
    for (int s = 0; s < 4; ++s) {
        const int sl = s * 2 + h;
        const int ia0 = ar0 * 64 + ((sl ^ (ar0 & 7)) << 3);
        const int ia1 = ar1 * 64 + ((sl ^ (ar1 & 7)) << 3);
        const int ib0 = bc0 * 64 + ((sl ^ (bc0 & 7)) << 3);
        const int ib1 = bc1 * 64 + ((sl ^ (bc1 & 7)) << 3);
        short8v a0h = *reinterpret_cast<const short8v*>(&Ah[ia0]);
        short8v a1h = *reinterpret_cast<const short8v*>(&Ah[ia1]);
        short8v a0l = *reinterpret_cast<const short8v*>(&Al[ia0]);
        short8v a1l = *reinterpret_cast<const short8v*>(&Al[ia1]);
        short8v b0h = *reinterpret_cast<const short8v*>(&Bh[ib0]);
        short8v b1h = *reinterpret_cast<const short8v*>(&Bh[ib1]);
        short8v b0l = *reinterpret_cast<const short8v*>(&Bl[ib0]);
        short8v b1l = *reinterpret_cast<const short8v*>(&Bl[ib1]);
        acc00 = __builtin_amdgcn_mfma_f32_32x32x16_bf16(a0h, b0h, acc00, 0, 0, 0);
        acc01 = __builtin_amdgcn_mfma_f32_32x32x16_bf16(a0h, b1h, acc01, 0, 0, 0);
        acc10 = __builtin_amdgcn_mfma_f32_32x32x16_bf16(a1h, b0h, acc10, 0, 0, 0);
        acc11 = __builtin_amdgcn_mfma_f32_32x32x16_bf16(a1h, b1h, acc11, 0, 0, 0);
        acc00 = __builtin_amdgcn_mfma_f32_32x32x16_bf16(a0h, b0l, acc00, 0, 0, 0);
        acc01 = __builtin_amdgcn_mfma_f32_32x32x16_bf16(a0h, b1l, acc01, 0, 0, 0);
        acc10 = __builtin_amdgcn_mfma_f32_32x32x16_bf16(a1h, b0l, acc10, 0, 0, 0);
        acc11 = __builtin_amdgcn_mfma_f32_32x32x16_bf16(a1h, b1l, acc11, 0, 0, 0);
        acc00 = __builtin_amdgcn_mfma_f32_32x32x16_bf16(a0l, b0h, acc00, 0, 0, 0);
        acc01 = __builtin_amdgcn_mfma_f32_32x32x16_bf16(a0l, b1h, acc01, 0, 0, 0);
        acc10 = __builtin_amdgcn_mfma_f32_32x32x16_bf16(a1l, b0h, acc10, 0, 0, 0);
        acc11 = __builtin_amdgcn_mfma_f32_32x32x16_bf16(a1l, b1h, acc11, 0, 0, 0);
    }
    const int colg0 = n0 + bc0;
    const int colg1 = n0 + bc1;
    const float sqc0 = sq[bofs + colg0];
    const float sqc1 = sq[bofs + colg1];
    unsigned short* kb = keys + (size_t)blockIdx.y * NP * NP;
    #pragma unroll
    for (int ai = 0; ai < 2; ++ai) {
        const f32x16& A0 = ai ? acc10 : acc00;
        const f32x16& A1 = ai ? acc11 : acc01;
        #pragma unroll
        for (int q = 0; q < 4; ++q) {
            const int rbase = wr * 64 + ai * 32 + 8 * q + 4 * h;   // frag row base
            float sr[4];
            #pragma unroll
            for (int j = 0; j < 4; ++j) sr[j] = sq[bofs + m0 + rbase + j];
            ushort4 s0, s1;
            s0.x = key16(sr[0] + sqc0 - 2.f * A0[q * 4 + 0]);
            s0.y = key16(sr[1] + sqc0 - 2.f * A0[q * 4 + 1]);
            s0.z = key16(sr[2] + sqc0 - 2.f * A0[q * 4 + 2]);
            s0.w = key16(sr[3] + sqc0 - 2.f * A0[q * 4 + 3]);
            s1.x = key16(sr[0] + sqc1 - 2.f * A1[q * 4 + 0]);
            s1.y = key16(sr[1] + sqc1 - 2.f * A1[q * 4 + 1]);
            s1.z = key16(sr[2] + sqc1 - 2.f * A1[q * 4 + 2]);
            s1.w = key16(sr[3] + sqc1 - 2.f * A1[q * 4 + 3]);
            *reinterpret_cast<ushort4*>(&kb[(size_t)colg0 * NP + m0 + rbase]) = s0;
            *reinterpret_cast<ushort4*>(&kb[(size_t)colg1 * NP + m0 + rbase]) = s1;
        }
    }
}

// ---------------- select16: candidate set {key16 <= T16+6}, cap 64 ----------------
__global__ __launch_bounds__(256) void knn_select16_kernel(const unsigned short* __restrict__ keys,
                                                           int b0,
                                                           int* __restrict__ cands,
                                                           int* __restrict__ cnts) {
    const int tid = threadIdx.x;
    const int w = tid >> 6, lane = tid & 63;
    const int ql = blockIdx.x * 4 + w;        // chunk-local query
    const int bc = ql / NP;
    const int qg = b0 * NP + ql;              // global query
    const int bofs = (b0 + bc) * NP;
    const unsigned* kr = reinterpret_cast<const unsigned*>(keys) + (size_t)ql * (NP / 2);

    unsigned kv[16];
    #pragma unroll
    for (int v = 0; v < 16; ++v) kv[v] = kr[v * 64 + lane];

    unsigned lmn = 0xFFFFu;
    #pragma unroll
    for (int v = 0; v < 16; ++v) {
        lmn = min(lmn, kv[v] & 0xFFFFu);
        lmn = min(lmn, kv[v] >> 16);
    }
    unsigned M = lmn, lo = lmn;
    #pragma unroll
    for (int s = 1; s < 64; s <<= 1) {
        unsigned tM = __shfl_xor(M, s);
        unsigned tl = __shfl_xor(lo, s);
        M = max(M, tM);
        lo = min(lo, tl);
    }
    unsigned hi = M;   // count(<= M) >= 64 >= KK
    while (lo < hi) {
        unsigned mid = (lo + hi) >> 1;
        int c = 0;
        #pragma unroll
        for (int v = 0; v < 16; ++v) {
            c += ((kv[v] & 0xFFFFu) <= mid) ? 1 : 0;
            c += ((kv[v] >> 16) <= mid) ? 1 : 0;
        }
        #pragma unroll
        for (int s = 1; s < 64; s <<= 1) c += __shfl_xor(c, s);
        if (c >= KK) hi = mid; else lo = mid + 1;
    }
    const unsigned T = min(lo + 6u, 0xFFFFu);   // +6 ulp margin covers MFMA approx error

    unsigned nl = 0;
    #pragma unroll
    for (int v = 0; v < 16; ++v) {
        nl += ((kv[v] & 0xFFFFu) <= T) ? 1u : 0u;
        nl += ((kv[v] >> 16) <= T) ? 1u : 0u;
    }
    unsigned sc = nl;
    #pragma unroll
    for (int s = 1; s < 64; s <<= 1) {
        unsigned t2 = __shfl_up(sc, s);
        if (lane >= s) sc += t2;
    }
    const unsigned total = __shfl(sc, 63);
    unsigned off = sc - nl;
    int* cp = cands + (size_t)qg * 64;
    #pragma unroll
    for (int v = 0; v < 16; ++v) {
        if ((kv[v] & 0xFFFFu) <= T) { if (off < 64u) cp[off] = bofs + (v * 64 + lane) * 2; ++off; }
        if ((kv[v] >> 16) <= T)     { if (off < 64u) cp[off] = bofs + (v * 64 + lane) * 2 + 1; ++off; }
    }
    if (lane == 0) cnts[qg] = (int)total;
}

// ---------------- refine: exact f32 re-rank of candidates (float4 loads) ----------------
template <int D>
__global__ __launch_bounds__(256) void knn_refine_kernel(const float* __restrict__ x, int ldx,
                                                         const float* __restrict__ sq,
                                                         const int* __restrict__ cands,
                                                         const int* __restrict__ cnts,
                                                         int* __restrict__ idx_out) {
    constexpr int D4 = D / 4;
    const int tid = threadIdx.x;
    const int w = tid >> 6, lane = tid & 63;
    const int q = blockIdx.x * 4 + w;
    const int bofs = (q / NP) * NP;
    float4 qv[D4];
    const float4* xq4 = reinterpret_cast<const float4*>(x + (size_t)q * ldx);
    #pragma unroll
    for (int k = 0; k < D4; ++k) qv[k] = xq4[k];
    const float sqq = sq[q];
    const int cnt = cnts[q];
    int* op = idx_out + (size_t)q * KK;

    if (cnt <= 64) {
        const int cidx = (lane < cnt) ? cands[(size_t)q * 64 + lane] : -1;
        unsigned key = 0xFFFFFFFFu;
        if (cidx >= 0) {
            const float4* xc4 = reinterpret_cast<const float4*>(x + (size_t)cidx * ldx);
            float acc = 0.f;
            #pragma unroll
            for (int k = 0; k < D4; ++k) {
                float4 c = xc4[k];
                acc += qv[k].x * c.x; acc += qv[k].y * c.y;
                acc += qv[k].z * c.z; acc += qv[k].w * c.w;
            }
            key = mono_key(sqq + sq[cidx] - 2.f * acc);
        }
        unsigned lo = key, hi = key;
        #pragma unroll
        for (int s = 1; s < 64; s <<= 1) {
            unsigned tl = __shfl_xor(lo, s);
            unsigned th = __shfl_xor(hi, s);
            lo = min(lo, tl);
            hi = max(hi, th);
        }
        while (lo < hi) {
            unsigned mid = lo + ((hi - lo) >> 1);
            int c = __popcll(__ballot(key <= mid));
            if (c >= KK) hi = mid; else lo = mid + 1;
        }
        const unsigned T = lo;
        unsigned long long blt = __ballot(key < T);
        const int strict = __popcll(blt);
        if (key < T) {
            int o = __popcll(blt & ((1ull << lane) - 1ull));
            op[o] = cidx;
        }
        const int rem = KK - strict;
        bool eq = (key == T) && (cidx >= 0);
        bool done = false;
        for (int t = 0; t < rem; ++t) {   // emit ties in ascending global index order
            int v = (eq && !done) ? cidx : 0x7FFFFFFF;
            #pragma unroll
            for (int s = 1; s < 64; s <<= 1) v = min(v, __shfl_xor(v, s));
            if (eq && !done && cidx == v) { op[strict + t] = cidx; done = true; }
        }
    } else {
        // fallback: exact full-row scan (deterministic; ~never taken)
        unsigned keysr[32];
        for (int u = 0; u < 32; ++u) {
            const int c = bofs + u * 64 + lane;
            const float4* xc4 = reinterpret_cast<const float4*>(x + (size_t)c * ldx);
            float acc = 0.f;
            #pragma unroll
            for (int k = 0; k < D4; ++k) {
                float4 cv = xc4[k];
                acc += qv[k].x * cv.x; acc += qv[k].y * cv.y;
                acc += qv[k].z * cv.z; acc += qv[k].w * cv.w;
            }
            keysr[u] = mono_key(sqq + sq[c] - 2.f * acc);
        }
        unsigned lmn = 0xFFFFFFFFu;
        #pragma unroll
        for (int u = 0; u < 32; ++u) lmn = min(lmn, keysr[u]);
        unsigned M = lmn, lo = lmn;
        #pragma unroll
        for (int s = 1; s < 64; s <<= 1) {
            unsigned tM = __shfl_xor(M, s);
            unsigned tl = __shfl_xor(lo, s);
            M = max(M, tM);
            lo = min(lo, tl);
        }
        unsigned hi = M;
        while (lo < hi) {
            unsigned mid = lo + ((hi - lo) >> 1);
            int c = 0;
            #pragma unroll
            for (int u = 0; u < 32; ++u)
                c += __popcll(__ballot(keysr[u] <= mid));
            if (c >= KK) hi = mid; else lo = mid + 1;
        }
        const unsigned T = lo;
        unsigned nl = 0;
        #pragma unroll
        for (int u = 0; u < 32; ++u) nl += (keysr[u] < T) ? 1u : 0u;
        unsigned sc2 = nl;
        #pragma unroll
        for (int s = 1; s < 64; s <<= 1) {
            unsigned t2 = __shfl_up(sc2, s);
            if (lane >= s) sc2 += t2;
        }
        unsigned cstrict = __shfl(sc2, 63);
        unsigned o = sc2 - nl;
        #pragma unroll
        for (int u = 0; u < 32; ++u) {
            if (keysr[u] < T) { op[o] = bofs + u * 64 + lane; ++o; }
        }
        int rem = KK - (int)cstrict;
        int ebase = (int)cstrict;
        #pragma unroll
        for (int u = 0; u < 32; ++u) {
            if (rem > 0) {
                bool eq = (keysr[u] == T);
                unsigned long long bm = __ballot(eq);
                int before = __popcll(bm & ((1ull << lane) - 1ull));
                if (eq && before < rem) op[ebase + before] = bofs + u * 64 + lane;
                int take = __popcll(bm);
                if (take > rem) take = rem;
                ebase += take;
                rem -= take;
            }
        }
    }
}

// ---------------- Wt[c][j] build: [Wd | Wtail] transposed, zero-padded ----------------
__global__ __launch_bounds__(256) void wt_build_kernel(const float* __restrict__ W,
                                                       float* __restrict__ Wt,
                                                       int D, int Dp, int C) {
    int i = blockIdx.x * 256 + threadIdx.x;
    if (i < 2 * C * Dp) {
        int c = i / Dp, j = i % Dp;
        float v = 0.f;
        if (j < D) {
            v = (c < C) ? (W[j * C + c] - W[(D + j) * C + c])
                        : W[(D + j) * C + (c - C)];
        }
        Wt[i] = v;
    }
}

// ---------------- X[TOT,Dp] @ Wt^T -> basexw[TOT,2C] ----------------
template <int NJ4, int C2>
__global__ __launch_bounds__(256) void xw_gemm_kernel(const float* __restrict__ x, int ldx,
                                                      const float* __restrict__ Wt,
                                                      float* __restrict__ bx) {
    constexpr int PG = 256 / C2;   // point groups
    constexpr int PTS = 16 / PG;   // points per thread
    __shared__ float4 Xs[16][NJ4];
    const int tid = threadIdx.x;
    const int p0 = blockIdx.x * 16;
    for (int i = tid; i < 16 * NJ4; i += 256) {
        int r = i / NJ4, j4 = i % NJ4;
        Xs[r][j4] = *reinterpret_cast<const float4*>(x + (size_t)(p0 + r) * ldx + j4 * 4);
    }
    __syncthreads();
    const int c = tid % C2, pg = tid / C2;
    const float4* wrow = reinterpret_cast<const float4*>(Wt + (size_t)c * (NJ4 * 4));
    float acc[PTS];
    #pragma unroll
    for (int u = 0; u < PTS; ++u) acc[u] = 0.f;
    #pragma unroll
    for (int j4 = 0; j4 < NJ4; ++j4) {
        float4 w4 = wrow[j4];
        #pragma unroll
        for (int u = 0; u < PTS; ++u) {
            float4 x4 = Xs[pg * PTS + u][j4];
            acc[u] += x4.x * w4.x + x4.y * w4.y + x4.z * w4.z + x4.w * w4.w;
        }
    }
    #pragma unroll
    for (int u = 0; u < PTS; ++u)
        bx[(size_t)(p0 + pg * PTS + u) * C2 + c] = acc[u];
}

// ---------------- edge pass: gather XW, stats + per-point max/min ----------------
template <int C>
__global__ __launch_bounds__(256) void edge_pass_kernel(const float* __restrict__ bx,
                                                        const int* __restrict__ idx,
                                                        float* __restrict__ psum,
                                                        float* __restrict__ psum2,
                                                        float* __restrict__ mmax,
                                                        float* __restrict__ mmin) {
    constexpr int PT = 256 / C;
    constexpr int C2 = 2 * C;
    __shared__ int sidx[PT][KK];
    __shared__ float red[256];
    const int tid = threadIdx.x;
    const int c = tid % C;
    const int pl = tid / C;
    float s1 = 0.f, s2 = 0.f;
    const int NT = TOT / PT;
    for (int t = blockIdx.x; t < NT; t += EBLK) {
        const int p0 = t * PT;
        __syncthreads();
        if (tid < PT * KK) sidx[tid / KK][tid % KK] = idx[(size_t)p0 * KK + tid];
        __syncthreads();
        const int p = p0 + pl;
        const float bv = bx[(size_t)p * C2 + c];
        float A = 0.f, Q = 0.f, M = -FLT_MAX, mn = FLT_MAX;
        #pragma unroll
        for (int k = 0; k < KK; ++k) {
            float v = bx[(size_t)sidx[pl][k] * C2 + C + c];
            A += v; Q += v * v; M = fmaxf(M, v); mn = fminf(mn, v);
        }
        s1 += (float)KK * bv + A;
        s2 += (float)KK * bv * bv + 2.f * bv * A + Q;
        mmax[(size_t)p * C + c] = bv + M;
        mmin[(size_t)p * C + c] = bv + mn;
    }
    red[tid] = s1;
    __syncthreads();
    if (tid < C) {
        float v = red[tid];
        #pragma unroll
        for (int u = 1; u < PT; ++u) v += red[tid + u * C];
        psum[(size_t)blockIdx.x * C + tid] = v;
    }
    __syncthreads();
    red[tid] = s2;
    __syncthreads();
    if (tid < C) {
        float v = red[tid];
        #pragma unroll
        for (int u = 1; u < PT; ++u) v += red[tid + u * C];
        psum2[(size_t)blockIdx.x * C + tid] = v;
    }
}

// ---------------- BN stats reduce -> alpha/beta ----------------
__global__ __launch_bounds__(256) void bn_reduce_kernel(
        const float* __restrict__ psum, const float* __restrict__ psum2,
        int npart, int C, const float* __restrict__ g, const float* __restrict__ bb,
        float inv_cnt, float* __restrict__ alpha, float* __restrict__ beta) {
    const int c = blockIdx.x;
    const int tid = threadIdx.x;
    __shared__ float r1[256], r2[256];
    float s1 = 0.f, s2 = 0.f;
    for (int i = tid; i < npart; i += 256) {
        s1 += psum[(size_t)i * C + c];
        s2 += psum2[(size_t)i * C + c];
    }
    r1[tid] = s1; r2[tid] = s2;
    __syncthreads();
    for (int s = 128; s > 0; s >>= 1) {
        if (tid < s) { r1[tid] += r1[tid + s]; r2[tid] += r2[tid + s]; }
        __syncthreads();
    }
    if (tid == 0) {
        float mean = r1[0] * inv_cnt;
        float var = r2[0] * inv_cnt - mean * mean;
        float a = g[c] * rsqrtf(var + 1e-5f);
        alpha[c] = a;
        beta[c] = bb[c] - mean * a;
    }
}

// ---------------- edge finalize: pick by sign(alpha), affine+leaky; f32 + bf16 hi/lo (+sq) ----------------
template <int C>
__global__ __launch_bounds__(256) void edge_finalize_kernel(const float* __restrict__ mmax,
                                                            const float* __restrict__ mmin,
                                                            const float* __restrict__ alpha,
                                                            const float* __restrict__ beta,
                                                            float* __restrict__ xcf, int ldf,
                                                            unsigned short* __restrict__ xch,
                                                            unsigned short* __restrict__ xcl,
                                                            int ch_off,
                                                            float* __restrict__ sq_out) {
    constexpr int CQ = C / 4;
    __shared__ float red[256];
    const int tid = threadIdx.x;
    int i4 = blockIdx.x * 256 + tid;
    float4 o = make_float4(0.f, 0.f, 0.f, 0.f);
    int p = 0;
    if (i4 < TOT * CQ) {
        int cq; p = i4 / CQ; cq = i4 - p * CQ;
        float4 M4 = reinterpret_cast<const float4*>(mmax)[i4];
        float4 m4 = reinterpret_cast<const float4*>(mmin)[i4];
        float4 a4 = reinterpret_cast<const float4*>(alpha)[cq];
        float4 b4 = reinterpret_cast<const float4*>(beta)[cq];
        o.x = leaky(a4.x * (a4.x >= 0.f ? M4.x : m4.x) + b4.x);
        o.y = leaky(a4.y * (a4.y >= 0.f ? M4.y : m4.y) + b4.y);
        o.z = leaky(a4.z * (a4.z >= 0.f ? M4.z : m4.z) + b4.z);
        o.w = leaky(a4.w * (a4.w >= 0.f ? M4.w : m4.w) + b4.w);
        if (xcf)
            *reinterpret_cast<float4*>(xcf + (size_t)p * ldf + cq * 4) = o;
        ushort4 hh, ll;
        hh.x = bf16_rne(o.x); ll.x = bf16_rne(o.x - bf16_f(hh.x));
        hh.y = bf16_rne(o.y); ll.y = bf16_rne(o.y - bf16_f(hh.y));
        hh.z = bf16_rne(o.z); ll.z = bf16_rne(o.z - bf16_f(hh.z));
        hh.w = bf16_rne(o.w); ll.w = bf16_rne(o.w - bf16_f(hh.w));
        const size_t oo = (size_t)p * 256 + ch_off + cq * 4;
        *reinterpret_cast<ushort4*>(xch + oo) = hh;
        *reinterpret_cast<ushort4*>(xcl + oo) = ll;
    }
    if (sq_out) {   // only used for C=64 (CQ=16, 16 pts/block, exact grid)
        red[tid] = o.x * o.x + o.y * o.y + o.z * o.z + o.w * o.w;
        __syncthreads();
        if ((tid & (CQ - 1)) == 0) {
            float s = red[tid];
            #pragma unroll
            for (int u = 1; u < CQ; ++u) s += red[tid + u];
            sq_out[p] = s;
        }
    }
}

// ---------------- Wf -> bf16 hi/lo, transposed to [1024][256] ----------------
__global__ __launch_bounds__(256) void wfhl_build_kernel(const float* __restrict__ Wf,
                                                         unsigned short* __restrict__ wfh,
                                                         unsigned short* __restrict__ wfl) {
    int i = blockIdx.x * 256 + threadIdx.x;
    if (i < 256 * 1024) {
        int e = i / 1024, o = i - e * 1024;
        float v = Wf[i];
        unsigned short h = bf16_rne(v);
        wfh[(size_t)o * 256 + e] = h;
        wfl[(size_t)o * 256 + e] = bf16_rne(v - bf16_f(h));
    }
}

// ---------------- conv_final via MFMA bf16x3 + stat partials ----------------
__global__ __launch_bounds__(256) void fc_mfma_kernel(const unsigned short* __restrict__ xch,
                                                      const unsigned short* __restrict__ xcl,
                                                      const unsigned short* __restrict__ wfh,
                                                      const unsigned short* __restrict__ wfl,
                                                      float* __restrict__ psum,
                                                      float* __restrict__ psum2,
                                                      float* __restrict__ pmax,
                                                      float* __restrict__ pmin) {
    __shared__ __align__(16) unsigned short Ah[128 * 64];
    __shared__ __align__(16) unsigned short Al[128 * 64];
    __shared__ __align__(16) unsigned short Bh[128 * 64];
    __shared__ __align__(16) unsigned short Bl[128 * 64];
    const int tid = threadIdx.x;
    const int w = tid >> 6, lane = tid & 63;
    const int wr = w >> 1, wc = w & 1;
    const int pt = blockIdx.x, ct = blockIdx.y;
    f32x16 acc00 = {}, acc01 = {}, acc10 = {}, acc11 = {};
    for (int kc = 0; kc < 4; ++kc) {
        const int k0 = kc * 64;
        __syncthreads();
        for (int i = tid; i < 1024; i += 256) {
            const int r = i >> 3, slot = i & 7;
            const int ls = r * 64 + ((slot ^ (r & 7)) << 3);
            const size_t ga = (size_t)(pt * 128 + r) * 256 + k0 + slot * 8;
            const size_t gb = (size_t)(ct * 128 + r) * 256 + k0 + slot * 8;
            *reinterpret_cast<uint4*>(&Ah[ls]) = *reinterpret_cast<const uint4*>(&xch[ga]);
            *reinterpret_cast<uint4*>(&Al[ls]) = *reinterpret_cast<const uint4*>(&xcl[ga]);
            *reinterpret_cast<uint4*>(&Bh[ls]) = *reinterpret_cast<const uint4*>(&wfh[gb]);
            *reinterpret_cast<uint4*>(&Bl[ls]) = *reinterpret_cast<const uint4*>(&wfl[gb]);
        }
        __syncthreads();
        const int h = lane >> 5;
        const int ar0 = wr * 64 + (lane & 31), ar1 = ar0 + 32;
        const int bc0 = wc * 64 + (lane & 31), bc1 = bc0 + 32;
        #pragma unroll
        for (int s = 0; s < 4; ++s) {
            const int sl = s * 2 + h;
            const int ia0 = ar0 * 64 + ((sl ^ (ar0 & 7)) << 3);
            const int ia1 = ar1 * 64 + ((sl ^ (ar1 & 7)) << 3);
            const int ib0 = bc0 * 64 + ((sl ^ (bc0 & 7)) << 3);
            const int ib1 = bc1 * 64 + ((sl ^ (bc1 & 7)) << 3);
            short8v a0h = *reinterpret_cast<const short8v*>(&Ah[ia0]);
            short8v a1h = *reinterpret_cast<const short8v*>(&Ah[ia1]);
            short8v a0l = *reinterpret_cast<const short8v*>(&Al[ia0]);
            short8v a1l = *reinterpret_cast<const short8v*>(&Al[ia1]);
            short8v b0h = *reinterpret_cast<const short8v*>(&Bh[ib0]);
            short8v b1h = *reinterpret_cast<const short8v*>(&Bh[ib1]);
            short8v b0l = *reinterpret_cast<const short8v*>(&Bl[ib0]);
            short8v b1l = *reinterpret_cast<const short8v*>(&Bl[ib1]);
            acc00 = __builtin_amdgcn_mfma_f32_32x32x16_bf16(a0h, b0h, acc00, 0, 0, 0);
            acc01 = __builtin_amdgcn_mfma_f32_32x32x16_bf16(a0h, b1h, acc01, 0, 0, 0);
            acc10 = __builtin_amdgcn_mfma_f32_32x32x16_bf16(a1h, b0h, acc10, 0, 0, 0);
            acc11 = __builtin_amdgcn_mfma_f32_32x32x16_bf16(a1h, b1h, acc11, 0, 0, 0);
            acc00 = __builtin_amdgcn_mfma_f32_32x32x16_bf16(a0h, b0l, acc00, 0, 0, 0);
            acc01 = __builtin_amdgcn_mfma_f32_32x32x16_bf16(a0h, b1l, acc01, 0, 0, 0);
            acc10 = __builtin_amdgcn_mfma_f32_32x32x16_bf16(a1h, b0l, acc10, 0, 0, 0);
            acc11 = __builtin_amdgcn_mfma_f32_32x32x16_bf16(a1h, b1l, acc11, 0, 0, 0);
            acc00 = __builtin_amdgcn_mfma_f32_32x32x16_bf16(a0l, b0h, acc00, 0, 0, 0);
            acc01 = __builtin_amdgcn_mfma_f32_32x32x16_bf16(a0l, b1h, acc01, 0, 0, 0);
            acc10 = __builtin_amdgcn_mfma_f32_32x32x16_bf16(a1l, b0h, acc10, 0, 0, 0);
            acc11 = __builtin_amdgcn_mfma_f32_32x32x16_bf16(a1l, b1h, acc11, 0, 0, 0);
        }
    }
    float* red = reinterpret_cast<float*>(Ah);   // [2 wr][128 ch][4 stats]
    __syncthreads();
    #pragma unroll
    for (int fc = 0; fc < 2; ++fc) {
        float s1 = 0.f, s2 = 0.f, mx = -FLT_MAX, mn = FLT_MAX;
        #pragma unroll
        for (int e = 0; e < 16; ++e) {
            float v0 = (fc == 0) ? acc00[e] : acc01[e];
            float v1 = (fc == 0) ? acc10[e] : acc11[e];
            s1 += v0 + v1;
            s2 += v0 * v0 + v1 * v1;
            mx = fmaxf(mx, fmaxf(v0, v1));
            mn = fminf(mn, fminf(v0, v1));
        }
        s1 += __shfl_xor(s1, 32);
        s2 += __shfl_xor(s2, 32);
        mx = fmaxf(mx, __shfl_xor(mx, 32));
        mn = fminf(mn, __shfl_xor(mn, 32));
        if (lane < 32) {
            const int ch = wc * 64 + fc * 32 + lane;
            float4 st; st.x = s1; st.y = s2; st.z = mx; st.w = mn;
            *reinterpret_cast<float4*>(&red[(wr * 128 + ch) * 4]) = st;
        }
    }
    __syncthreads();
    if (tid < 128) {
        float4 s0 = *reinterpret_cast<const float4*>(&red[tid * 4]);
        float4 s1 = *reinterpret_cast<const float4*>(&red[(128 + tid) * 4]);
        const size_t go = (size_t)pt * 1024 + ct * 128 + tid;
        psum[go]  = s0.x + s1.x;
        psum2[go] = s0.y + s1.y;
        pmax[go]  = fmaxf(s0.z, s1.z);
        pmin[go]  = fminf(s0.w, s1.w);
    }
}

// ---------------- gfeat finalize (16 point-tile partials per batch) ----------------
__global__ __launch_bounds__(256) void gfeat_final_kernel(const float* __restrict__ pmax,
                                                          const float* __restrict__ pmin,
                                                          const float* __restrict__ alpha,
                                                          const float* __restrict__ beta,
                                                          float* __restrict__ gfeat) {
    int i = blockIdx.x * 256 + threadIdx.x;
    if (i < NB * 1024) {
        int b = i >> 10, c = i & 1023;
        float mx = -FLT_MAX, mn = FLT_MAX;
        for (int j = 0; j < 16; ++j) {
            size_t o = (size_t)(b * 16 + j) * 1024 + c;
            mx = fmaxf(mx, pmax[o]);
            mn = fminf(mn, pmin[o]);
        }
        float a = alpha[c];
        gfeat[i] = leaky(a * (a >= 0.f ? mx : mn) + beta[c]);
    }
}

// ---------------- classifier: split-K skinny GEMM, A is [16][K] ----------------
template <int CHUNK>
__global__ __launch_bounds__(256) void skinny_gemm_kernel(const float* __restrict__ A,
                                                          const float* __restrict__ W,
                                                          float* __restrict__ part,
                                                          int K, int N) {
    __shared__ float Asub[4][16][CHUNK];
    const int tid = threadIdx.x;
    const int g = tid >> 6, lane = tid & 63;
    const int c = blockIdx.x * 64 + lane;
    const int ks = blockIdx.y * 4 + g;
    const int e0 = ks * CHUNK;
    for (int i = lane; i < 16 * CHUNK; i += 64) {
        const int m = i / CHUNK, el = i - m * CHUNK;
        Asub[g][m][el] = A[(size_t)m * K + e0 + el];
    }
    if (c < N) {
        float acc[16];
        #pragma unroll
        for (int m = 0; m < 16; ++m) acc[m] = 0.f;
        #pragma unroll 4
        for (int el = 0; el < CHUNK; ++el) {
            float w = W[(size_t)(e0 + el) * N + c];
            #pragma unroll
            for (int m = 0; m < 16; ++m) acc[m] += Asub[g][m][el] * w;
        }
        #pragma unroll
        for (int m = 0; m < 16; ++m)
            part[((size_t)ks * 16 + m) * N + c] = acc[m];
    }
}

// ---------------- classifier finish: reduce splits + bias (+BN over rows + leaky) ----------------
__global__ __launch_bounds__(256) void fin_kernel(const float* __restrict__ part,
                                                  int S, int N,
                                                  const float* __restrict__ bias,
                                                  const float* __restrict__ g,
                                                  const float* __restrict__ bb,
                                                  int do_bn,
                                                  float* __restrict__ out, int Nout) {
    int c = blockIdx.x * 256 + threadIdx.x;
    if (c >= N) return;
    float z[16];
    #pragma unroll
    for (int m = 0; m < 16; ++m) z[m] = bias[c];
    for (int s = 0; s < S; ++s)
        #pragma unroll
        for (int m = 0; m < 16; ++m) z[m] += part[((size_t)s * 16 + m) * N + c];
    if (do_bn) {
        float s1 = 0.f, s2 = 0.f;
        #pragma unroll
        for (int m = 0; m < 16; ++m) { s1 += z[m]; s2 += z[m] * z[m]; }
        float mean = s1 * (1.f / 16.f);
        float var = s2 * (1.f / 16.f) - mean * mean;
        float a = g[c] * rsqrtf(var + 1e-5f);
        float be = bb[c] - mean * a;
        #pragma unroll
        for (int m = 0; m < 16; ++m) out[(size_t)m * N + c] = leaky(a * z[m] + be);
    } else {
        if (c < Nout)
            #pragma unroll
            for (int m = 0; m < 16; ++m) out[(size_t)m * Nout + c] = z[m];
    }
}

static void run_knn_l1(const float* x, const float* sq, unsigned short* keys16, int CB,
                       int* cands, int* cnts, int* idx, hipStream_t stream) {
    for (int b0 = 0; b0 < NB; b0 += CB) {
        dim3 g(136, CB);   // lower-triangle tile pairs
        dist_sym16_kernel<4><<<g, 256, 0, stream>>>(x, 4, sq, b0, keys16);
        knn_select16_kernel<<<CB * NP / 4, 256, 0, stream>>>(keys16, b0, cands, cnts);
    }
    knn_refine_kernel<4><<<TOT / 4, 256, 0, stream>>>(x, 4, sq, cands, cnts, idx);
}

static void run_knn_feat(const unsigned short* xh, const unsigned short* xl, int ch_off,
                         const float* xf, const float* sq, unsigned short* keys16, int CB,
                         int* cands, int* cnts, int* idx, hipStream_t stream) {
    for (int b0 = 0; b0 < NB; b0 += CB) {
        dim3 g(256, CB);   // full tile grid
        dist_mfma16_kernel<<<g, 256, 0, stream>>>(xh, xl, ch_off, sq, b0, keys16);
        knn_select16_kernel<<<CB * NP / 4, 256, 0, stream>>>(keys16, b0, cands, cnts);
    }
    knn_refine_kernel<64><<<TOT / 4, 256, 0, stream>>>(xf, 128, sq, cands, cnts, idx);
}

} // namespace

extern "C" void kernel_launch(void* const* d_in, const int* in_sizes, int n_in,
                              void* d_out, int out_size, void* d_ws, size_t ws_size,
                              hipStream_t stream) {
    (void)in_sizes; (void)n_in; (void)out_size;
    const float* pos = (const float*)d_in[0];
    const float* W1  = (const float*)d_in[1];
    const float* g1  = (const float*)d_in[2];
    const float* b1  = (const float*)d_in[3];
    const float* W2  = (const float*)d_in[4];
    const float* g2  = (const float*)d_in[5];
    const float* b2  = (const float*)d_in[6];
    const float* W3  = (const float*)d_in[7];
    const float* g3  = (const float*)d_in[8];
    const float* b3  = (const float*)d_in[9];
    const float* Wf  = (const float*)d_in[10];
    const float* gf  = (const float*)d_in[11];
    const float* bf  = (const float*)d_in[12];
    const float* W4  = (const float*)d_in[13];
    const float* b4  = (const float*)d_in[14];
    const float* g4  = (const float*)d_in[15];
    const float* be4 = (const float*)d_in[16];
    const float* W5  = (const float*)d_in[17];
    const float* b5  = (const float*)d_in[18];
    const float* g5  = (const float*)d_in[19];
    const float* be5 = (const float*)d_in[20];
    const float* W6  = (const float*)d_in[21];
    const float* b6  = (const float*)d_in[22];
    float* out = (float*)d_out;

    float* ws = (float*)d_ws;
    size_t off = 0;
    int*   idx    = (int*)ws;      off += (size_t)TOT * KK;          // 2.6 MB
    float* pos4   = ws + off;      off += (size_t)TOT * 4;
    float* sq     = ws + off;      off += (size_t)TOT;
    float* Wt     = ws + off;      off += 256 * 64;
    float* basexw = ws + off;      off += (size_t)TOT * 256;         // 32 MB
    float* mmax   = ws + off;      off += (size_t)TOT * 128;         // 16 MB
    float* mmin   = ws + off;      off += (size_t)TOT * 128;         // 16 MB
    float* xc12   = ws + off;      off += (size_t)TOT * 128;         // 16 MB (x1|x2 f32)
    unsigned short* xch = (unsigned short*)(ws + off); off += (size_t)TOT * 128;  // 16 MB bf16 hi
    unsigned short* xcl = (unsigned short*)(ws + off); off += (size_t)TOT * 128;  // 16 MB bf16 lo
    unsigned short* wfh = (unsigned short*)(ws + off); off += (size_t)1024 * 128;
    unsigned short* wfl = (unsigned short*)(ws + off); off += (size_t)1024 * 128;
    float* psum   = ws + off;      off += (size_t)512 * 1024;        // 2 MB
    float* psum2  = ws + off;      off += (size_t)512 * 1024;
    float* pmax   = ws + off;      off += (size_t)512 * 1024;
    float* pmin   = ws + off;      off += (size_t)512 * 1024;
    float* alpha  = ws + off;      off += 1024;
    float* beta   = ws + off;      off += 1024;
    float* gfeat  = ws + off;      off += NB * 1024;
    float* part   = ws + off;      off += 8 * 16 * 512;              // split-K partials
    float* h4     = ws + off;      off += NB * 512;
    float* h5     = ws + off;      off += NB * 256;
    int*   cands  = (int*)(ws + off); off += (size_t)TOT * 64;       // 8.4 MB
    int*   cnts   = (int*)(ws + off); off += TOT;
    unsigned short* keys16 = (unsigned short*)(ws + off);
    const size_t avail = (ws_size > off * 4) ? (ws_size - off * 4) : 0;
    const size_t per_batch = (size_t)NP * NP * 2;   // 16-bit keys
    int CB = 1;
    for (int cb : {8, 4, 2}) {     // keys16 <= 64 MB, L3-resident
        if ((size_t)cb * per_batch <= avail) { CB = cb; break; }
    }

    const int npts_blk = (TOT + 255) / 256;

    // ---------- Layer 1 (D=3 padded to 4, C=64) ----------
    pos4sq_kernel<<<npts_blk, 256, 0, stream>>>(pos, pos4, sq);
    run_knn_l1(pos4, sq, keys16, CB, cands, cnts, idx, stream);
    wt_build_kernel<<<2, 256, 0, stream>>>(W1, Wt, 3, 4, 64);
    xw_gemm_kernel<1, 128><<<TOT / 16, 256, 0, stream>>>(pos4, 4, Wt, basexw);
    edge_pass_kernel<64><<<EBLK, 256, 0, stream>>>(basexw, idx, psum, psum2, mmax, mmin);
    bn_reduce_kernel<<<64, 256, 0, stream>>>(psum, psum2, EBLK, 64, g1, b1,
                                             1.f / (float)(TOT * KK), alpha, beta);
    edge_finalize_kernel<64><<<TOT * 16 / 256, 256, 0, stream>>>(
        mmax, mmin, alpha, beta, xc12 + 0, 128, xch, xcl, 0, sq);   // sq for layer 2

    // ---------- Layer 2 (D=64, C=64), input x1 = xc12[:,0:64] / xch[:,0:64] ----------
    run_knn_feat(xch, xcl, 0, xc12 + 0, sq, keys16, CB, cands, cnts, idx, stream);
    wt_build_kernel<<<32, 256, 0, stream>>>(W2, Wt, 64, 64, 64);
    xw_gemm_kernel<16, 128><<<TOT / 16, 256, 0, stream>>>(xc12 + 0, 128, Wt, basexw);
    edge_pass_kernel<64><<<EBLK, 256, 0, stream>>>(basexw, idx, psum, psum2, mmax, mmin);
    bn_reduce_kernel<<<64, 256, 0, stream>>>(psum, psum2, EBLK, 64, g2, b2,
                                             1.f / (float)(TOT * KK), alpha, beta);
    edge_finalize_kernel<64><<<TOT * 16 / 256, 256, 0, stream>>>(
        mmax, mmin, alpha, beta, xc12 + 64, 128, xch, xcl, 64, sq); // sq for layer 3

    // ---------- Layer 3 (D=64, C=128), input x2 = xc12[:,64:128] / xch[:,64:128] ----------
    run_knn_feat(xch, xcl, 64, xc12 + 64, sq, keys16, CB, cands, cnts, idx, stream);
    wt_build_kernel<<<64, 256, 0, stream>>>(W3, Wt, 64, 64, 128);
    xw_gemm_kernel<16, 256><<<TOT / 16, 256, 0, stream>>>(xc12 + 64, 128, Wt, basexw);
    edge_pass_kernel<128><<<EBLK, 256, 0, stream>>>(basexw, idx, psum, psum2, mmax, mmin);
    bn_reduce_kernel<<<128, 256, 0, stream>>>(psum, psum2, EBLK, 128, g3, b3,
                                              1.f / (float)(TOT * KK), alpha, beta);
    edge_finalize_kernel<128><<<TOT * 32 / 256, 256, 0, stream>>>(
        mmax, mmin, alpha, beta, nullptr, 0, xch, xcl, 128, nullptr);

    // ---------- conv_final (MFMA bf16x3) + global max pool ----------
    wfhl_build_kernel<<<1024, 256, 0, stream>>>(Wf, wfh, wfl);
    {
        dim3 g(TOT / 128, 8, 1);
        fc_mfma_kernel<<<g, 256, 0, stream>>>(xch, xcl, wfh, wfl, psum, psum2, pmax, pmin);
    }
    bn_reduce_kernel<<<1024, 256, 0, stream>>>(psum, psum2, 256, 1024, gf, bf,
                                               1.f / (float)TOT, alpha, beta);
    gfeat_final_kernel<<<64, 256, 0, stream>>>(pmax, pmin, alpha, beta, gfeat);

    // ---------- classifier (split-K skinny GEMMs) ----------
    skinny_gemm_kernel<128><<<dim3(8, 2), 256, 0, stream>>>(gfeat, W4, part, 1024, 512);
    fin_kernel<<<2, 256, 0, stream>>>(part, 8, 512, b4, g4, be4, 1, h4, 512);
    skinny_gemm_kernel<64><<<dim3(4, 2), 256, 0, stream>>>(h4, W5, part, 512, 256);
    fin_kernel<<<1, 256, 0, stream>>>(part, 8, 256, b5, g5, be5, 1, h5, 256);
    skinny_gemm_kernel<32><<<dim3(1, 2), 256, 0, stream>>>(h5, W6, part, 256, 40);
    fin_kernel<<<1, 256, 0, stream>>>(part, 8, 40, b6, nullptr, nullptr, 0, out, 40);
}